// Round 7
// baseline (300.760 us; speedup 1.0000x reference)
//
#include <hip/hip_runtime.h>

#define EPS 1e-5f
typedef unsigned short u16;
typedef unsigned int u32;
typedef float f32x4 __attribute__((ext_vector_type(4)));
typedef short bf16x8 __attribute__((ext_vector_type(8)));

__device__ __forceinline__ float bf2f(u16 h){
  return __uint_as_float(((u32)h) << 16);
}
__device__ __forceinline__ u16 f2bf(float f){
  u32 u = __float_as_uint(f);
  u += 0x7fffu + ((u >> 16) & 1u);
  return (u16)(u >> 16);
}
__device__ __forceinline__ u32 pk2(float lo, float hi){
  return ((u32)f2bf(hi) << 16) | (u32)f2bf(lo);
}
union BF8 { bf16x8 v; u32 u[4]; };

// ---------------------------------------------------------------------------
// k_prep1: GN(x)->normed, GN(normed)->xr, gap (per-channel mean of normed)
// ---------------------------------------------------------------------------
__global__ __launch_bounds__(256) void k_prep1(
    const float* __restrict__ x, const float* __restrict__ gn_g, const float* __restrict__ gn_b,
    const float* __restrict__ ra_g, const float* __restrict__ ra_b,
    float* __restrict__ normed, float* __restrict__ xr, float* __restrict__ gap)
{
  int ch = blockIdx.x, b = blockIdx.y;
  int c0 = ch * 32;
  __shared__ float xs[1568], ns[1568];
  const float* xb = x + ((size_t)b * 256 + c0) * 49;
  for (int i = threadIdx.x; i < 1568; i += 256) xs[i] = xb[i];
  __syncthreads();
  int wv = threadIdx.x >> 6, lane = threadIdx.x & 63;
  const float* gsrc = xs + wv * 392;
  float* ndst = ns + wv * 392;
  float s = 0.f, ss = 0.f;
  for (int i = lane; i < 392; i += 64){ float v = gsrc[i]; s += v; ss += v * v; }
  for (int off = 32; off; off >>= 1){ s += __shfl_down(s, off); ss += __shfl_down(ss, off); }
  s = __shfl(s, 0); ss = __shfl(ss, 0);
  float m = s / 392.f, rs = rsqrtf(ss / 392.f - m * m + EPS);
  for (int i = lane; i < 392; i += 64){
    int c = c0 + wv * 8 + i / 49;
    ndst[i] = (gsrc[i] - m) * rs * gn_g[c] + gn_b[c];
  }
  __syncthreads();
  float* nb = normed + ((size_t)b * 256 + c0) * 49;
  for (int i = threadIdx.x; i < 1568; i += 256) nb[i] = ns[i];
  if (threadIdx.x < 32){
    float g2 = 0.f; const float* rp = ns + threadIdx.x * 49;
    for (int p = 0; p < 49; p++) g2 += rp[p];
    gap[(size_t)b * 256 + c0 + threadIdx.x] = g2 * (1.f / 49.f);
  }
  s = 0.f; ss = 0.f;
  for (int i = lane; i < 392; i += 64){ float v = ndst[i]; s += v; ss += v * v; }
  for (int off = 32; off; off >>= 1){ s += __shfl_down(s, off); ss += __shfl_down(ss, off); }
  s = __shfl(s, 0); ss = __shfl(ss, 0);
  m = s / 392.f; rs = rsqrtf(ss / 392.f - m * m + EPS);
  float* xrb = xr + ((size_t)b * 256 + c0) * 49;
  for (int i = lane; i < 392; i += 64){
    int c = c0 + wv * 8 + i / 49;
    xrb[wv * 392 + i] = (ndst[i] - m) * rs * ra_g[c] + ra_b[c];
  }
}

// ---------------------------------------------------------------------------
// k_pos: per-(b,p) LN stats + gate softmax. grid(7,32), block 256.
// ---------------------------------------------------------------------------
__global__ __launch_bounds__(256) void k_pos(
    const float* __restrict__ x, const float* __restrict__ normed,
    const float* __restrict__ gate_w, const float* __restrict__ gate_b,
    float* __restrict__ gates_g, float* __restrict__ lnm_g, float* __restrict__ lnr_g)
{
  int pc = blockIdx.x, b = blockIdx.y;
  __shared__ float gw[1024];
  for (int i = threadIdx.x; i < 1024; i += 256) gw[i] = gate_w[i];
  __syncthreads();
  int wv = threadIdx.x >> 6, lane = threadIdx.x & 63;
  for (int pi = wv; pi < 7; pi += 4){
    int p = pc * 7 + pi;
    const float* nb = normed + (size_t)b * 12544 + p;
    const float* xb = x + (size_t)b * 12544 + p;
    float s = 0.f, ss = 0.f, g0 = 0.f, g1 = 0.f, g2 = 0.f, g3 = 0.f;
    for (int c = lane; c < 256; c += 64){
      float nv = nb[c * 49];
      float xv = xb[c * 49];
      s += nv; ss += nv * nv;
      g0 += xv * gw[c]; g1 += xv * gw[256 + c];
      g2 += xv * gw[512 + c]; g3 += xv * gw[768 + c];
    }
    for (int off = 32; off; off >>= 1){
      s += __shfl_down(s, off); ss += __shfl_down(ss, off);
      g0 += __shfl_down(g0, off); g1 += __shfl_down(g1, off);
      g2 += __shfl_down(g2, off); g3 += __shfl_down(g3, off);
    }
    if (lane == 0){
      float mu = s / 256.f;
      lnm_g[b * 49 + p] = mu;
      lnr_g[b * 49 + p] = rsqrtf(ss / 256.f - mu * mu + EPS);
      g0 += gate_b[0]; g1 += gate_b[1]; g2 += gate_b[2]; g3 += gate_b[3];
      float mx = fmaxf(fmaxf(g0, g1), fmaxf(g2, g3));
      float e0 = __expf(g0 - mx), e1 = __expf(g1 - mx), e2 = __expf(g2 - mx), e3 = __expf(g3 - mx);
      float inv = 1.f / (e0 + e1 + e2 + e3);
      float* gg = gates_g + (size_t)b * 196 + p;
      gg[0] = e0 * inv; gg[49] = e1 * inv; gg[98] = e2 * inv; gg[147] = e3 * inv;
    }
  }
}

// ---------------------------------------------------------------------------
// k_h1aw: x<7 -> h1 (LDS GEMM); x==7 -> aw MLP. grid(8,32).
// ---------------------------------------------------------------------------
__global__ __launch_bounds__(256) void k_h1aw(
    const float* __restrict__ normed, const float* __restrict__ sa_w1, const float* __restrict__ sa_b1,
    const float* __restrict__ ap_w1, const float* __restrict__ ap_b1,
    const float* __restrict__ ap_w2, const float* __restrict__ ap_b2,
    const float* __restrict__ gap_g,
    float* __restrict__ h1_g, float* __restrict__ aw_g)
{
  int xb2 = blockIdx.x, b = blockIdx.y;
  int t = threadIdx.x;
  if (xb2 == 7){
    __shared__ float gaps[256], h[128], lg[16];
    gaps[t] = gap_g[b * 256 + t];
    __syncthreads();
    if (t < 128){
      float s = ap_b1[t];
      const float* wr = ap_w1 + t * 256;
      #pragma unroll 4
      for (int c = 0; c < 256; c++) s += gaps[c] * wr[c];
      h[t] = fmaxf(s, 0.f);
    }
    __syncthreads();
    if (t < 16){
      float s = ap_b2[t];
      const float* wr = ap_w2 + t * 128;
      #pragma unroll 4
      for (int o = 0; o < 128; o++) s += h[o] * wr[o];
      lg[t] = s;
    }
    __syncthreads();
    if (t == 0){
      float mx = -1e30f;
      for (int k = 0; k < 16; k++) mx = fmaxf(mx, lg[k]);
      float e[16], sm = 0.f;
      for (int k = 0; k < 16; k++){ e[k] = __expf(lg[k] - mx); sm += e[k]; }
      float inv = 1.f / sm;
      for (int k = 0; k < 16; k++) aw_g[b * 16 + k] = e[k] * inv;
    }
    return;
  }
  __shared__ float w1t[256 * 33];
  __shared__ float ns2[256 * 7];
  int p0 = xb2 * 7;
  for (int i = t; i < 8192; i += 256){
    int o = i >> 8, c = i & 255;
    w1t[c * 33 + o] = sa_w1[i];
  }
  for (int i = t; i < 1792; i += 256){
    int c = i / 7, pl = i - c * 7;
    ns2[i] = normed[(size_t)b * 12544 + c * 49 + p0 + pl];
  }
  __syncthreads();
  if (t < 224){
    int pl = t >> 5, o = t & 31;
    float s = sa_b1[o];
    #pragma unroll 8
    for (int c = 0; c < 256; c++) s += ns2[c * 7 + pl] * w1t[c * 33 + o];
    h1_g[(size_t)b * 1568 + (p0 + pl) * 32 + o] = fmaxf(s, 0.f);
  }
}

// ---------------------------------------------------------------------------
// k_spatial: tmp = normed*(1+sigmoid(w2@h1+b2)); GN(tmp) -> spatial. grid(8,32)
// ---------------------------------------------------------------------------
__global__ __launch_bounds__(256) void k_spatial(
    const float* __restrict__ normed, const float* __restrict__ h1_g,
    const float* __restrict__ sa_w2, const float* __restrict__ sa_b2,
    const float* __restrict__ sa_g, const float* __restrict__ sa_bb,
    float* __restrict__ spat_g)
{
  int gc = blockIdx.x, b = blockIdx.y;
  __shared__ float h1s[49 * 33];
  __shared__ float w2s[1024];
  int t = threadIdx.x;
  for (int i = t; i < 1568; i += 256){
    int p = i >> 5, o = i & 31;
    h1s[p * 33 + o] = h1_g[(size_t)b * 1568 + i];
  }
  for (int i = t; i < 1024; i += 256) w2s[i] = sa_w2[gc * 1024 + i];
  __syncthreads();
  int wv = t >> 6, lane = t & 63;
  int cg0 = wv * 8;
  const float* nb = normed + (size_t)b * 12544 + (gc * 32 + cg0) * 49;
  float tmp[7];
  float s = 0.f, ss = 0.f;
  #pragma unroll
  for (int j = 0; j < 7; j++){
    int i = lane + 64 * j;
    float v = 0.f;
    if (i < 392){
      int c = i / 49;
      const float* wr = w2s + (cg0 + c) * 32;
      const float* hp = h1s + (i - c * 49) * 33;
      float d = sa_b2[gc * 32 + cg0 + c];
      #pragma unroll
      for (int o = 0; o < 32; o++) d += hp[o] * wr[o];
      v = nb[i] * (1.f + 1.f / (1.f + __expf(-d)));
      s += v; ss += v * v;
    }
    tmp[j] = v;
  }
  for (int off = 32; off; off >>= 1){ s += __shfl_down(s, off); ss += __shfl_down(ss, off); }
  s = __shfl(s, 0); ss = __shfl(ss, 0);
  float m = s / 392.f, rs = rsqrtf(ss / 392.f - m * m + EPS);
  float* sb = spat_g + (size_t)b * 12544 + (gc * 32 + cg0) * 49;
  #pragma unroll
  for (int j = 0; j < 7; j++){
    int i = lane + 64 * j;
    if (i < 392){
      int c = gc * 32 + cg0 + i / 49;
      sb[i] = (tmp[j] - m) * rs * sa_g[c] + sa_bb[c];
    }
  }
}

// ---------------------------------------------------------------------------
// k_weff: Weff[b, j] = sum_k aw[b,k] * W[k, j]  (bf16 out), double-buffered:
// each thread owns two j-chunks; chunk-B loads issued before chunk-A compute
// so HBM reads overlap the FMA+store tail. grid 800.
// ---------------------------------------------------------------------------
__global__ __launch_bounds__(256) void k_weff(
    const float* __restrict__ W, const float* __restrict__ aw, u16* __restrict__ weff)
{
  __shared__ float aws[512];
  for (int i = threadIdx.x; i < 512; i += 256) aws[i] = aw[i];
  size_t j0 = (size_t)blockIdx.x * 1024 + (size_t)threadIdx.x * 4;
  size_t j1 = j0 + 819200;
  float4 wa[16], wb[16];
  #pragma unroll
  for (int k = 0; k < 16; k++)
    wa[k] = *(const float4*)(W + (size_t)k * 1638400 + j0);
  #pragma unroll
  for (int k = 0; k < 16; k++)
    wb[k] = *(const float4*)(W + (size_t)k * 1638400 + j1);
  __syncthreads();
  #pragma unroll 1
  for (int b = 0; b < 32; b++){
    const float* a = aws + b * 16;
    float a0 = 0.f, a1 = 0.f, a2 = 0.f, a3 = 0.f;
    #pragma unroll
    for (int k = 0; k < 16; k++){
      float s = a[k];
      a0 += s * wa[k].x; a1 += s * wa[k].y; a2 += s * wa[k].z; a3 += s * wa[k].w;
    }
    ushort4 o;
    o.x = f2bf(a0); o.y = f2bf(a1); o.z = f2bf(a2); o.w = f2bf(a3);
    *(ushort4*)(weff + (size_t)b * 1638400 + j0) = o;
  }
  #pragma unroll 1
  for (int b = 0; b < 32; b++){
    const float* a = aws + b * 16;
    float a0 = 0.f, a1 = 0.f, a2 = 0.f, a3 = 0.f;
    #pragma unroll
    for (int k = 0; k < 16; k++){
      float s = a[k];
      a0 += s * wb[k].x; a1 += s * wb[k].y; a2 += s * wb[k].z; a3 += s * wb[k].w;
    }
    ushort4 o;
    o.x = f2bf(a0); o.y = f2bf(a1); o.z = f2bf(a2); o.w = f2bf(a3);
    *(ushort4*)(weff + (size_t)b * 1638400 + j1) = o;
  }
}

// ---------------------------------------------------------------------------
// k_im2col: X'[b][p][k'] bf16, k' = ci*25 + sy*5+sx; zero outside image.
// ---------------------------------------------------------------------------
__global__ __launch_bounds__(256) void k_im2col(
    const float* __restrict__ normed, u16* __restrict__ xim)
{
  int p = blockIdx.x, b = blockIdx.y;
  __shared__ u16 row[6400];
  int ci = threadIdx.x;
  int py = p / 7, px = p - py * 7;
  const float* nb = normed + (size_t)b * 12544 + ci * 49;
  u16* rp = row + ci * 25;
  #pragma unroll
  for (int sy = 0; sy < 5; sy++){
    int iy = py + sy - 2;
    #pragma unroll
    for (int sx = 0; sx < 5; sx++){
      int ix = px + sx - 2;
      float v = (iy >= 0 && iy < 7 && ix >= 0 && ix < 7) ? nb[iy * 7 + ix] : 0.f;
      rp[sy * 5 + sx] = f2bf(v);
    }
  }
  __syncthreads();
  const u32* rs = (const u32*)row;
  u32* od = (u32*)(xim + (size_t)(b * 49 + p) * 6400);
  for (int i = threadIdx.x; i < 3200; i += 256) od[i] = rs[i];
}

// ---------------------------------------------------------------------------
// k_conv_mfma: comb_part[kp][b][co][p] = Weff[b] @ X'[b] over k'-slice.
// ---------------------------------------------------------------------------
__global__ __launch_bounds__(256) void k_conv_mfma(
    const u16* __restrict__ weff, const u16* __restrict__ xim, float* __restrict__ partial)
{
  int bx = blockIdx.x, b = blockIdx.y;
  int mblk = bx >> 3, kp = bx & 7;
  int wv = threadIdx.x >> 6, lane = threadIdx.x & 63;
  int lo = lane & 15, hi = lane >> 4;
  int co0 = mblk * 128 + wv * 32;
  const u16* wr0 = weff + (size_t)b * 1638400 + (size_t)(co0 + lo) * 6400 + kp * 800 + hi * 8;
  const u16* wr1 = wr0 + 16 * 6400;
  const u16* xb = xim + (size_t)b * 313600 + (size_t)lo * 6400 + kp * 800 + hi * 8;
  f32x4 acc[2][4];
  #pragma unroll
  for (int mi = 0; mi < 2; mi++)
    #pragma unroll
    for (int pi = 0; pi < 4; pi++) acc[mi][pi] = (f32x4){0.f, 0.f, 0.f, 0.f};
  #pragma unroll 1
  for (int ks = 0; ks < 25; ks++){
    int k0 = ks * 32;
    bf16x8 A0 = *(const bf16x8*)(wr0 + k0);
    bf16x8 A1 = *(const bf16x8*)(wr1 + k0);
    bf16x8 B0 = *(const bf16x8*)(xb + k0);
    bf16x8 B1 = *(const bf16x8*)(xb + 16 * 6400 + k0);
    bf16x8 B2 = *(const bf16x8*)(xb + 32 * 6400 + k0);
    bf16x8 B3 = *(const bf16x8*)(xb + 48 * 6400 + k0);
    acc[0][0] = __builtin_amdgcn_mfma_f32_16x16x32_bf16(A0, B0, acc[0][0], 0, 0, 0);
    acc[0][1] = __builtin_amdgcn_mfma_f32_16x16x32_bf16(A0, B1, acc[0][1], 0, 0, 0);
    acc[0][2] = __builtin_amdgcn_mfma_f32_16x16x32_bf16(A0, B2, acc[0][2], 0, 0, 0);
    acc[0][3] = __builtin_amdgcn_mfma_f32_16x16x32_bf16(A0, B3, acc[0][3], 0, 0, 0);
    acc[1][0] = __builtin_amdgcn_mfma_f32_16x16x32_bf16(A1, B0, acc[1][0], 0, 0, 0);
    acc[1][1] = __builtin_amdgcn_mfma_f32_16x16x32_bf16(A1, B1, acc[1][1], 0, 0, 0);
    acc[1][2] = __builtin_amdgcn_mfma_f32_16x16x32_bf16(A1, B2, acc[1][2], 0, 0, 0);
    acc[1][3] = __builtin_amdgcn_mfma_f32_16x16x32_bf16(A1, B3, acc[1][3], 0, 0, 0);
  }
  float* pb = partial + ((size_t)kp * 32 + b) * 12544;
  #pragma unroll
  for (int mi = 0; mi < 2; mi++){
    #pragma unroll
    for (int pi = 0; pi < 4; pi++){
      int p = pi * 16 + lo;
      if (p < 49){
        #pragma unroll
        for (int r = 0; r < 4; r++){
          int co = co0 + mi * 16 + hi * 4 + r;
          pb[co * 49 + p] = acc[mi][pi][r];
        }
      }
    }
  }
}

// k_conv_reduce: comb = sum of 8 k-partials
__global__ __launch_bounds__(256) void k_conv_reduce(
    const float* __restrict__ part, float* __restrict__ comb)
{
  int i = blockIdx.x * 256 + threadIdx.x;
  if (i >= 100352) return;
  float a0 = 0.f, a1 = 0.f, a2 = 0.f, a3 = 0.f;
  #pragma unroll
  for (int p = 0; p < 8; p++){
    float4 v = ((const float4*)part)[(size_t)p * 100352 + i];
    a0 += v.x; a1 += v.y; a2 += v.z; a3 += v.w;
  }
  float4 o; o.x = a0; o.y = a1; o.z = a2; o.w = a3;
  ((float4*)comb)[i] = o;
}

// ---------------------------------------------------------------------------
// mfma_gemm_dev: per-wave 32m x 16p tile via mfma_f32_16x16x32_bf16.
// ---------------------------------------------------------------------------
__device__ __forceinline__ void mfma_gemm_dev(
    const float* __restrict__ W, const float* __restrict__ bias,
    const float* __restrict__ act, const float* __restrict__ res,
    float* __restrict__ out, int M, int K, int m0blk, int p0, int b,
    const float* __restrict__ lnm, const float* __restrict__ lnr,
    const float* __restrict__ lng, const float* __restrict__ lnb)
{
  int wv = threadIdx.x >> 6, lane = threadIdx.x & 63;
  int lo = lane & 15, hi = lane >> 4;
  int m0 = m0blk + wv * 32;
  int p = p0 + lo;
  bool pok = p < 49;
  const float* ab = act + (size_t)b * K * 49;
  float lm = 0.f, lr = 0.f;
  if (lng && pok){ lm = lnm[p]; lr = lnr[p]; }
  f32x4 acc0 = {0.f, 0.f, 0.f, 0.f};
  f32x4 acc1 = {0.f, 0.f, 0.f, 0.f};
  const float* wr0 = W + (size_t)(m0 + lo) * K + hi * 8;
  const float* wr1 = W + (size_t)(m0 + 16 + lo) * K + hi * 8;
  for (int k0 = 0; k0 < K; k0 += 32){
    int kb = k0 + hi * 8;
    float4 a0lo = *(const float4*)(wr0 + k0);
    float4 a0hi = *(const float4*)(wr0 + k0 + 4);
    float4 a1lo = *(const float4*)(wr1 + k0);
    float4 a1hi = *(const float4*)(wr1 + k0 + 4);
    float bv[8];
    if (pok){
      const float* ap = ab + (size_t)kb * 49 + p;
      #pragma unroll
      for (int i = 0; i < 8; i++) bv[i] = ap[i * 49];
      if (lng){
        #pragma unroll
        for (int i = 0; i < 8; i++) bv[i] = (bv[i] - lm) * lr * lng[kb + i] + lnb[kb + i];
      }
    } else {
      #pragma unroll
      for (int i = 0; i < 8; i++) bv[i] = 0.f;
    }
    BF8 A0, A1, B;
    A0.u[0] = pk2(a0lo.x, a0lo.y); A0.u[1] = pk2(a0lo.z, a0lo.w);
    A0.u[2] = pk2(a0hi.x, a0hi.y); A0.u[3] = pk2(a0hi.z, a0hi.w);
    A1.u[0] = pk2(a1lo.x, a1lo.y); A1.u[1] = pk2(a1lo.z, a1lo.w);
    A1.u[2] = pk2(a1hi.x, a1hi.y); A1.u[3] = pk2(a1hi.z, a1hi.w);
    B.u[0] = pk2(bv[0], bv[1]); B.u[1] = pk2(bv[2], bv[3]);
    B.u[2] = pk2(bv[4], bv[5]); B.u[3] = pk2(bv[6], bv[7]);
    acc0 = __builtin_amdgcn_mfma_f32_16x16x32_bf16(A0.v, B.v, acc0, 0, 0, 0);
    acc1 = __builtin_amdgcn_mfma_f32_16x16x32_bf16(A1.v, B.v, acc1, 0, 0, 0);
  }
  if (pok){
    #pragma unroll
    for (int r = 0; r < 4; r++){
      int m = m0 + hi * 4 + r;
      size_t idx = ((size_t)b * M + m) * 49 + p;
      float v = acc0[r] + (bias ? bias[m] : 0.f);
      if (res) v += res[idx];
      out[idx] = v;
      int m2 = m + 16;
      size_t idx2 = idx + 16 * 49;
      float v2 = acc1[r] + (bias ? bias[m2] : 0.f);
      if (res) v2 += res[idx2];
      out[idx2] = v2;
    }
  }
}

// merged qkv: bx<24 -> ra_qkv (act=xr); else aa_qkv (act=LN(normed) fused)
__global__ __launch_bounds__(256) void k_qkv(
    const float* __restrict__ ra_w, const float* __restrict__ aa_w,
    const float* __restrict__ xr, const float* __restrict__ normed,
    const float* __restrict__ lnm, const float* __restrict__ lnr,
    const float* __restrict__ ln_g, const float* __restrict__ ln_b,
    float* __restrict__ ra_qkv, float* __restrict__ aa_qkv)
{
  int bx = blockIdx.x, b = blockIdx.y;
  if (bx < 24){
    int m0 = (bx >> 2) * 128, p0 = (bx & 3) * 16;
    mfma_gemm_dev(ra_w, nullptr, xr, nullptr, ra_qkv, 768, 256, m0, p0, b,
                  nullptr, nullptr, nullptr, nullptr);
  } else {
    int bx2 = bx - 24;
    int m0 = (bx2 >> 2) * 128, p0 = (bx2 & 3) * 16;
    mfma_gemm_dev(aa_w, nullptr, normed, nullptr, aa_qkv, 1536, 256, m0, p0, b,
                  lnm + b * 49, lnr + b * 49, ln_g, ln_b);
  }
}

// merged projections: bx<8 ra_proj, <16 aa_out (K=512), else ad_proj
__global__ __launch_bounds__(256) void k_proj3(
    const float* __restrict__ ra_pw, const float* __restrict__ ra_pb, const float* __restrict__ r0,
    const float* __restrict__ aa_ow, const float* __restrict__ aa_ob, const float* __restrict__ aa_o,
    const float* __restrict__ ad_pw, const float* __restrict__ ad_pb, const float* __restrict__ comb,
    const float* __restrict__ normed,
    float* __restrict__ rotf, float* __restrict__ angf, float* __restrict__ adpf)
{
  int bx = blockIdx.x, b = blockIdx.y;
  if (bx < 8){
    int m0 = (bx >> 2) * 128, p0 = (bx & 3) * 16;
    mfma_gemm_dev(ra_pw, ra_pb, r0, normed, rotf, 256, 256, m0, p0, b,
                  nullptr, nullptr, nullptr, nullptr);
  } else if (bx < 16){
    int bx2 = bx - 8;
    int m0 = (bx2 >> 2) * 128, p0 = (bx2 & 3) * 16;
    mfma_gemm_dev(aa_ow, aa_ob, aa_o, normed, angf, 256, 512, m0, p0, b,
                  nullptr, nullptr, nullptr, nullptr);
  } else {
    int bx2 = bx - 16;
    int m0 = (bx2 >> 2) * 128, p0 = (bx2 & 3) * 16;
    mfma_gemm_dev(ad_pw, ad_pb, comb, normed, adpf, 256, 256, m0, p0, b,
                  nullptr, nullptr, nullptr, nullptr);
  }
}

// ---------------------------------------------------------------------------
// k_final: out = proj_w @ fused + proj_b + x, with fused = gated 4-branch sum
// computed on the fly in the B-staging (no materialized `fused` buffer).
// ---------------------------------------------------------------------------
__global__ __launch_bounds__(256) void k_final(
    const float* __restrict__ proj_w, const float* __restrict__ proj_b,
    const float* __restrict__ spat, const float* __restrict__ rotf,
    const float* __restrict__ angf, const float* __restrict__ adpf,
    const float* __restrict__ gates, const float* __restrict__ x,
    float* __restrict__ out)
{
  int bx = blockIdx.x, b = blockIdx.y;
  int wv = threadIdx.x >> 6, lane = threadIdx.x & 63;
  int lo = lane & 15, hi = lane >> 4;
  int m0 = (bx >> 2) * 128 + wv * 32;
  int p0 = (bx & 3) * 16;
  int p = p0 + lo;
  bool pok = p < 49;
  float g0 = 0.f, g1 = 0.f, g2 = 0.f, g3 = 0.f;
  if (pok){
    const float* g = gates + (size_t)b * 196 + p;
    g0 = g[0]; g1 = g[49]; g2 = g[98]; g3 = g[147];
  }
  size_t boff = (size_t)b * 12544;
  f32x4 acc0 = {0.f, 0.f, 0.f, 0.f};
  f32x4 acc1 = {0.f, 0.f, 0.f, 0.f};
  const float* wr0 = proj_w + (size_t)(m0 + lo) * 256 + hi * 8;
  const float* wr1 = wr0 + 16 * 256;
  for (int k0 = 0; k0 < 256; k0 += 32){
    int kb = k0 + hi * 8;
    float4 a0lo = *(const float4*)(wr0 + k0);
    float4 a0hi = *(const float4*)(wr0 + k0 + 4);
    float4 a1lo = *(const float4*)(wr1 + k0);
    float4 a1hi = *(const float4*)(wr1 + k0 + 4);
    float bv[8];
    if (pok){
      size_t base = boff + (size_t)kb * 49 + p;
      #pragma unroll
      for (int i = 0; i < 8; i++){
        size_t idx = base + (size_t)i * 49;
        bv[i] = spat[idx] * g0 + rotf[idx] * g1 + angf[idx] * g2 + adpf[idx] * g3;
      }
    } else {
      #pragma unroll
      for (int i = 0; i < 8; i++) bv[i] = 0.f;
    }
    BF8 A0, A1, B;
    A0.u[0] = pk2(a0lo.x, a0lo.y); A0.u[1] = pk2(a0lo.z, a0lo.w);
    A0.u[2] = pk2(a0hi.x, a0hi.y); A0.u[3] = pk2(a0hi.z, a0hi.w);
    A1.u[0] = pk2(a1lo.x, a1lo.y); A1.u[1] = pk2(a1lo.z, a1lo.w);
    A1.u[2] = pk2(a1hi.x, a1hi.y); A1.u[3] = pk2(a1hi.z, a1hi.w);
    B.u[0] = pk2(bv[0], bv[1]); B.u[1] = pk2(bv[2], bv[3]);
    B.u[2] = pk2(bv[4], bv[5]); B.u[3] = pk2(bv[6], bv[7]);
    acc0 = __builtin_amdgcn_mfma_f32_16x16x32_bf16(A0.v, B.v, acc0, 0, 0, 0);
    acc1 = __builtin_amdgcn_mfma_f32_16x16x32_bf16(A1.v, B.v, acc1, 0, 0, 0);
  }
  if (pok){
    #pragma unroll
    for (int r = 0; r < 4; r++){
      int m = m0 + hi * 4 + r;
      size_t idx = boff + (size_t)m * 49 + p;
      out[idx] = acc0[r] + proj_b[m] + x[idx];
      int m2 = m + 16;
      size_t idx2 = idx + 16 * 49;
      out[idx2] = acc1[r] + proj_b[m2] + x[idx2];
    }
  }
}

// ---------------------------------------------------------------------------
// k_attn: x<8 -> ra head (d=32, no bias); else aa head (d=64, rel-pos bias)
// softmax: 4 lanes per row + shfl_xor reduce (wave-parallel).
// ---------------------------------------------------------------------------
__device__ __forceinline__ void softmax_rows(float* sc, int tid)
{
  int r = tid >> 2, q = tid & 3;
  if (r < 49){
    float* row = sc + r * 52;
    float mx = -1e30f;
    for (int j = q; j < 49; j += 4) mx = fmaxf(mx, row[j]);
    mx = fmaxf(mx, __shfl_xor(mx, 1));
    mx = fmaxf(mx, __shfl_xor(mx, 2));
    float sm = 0.f;
    for (int j = q; j < 49; j += 4){ float e = __expf(row[j] - mx); row[j] = e; sm += e; }
    sm += __shfl_xor(sm, 1);
    sm += __shfl_xor(sm, 2);
    float inv = 1.f / sm;
    for (int j = q; j < 49; j += 4) row[j] *= inv;
  }
}

__global__ __launch_bounds__(256) void k_attn(
    const float* __restrict__ ra_qkv, const float* __restrict__ aa_qkv,
    const float* __restrict__ relpos,
    float* __restrict__ r0, float* __restrict__ ao)
{
  __shared__ float sm[3 * 49 * 65 + 49 * 52];
  int xb2 = blockIdx.x, b = blockIdx.y;
  if (xb2 < 8){
    int hd = xb2;
    float* qs = sm; float* ks = sm + 1617; float* vs = sm + 3234; float* sc = sm + 4851;
    const float* base = ra_qkv + (size_t)b * 768 * 49;
    for (int i = threadIdx.x; i < 1568; i += 256){
      int d = i / 49, tok = i - d * 49;
      qs[tok * 33 + d] = base[(hd * 32 + d) * 49 + tok];
      ks[tok * 33 + d] = base[(256 + hd * 32 + d) * 49 + tok];
      vs[tok * 33 + d] = base[(512 + hd * 32 + d) * 49 + tok];
    }
    __syncthreads();
    const float scale = 0.17677669529663687f;
    for (int it = threadIdx.x; it < 2401; it += 256){
      int i = it / 49, j = it - i * 49;
      float s = 0.f;
      #pragma unroll
      for (int d = 0; d < 32; d++) s += qs[i * 33 + d] * ks[j * 33 + d];
      sc[i * 52 + j] = s * scale;
    }
    __syncthreads();
    softmax_rows(sc, threadIdx.x);
    __syncthreads();
    for (int it = threadIdx.x; it < 1568; it += 256){
      int d = it / 49, i = it - d * 49;
      float o = 0.f;
      for (int j = 0; j < 49; j++) o += sc[i * 52 + j] * vs[j * 33 + d];
      r0[((size_t)b * 256 + hd * 32 + d) * 49 + i] = o;
    }
  } else {
    int hd = xb2 - 8;
    float* qs = sm; float* ks = sm + 3185; float* vs = sm + 6370; float* sc = sm + 9555;
    const float* base = aa_qkv + (size_t)b * 1536 * 49;
    for (int i = threadIdx.x; i < 3136; i += 256){
      int d = i / 49, tok = i - d * 49;
      qs[tok * 65 + d] = base[(hd * 64 + d) * 49 + tok];
      ks[tok * 65 + d] = base[(512 + hd * 64 + d) * 49 + tok];
      vs[tok * 65 + d] = base[(1024 + hd * 64 + d) * 49 + tok];
    }
    __syncthreads();
    for (int it = threadIdx.x; it < 2401; it += 256){
      int i = it / 49, j = it - i * 49;
      float s = 0.f;
      #pragma unroll
      for (int d = 0; d < 64; d++) s += qs[i * 65 + d] * ks[j * 65 + d];
      int dy = j / 7 - i / 7 + 6, dx = j % 7 - i % 7 + 6;
      sc[i * 52 + j] = s * 0.125f + relpos[(dy * 13 + dx) * 8 + hd];
    }
    __syncthreads();
    softmax_rows(sc, threadIdx.x);
    __syncthreads();
    for (int it = threadIdx.x; it < 3136; it += 256){
      int d = it / 49, i = it - d * 49;
      float o = 0.f;
      for (int j = 0; j < 49; j++) o += sc[i * 52 + j] * vs[j * 65 + d];
      ao[((size_t)b * 512 + hd * 64 + d) * 49 + i] = o;
    }
  }
}

// ---------------------------------------------------------------------------
extern "C" void kernel_launch(void* const* d_in, const int* in_sizes, int n_in,
                              void* d_out, int out_size, void* d_ws, size_t ws_size,
                              hipStream_t stream)
{
  const float* x        = (const float*)d_in[0];
  const float* gn_g     = (const float*)d_in[1];
  const float* gn_b     = (const float*)d_in[2];
  const float* sa_w1    = (const float*)d_in[3];
  const float* sa_b1    = (const float*)d_in[4];
  const float* sa_w2    = (const float*)d_in[5];
  const float* sa_b2    = (const float*)d_in[6];
  const float* sa_gn_g  = (const float*)d_in[7];
  const float* sa_gn_b  = (const float*)d_in[8];
  const float* ra_gn_g  = (const float*)d_in[9];
  const float* ra_gn_b  = (const float*)d_in[10];
  const float* ra_qkv_w = (const float*)d_in[11];
  const float* ra_proj_w= (const float*)d_in[12];
  const float* ra_proj_b= (const float*)d_in[13];
  const float* aa_ln_g  = (const float*)d_in[14];
  const float* aa_ln_b  = (const float*)d_in[15];
  const float* aa_qkv_w = (const float*)d_in[16];
  const float* aa_relpos= (const float*)d_in[17];
  const float* aa_out_w = (const float*)d_in[18];
  const float* aa_out_b = (const float*)d_in[19];
  const float* ad_dir_w = (const float*)d_in[20];
  const float* ad_ap_w1 = (const float*)d_in[21];
  const float* ad_ap_b1 = (const float*)d_in[22];
  const float* ad_ap_w2 = (const float*)d_in[23];
  const float* ad_ap_b2 = (const float*)d_in[24];
  const float* ad_proj_w= (const float*)d_in[25];
  const float* ad_proj_b= (const float*)d_in[26];
  const float* gate_w   = (const float*)d_in[27];
  const float* gate_b   = (const float*)d_in[28];
  const float* proj_w   = (const float*)d_in[29];
  const float* proj_b   = (const float*)d_in[30];

  char* ws = (char*)d_ws;
  float* normed    = (float*)(ws + 0);
  float* xr        = (float*)(ws + 1605632);
  float* h1_g      = (float*)(ws + 3211264);
  float* lnm       = (float*)(ws + 3420160);
  float* lnr       = (float*)(ws + 3426560);
  float* spatial   = (float*)(ws + 4816896);
  float* rotf      = (float*)(ws + 6422528);
  float* anglef    = (float*)(ws + 8028160);
  float* adaptf    = (float*)(ws + 9633792);
  float* r0        = (float*)(ws + 12845056);
  float* gap       = (float*)(ws + 14450688);
  float* aw        = (float*)(ws + 14483456);
  float* gates     = (float*)(ws + 14485504);
  float* ra_qkv    = (float*)(ws + 14510592);
  float* aa_qkv    = (float*)(ws + 19327488);
  float* aa_o      = (float*)(ws + 28961280);
  float* comb      = (float*)(ws + 32172544);
  float* partial   = (float*)(ws + 33778176);   // 12,845,056 B
  u16*   xim       = (u16*)  (ws + 46623232);   // 20,070,400 B
  u16*   weff      = (u16*)  (ws + 66693632);   // 104,857,600 B

  float* out = (float*)d_out;

  k_prep1<<<dim3(8, 32), 256, 0, stream>>>(x, gn_g, gn_b, ra_gn_g, ra_gn_b, normed, xr, gap);
  k_pos<<<dim3(7, 32), 256, 0, stream>>>(x, normed, gate_w, gate_b, gates, lnm, lnr);
  k_h1aw<<<dim3(8, 32), 256, 0, stream>>>(normed, sa_w1, sa_b1,
                                          ad_ap_w1, ad_ap_b1, ad_ap_w2, ad_ap_b2,
                                          gap, h1_g, aw);
  k_spatial<<<dim3(8, 32), 256, 0, stream>>>(normed, h1_g, sa_w2, sa_b2, sa_gn_g, sa_gn_b, spatial);
  k_weff<<<dim3(800), 256, 0, stream>>>(ad_dir_w, aw, weff);
  k_im2col<<<dim3(49, 32), 256, 0, stream>>>(normed, xim);
  k_qkv<<<dim3(72, 32), 256, 0, stream>>>(ra_qkv_w, aa_qkv_w, xr, normed,
                                          lnm, lnr, aa_ln_g, aa_ln_b, ra_qkv, aa_qkv);
  k_attn<<<dim3(16, 32), 256, 0, stream>>>(ra_qkv, aa_qkv, aa_relpos, r0, aa_o);
  k_conv_mfma<<<dim3(16, 32), 256, 0, stream>>>(weff, xim, partial);
  k_conv_reduce<<<dim3(392), 256, 0, stream>>>(partial, comb);
  k_proj3<<<dim3(24, 32), 256, 0, stream>>>(ra_proj_w, ra_proj_b, r0,
                                            aa_out_w, aa_out_b, aa_o,
                                            ad_proj_w, ad_proj_b, comb,
                                            normed, rotf, anglef, adaptf);
  k_final<<<dim3(8, 32), 256, 0, stream>>>(proj_w, proj_b, spatial, rotf, anglef, adaptf,
                                           gates, x, out);
}

// Round 8
// 292.432 us; speedup vs baseline: 1.0285x; 1.0285x over previous
//
#include <hip/hip_runtime.h>

#define EPS 1e-5f
typedef unsigned short u16;
typedef unsigned int u32;
typedef float f32x4 __attribute__((ext_vector_type(4)));
typedef short bf16x8 __attribute__((ext_vector_type(8)));

__device__ __forceinline__ float bf2f(u16 h){
  return __uint_as_float(((u32)h) << 16);
}
__device__ __forceinline__ u16 f2bf(float f){
  u32 u = __float_as_uint(f);
  u += 0x7fffu + ((u >> 16) & 1u);
  return (u16)(u >> 16);
}
__device__ __forceinline__ u32 pk2(float lo, float hi){
  return ((u32)f2bf(hi) << 16) | (u32)f2bf(lo);
}
union BF8 { bf16x8 v; u32 u[4]; };

// ---------------------------------------------------------------------------
// k_prep1: GN(x)->normed, GN(normed)->xr, gap (per-channel mean of normed)
// ---------------------------------------------------------------------------
__global__ __launch_bounds__(256) void k_prep1(
    const float* __restrict__ x, const float* __restrict__ gn_g, const float* __restrict__ gn_b,
    const float* __restrict__ ra_g, const float* __restrict__ ra_b,
    float* __restrict__ normed, float* __restrict__ xr, float* __restrict__ gap)
{
  int ch = blockIdx.x, b = blockIdx.y;
  int c0 = ch * 32;
  __shared__ float xs[1568], ns[1568];
  const float* xb = x + ((size_t)b * 256 + c0) * 49;
  for (int i = threadIdx.x; i < 1568; i += 256) xs[i] = xb[i];
  __syncthreads();
  int wv = threadIdx.x >> 6, lane = threadIdx.x & 63;
  const float* gsrc = xs + wv * 392;
  float* ndst = ns + wv * 392;
  float s = 0.f, ss = 0.f;
  for (int i = lane; i < 392; i += 64){ float v = gsrc[i]; s += v; ss += v * v; }
  for (int off = 32; off; off >>= 1){ s += __shfl_down(s, off); ss += __shfl_down(ss, off); }
  s = __shfl(s, 0); ss = __shfl(ss, 0);
  float m = s / 392.f, rs = rsqrtf(ss / 392.f - m * m + EPS);
  for (int i = lane; i < 392; i += 64){
    int c = c0 + wv * 8 + i / 49;
    ndst[i] = (gsrc[i] - m) * rs * gn_g[c] + gn_b[c];
  }
  __syncthreads();
  float* nb = normed + ((size_t)b * 256 + c0) * 49;
  for (int i = threadIdx.x; i < 1568; i += 256) nb[i] = ns[i];
  if (threadIdx.x < 32){
    float g2 = 0.f; const float* rp = ns + threadIdx.x * 49;
    for (int p = 0; p < 49; p++) g2 += rp[p];
    gap[(size_t)b * 256 + c0 + threadIdx.x] = g2 * (1.f / 49.f);
  }
  s = 0.f; ss = 0.f;
  for (int i = lane; i < 392; i += 64){ float v = ndst[i]; s += v; ss += v * v; }
  for (int off = 32; off; off >>= 1){ s += __shfl_down(s, off); ss += __shfl_down(ss, off); }
  s = __shfl(s, 0); ss = __shfl(ss, 0);
  m = s / 392.f; rs = rsqrtf(ss / 392.f - m * m + EPS);
  float* xrb = xr + ((size_t)b * 256 + c0) * 49;
  for (int i = lane; i < 392; i += 64){
    int c = c0 + wv * 8 + i / 49;
    xrb[wv * 392 + i] = (ndst[i] - m) * rs * ra_g[c] + ra_b[c];
  }
}

// ---------------------------------------------------------------------------
// k_pos: per-(b,p) LN stats + gate softmax. grid(7,32), block 256.
// ---------------------------------------------------------------------------
__global__ __launch_bounds__(256) void k_pos(
    const float* __restrict__ x, const float* __restrict__ normed,
    const float* __restrict__ gate_w, const float* __restrict__ gate_b,
    float* __restrict__ gates_g, float* __restrict__ lnm_g, float* __restrict__ lnr_g)
{
  int pc = blockIdx.x, b = blockIdx.y;
  __shared__ float gw[1024];
  for (int i = threadIdx.x; i < 1024; i += 256) gw[i] = gate_w[i];
  __syncthreads();
  int wv = threadIdx.x >> 6, lane = threadIdx.x & 63;
  for (int pi = wv; pi < 7; pi += 4){
    int p = pc * 7 + pi;
    const float* nb = normed + (size_t)b * 12544 + p;
    const float* xb = x + (size_t)b * 12544 + p;
    float s = 0.f, ss = 0.f, g0 = 0.f, g1 = 0.f, g2 = 0.f, g3 = 0.f;
    for (int c = lane; c < 256; c += 64){
      float nv = nb[c * 49];
      float xv = xb[c * 49];
      s += nv; ss += nv * nv;
      g0 += xv * gw[c]; g1 += xv * gw[256 + c];
      g2 += xv * gw[512 + c]; g3 += xv * gw[768 + c];
    }
    for (int off = 32; off; off >>= 1){
      s += __shfl_down(s, off); ss += __shfl_down(ss, off);
      g0 += __shfl_down(g0, off); g1 += __shfl_down(g1, off);
      g2 += __shfl_down(g2, off); g3 += __shfl_down(g3, off);
    }
    if (lane == 0){
      float mu = s / 256.f;
      lnm_g[b * 49 + p] = mu;
      lnr_g[b * 49 + p] = rsqrtf(ss / 256.f - mu * mu + EPS);
      g0 += gate_b[0]; g1 += gate_b[1]; g2 += gate_b[2]; g3 += gate_b[3];
      float mx = fmaxf(fmaxf(g0, g1), fmaxf(g2, g3));
      float e0 = __expf(g0 - mx), e1 = __expf(g1 - mx), e2 = __expf(g2 - mx), e3 = __expf(g3 - mx);
      float inv = 1.f / (e0 + e1 + e2 + e3);
      float* gg = gates_g + (size_t)b * 196 + p;
      gg[0] = e0 * inv; gg[49] = e1 * inv; gg[98] = e2 * inv; gg[147] = e3 * inv;
    }
  }
}

// ---------------------------------------------------------------------------
// k_h1aw: x<7 -> h1 (LDS GEMM); x==7 -> aw MLP. grid(8,32).
// ---------------------------------------------------------------------------
__global__ __launch_bounds__(256) void k_h1aw(
    const float* __restrict__ normed, const float* __restrict__ sa_w1, const float* __restrict__ sa_b1,
    const float* __restrict__ ap_w1, const float* __restrict__ ap_b1,
    const float* __restrict__ ap_w2, const float* __restrict__ ap_b2,
    const float* __restrict__ gap_g,
    float* __restrict__ h1_g, float* __restrict__ aw_g)
{
  int xb2 = blockIdx.x, b = blockIdx.y;
  int t = threadIdx.x;
  if (xb2 == 7){
    __shared__ float gaps[256], h[128], lg[16];
    gaps[t] = gap_g[b * 256 + t];
    __syncthreads();
    if (t < 128){
      float s = ap_b1[t];
      const float* wr = ap_w1 + t * 256;
      #pragma unroll 4
      for (int c = 0; c < 256; c++) s += gaps[c] * wr[c];
      h[t] = fmaxf(s, 0.f);
    }
    __syncthreads();
    if (t < 16){
      float s = ap_b2[t];
      const float* wr = ap_w2 + t * 128;
      #pragma unroll 4
      for (int o = 0; o < 128; o++) s += h[o] * wr[o];
      lg[t] = s;
    }
    __syncthreads();
    if (t == 0){
      float mx = -1e30f;
      for (int k = 0; k < 16; k++) mx = fmaxf(mx, lg[k]);
      float e[16], sm = 0.f;
      for (int k = 0; k < 16; k++){ e[k] = __expf(lg[k] - mx); sm += e[k]; }
      float inv = 1.f / sm;
      for (int k = 0; k < 16; k++) aw_g[b * 16 + k] = e[k] * inv;
    }
    return;
  }
  __shared__ float w1t[256 * 33];
  __shared__ float ns2[256 * 7];
  int p0 = xb2 * 7;
  for (int i = t; i < 8192; i += 256){
    int o = i >> 8, c = i & 255;
    w1t[c * 33 + o] = sa_w1[i];
  }
  for (int i = t; i < 1792; i += 256){
    int c = i / 7, pl = i - c * 7;
    ns2[i] = normed[(size_t)b * 12544 + c * 49 + p0 + pl];
  }
  __syncthreads();
  if (t < 224){
    int pl = t >> 5, o = t & 31;
    float s = sa_b1[o];
    #pragma unroll 8
    for (int c = 0; c < 256; c++) s += ns2[c * 7 + pl] * w1t[c * 33 + o];
    h1_g[(size_t)b * 1568 + (p0 + pl) * 32 + o] = fmaxf(s, 0.f);
  }
}

// ---------------------------------------------------------------------------
// k_spatial: tmp = normed*(1+sigmoid(w2@h1+b2)); GN(tmp) -> spatial. grid(8,32)
// ---------------------------------------------------------------------------
__global__ __launch_bounds__(256) void k_spatial(
    const float* __restrict__ normed, const float* __restrict__ h1_g,
    const float* __restrict__ sa_w2, const float* __restrict__ sa_b2,
    const float* __restrict__ sa_g, const float* __restrict__ sa_bb,
    float* __restrict__ spat_g)
{
  int gc = blockIdx.x, b = blockIdx.y;
  __shared__ float h1s[49 * 33];
  __shared__ float w2s[1024];
  int t = threadIdx.x;
  for (int i = t; i < 1568; i += 256){
    int p = i >> 5, o = i & 31;
    h1s[p * 33 + o] = h1_g[(size_t)b * 1568 + i];
  }
  for (int i = t; i < 1024; i += 256) w2s[i] = sa_w2[gc * 1024 + i];
  __syncthreads();
  int wv = t >> 6, lane = t & 63;
  int cg0 = wv * 8;
  const float* nb = normed + (size_t)b * 12544 + (gc * 32 + cg0) * 49;
  float tmp[7];
  float s = 0.f, ss = 0.f;
  #pragma unroll
  for (int j = 0; j < 7; j++){
    int i = lane + 64 * j;
    float v = 0.f;
    if (i < 392){
      int c = i / 49;
      const float* wr = w2s + (cg0 + c) * 32;
      const float* hp = h1s + (i - c * 49) * 33;
      float d = sa_b2[gc * 32 + cg0 + c];
      #pragma unroll
      for (int o = 0; o < 32; o++) d += hp[o] * wr[o];
      v = nb[i] * (1.f + 1.f / (1.f + __expf(-d)));
      s += v; ss += v * v;
    }
    tmp[j] = v;
  }
  for (int off = 32; off; off >>= 1){ s += __shfl_down(s, off); ss += __shfl_down(ss, off); }
  s = __shfl(s, 0); ss = __shfl(ss, 0);
  float m = s / 392.f, rs = rsqrtf(ss / 392.f - m * m + EPS);
  float* sb = spat_g + (size_t)b * 12544 + (gc * 32 + cg0) * 49;
  #pragma unroll
  for (int j = 0; j < 7; j++){
    int i = lane + 64 * j;
    if (i < 392){
      int c = gc * 32 + cg0 + i / 49;
      sb[i] = (tmp[j] - m) * rs * sa_g[c] + sa_bb[c];
    }
  }
}

// ---------------------------------------------------------------------------
// k_weff: Weff[b, j] = sum_k aw[b,k] * W[k, j]  (bf16 out).
// 4-stage register pipeline: thread owns 4 scalar-j chunks (16 f32 each,
// <=2 buffers live); loads of chunk c+1 overlap compute+store of chunk c,
// so reads/FMAs/writes interleave continuously. grid 1600.
// ---------------------------------------------------------------------------
__global__ __launch_bounds__(256) void k_weff(
    const float* __restrict__ W, const float* __restrict__ aw, u16* __restrict__ weff)
{
  __shared__ float aws[512];
  for (int i = threadIdx.x; i < 512; i += 256) aws[i] = aw[i];
  const size_t t = (size_t)blockIdx.x * 256 + threadIdx.x;  // 0..409599
  const size_t CS = 409600;
  float A[16], B[16];
  #pragma unroll
  for (int k = 0; k < 16; k++) A[k] = W[(size_t)k * 1638400 + t];
  #pragma unroll
  for (int k = 0; k < 16; k++) B[k] = W[(size_t)k * 1638400 + t + CS];
  __syncthreads();

  #pragma unroll 1
  for (int b = 0; b < 32; b++){
    const float* a = aws + b * 16;
    float s = 0.f;
    #pragma unroll
    for (int k = 0; k < 16; k++) s += a[k] * A[k];
    weff[(size_t)b * 1638400 + t] = f2bf(s);
  }
  #pragma unroll
  for (int k = 0; k < 16; k++) A[k] = W[(size_t)k * 1638400 + t + 2 * CS];

  #pragma unroll 1
  for (int b = 0; b < 32; b++){
    const float* a = aws + b * 16;
    float s = 0.f;
    #pragma unroll
    for (int k = 0; k < 16; k++) s += a[k] * B[k];
    weff[(size_t)b * 1638400 + t + CS] = f2bf(s);
  }
  #pragma unroll
  for (int k = 0; k < 16; k++) B[k] = W[(size_t)k * 1638400 + t + 3 * CS];

  #pragma unroll 1
  for (int b = 0; b < 32; b++){
    const float* a = aws + b * 16;
    float s = 0.f;
    #pragma unroll
    for (int k = 0; k < 16; k++) s += a[k] * A[k];
    weff[(size_t)b * 1638400 + t + 2 * CS] = f2bf(s);
  }
  #pragma unroll 1
  for (int b = 0; b < 32; b++){
    const float* a = aws + b * 16;
    float s = 0.f;
    #pragma unroll
    for (int k = 0; k < 16; k++) s += a[k] * B[k];
    weff[(size_t)b * 1638400 + t + 3 * CS] = f2bf(s);
  }
}

// ---------------------------------------------------------------------------
// k_im2col: X'[b][p][k'] bf16, k' = ci*25 + sy*5+sx; zero outside image.
// ---------------------------------------------------------------------------
__global__ __launch_bounds__(256) void k_im2col(
    const float* __restrict__ normed, u16* __restrict__ xim)
{
  int p = blockIdx.x, b = blockIdx.y;
  __shared__ u16 row[6400];
  int ci = threadIdx.x;
  int py = p / 7, px = p - py * 7;
  const float* nb = normed + (size_t)b * 12544 + ci * 49;
  u16* rp = row + ci * 25;
  #pragma unroll
  for (int sy = 0; sy < 5; sy++){
    int iy = py + sy - 2;
    #pragma unroll
    for (int sx = 0; sx < 5; sx++){
      int ix = px + sx - 2;
      float v = (iy >= 0 && iy < 7 && ix >= 0 && ix < 7) ? nb[iy * 7 + ix] : 0.f;
      rp[sy * 5 + sx] = f2bf(v);
    }
  }
  __syncthreads();
  const u32* rs = (const u32*)row;
  u32* od = (u32*)(xim + (size_t)(b * 49 + p) * 6400);
  for (int i = threadIdx.x; i < 3200; i += 256) od[i] = rs[i];
}

// ---------------------------------------------------------------------------
// k_conv_mfma: comb_part[kp][b][co][p] = Weff[b] @ X'[b] over k'-slice.
// ---------------------------------------------------------------------------
__global__ __launch_bounds__(256) void k_conv_mfma(
    const u16* __restrict__ weff, const u16* __restrict__ xim, float* __restrict__ partial)
{
  int bx = blockIdx.x, b = blockIdx.y;
  int mblk = bx >> 3, kp = bx & 7;
  int wv = threadIdx.x >> 6, lane = threadIdx.x & 63;
  int lo = lane & 15, hi = lane >> 4;
  int co0 = mblk * 128 + wv * 32;
  const u16* wr0 = weff + (size_t)b * 1638400 + (size_t)(co0 + lo) * 6400 + kp * 800 + hi * 8;
  const u16* wr1 = wr0 + 16 * 6400;
  const u16* xb = xim + (size_t)b * 313600 + (size_t)lo * 6400 + kp * 800 + hi * 8;
  f32x4 acc[2][4];
  #pragma unroll
  for (int mi = 0; mi < 2; mi++)
    #pragma unroll
    for (int pi = 0; pi < 4; pi++) acc[mi][pi] = (f32x4){0.f, 0.f, 0.f, 0.f};
  #pragma unroll 1
  for (int ks = 0; ks < 25; ks++){
    int k0 = ks * 32;
    bf16x8 A0 = *(const bf16x8*)(wr0 + k0);
    bf16x8 A1 = *(const bf16x8*)(wr1 + k0);
    bf16x8 B0 = *(const bf16x8*)(xb + k0);
    bf16x8 B1 = *(const bf16x8*)(xb + 16 * 6400 + k0);
    bf16x8 B2 = *(const bf16x8*)(xb + 32 * 6400 + k0);
    bf16x8 B3 = *(const bf16x8*)(xb + 48 * 6400 + k0);
    acc[0][0] = __builtin_amdgcn_mfma_f32_16x16x32_bf16(A0, B0, acc[0][0], 0, 0, 0);
    acc[0][1] = __builtin_amdgcn_mfma_f32_16x16x32_bf16(A0, B1, acc[0][1], 0, 0, 0);
    acc[0][2] = __builtin_amdgcn_mfma_f32_16x16x32_bf16(A0, B2, acc[0][2], 0, 0, 0);
    acc[0][3] = __builtin_amdgcn_mfma_f32_16x16x32_bf16(A0, B3, acc[0][3], 0, 0, 0);
    acc[1][0] = __builtin_amdgcn_mfma_f32_16x16x32_bf16(A1, B0, acc[1][0], 0, 0, 0);
    acc[1][1] = __builtin_amdgcn_mfma_f32_16x16x32_bf16(A1, B1, acc[1][1], 0, 0, 0);
    acc[1][2] = __builtin_amdgcn_mfma_f32_16x16x32_bf16(A1, B2, acc[1][2], 0, 0, 0);
    acc[1][3] = __builtin_amdgcn_mfma_f32_16x16x32_bf16(A1, B3, acc[1][3], 0, 0, 0);
  }
  float* pb = partial + ((size_t)kp * 32 + b) * 12544;
  #pragma unroll
  for (int mi = 0; mi < 2; mi++){
    #pragma unroll
    for (int pi = 0; pi < 4; pi++){
      int p = pi * 16 + lo;
      if (p < 49){
        #pragma unroll
        for (int r = 0; r < 4; r++){
          int co = co0 + mi * 16 + hi * 4 + r;
          pb[co * 49 + p] = acc[mi][pi][r];
        }
      }
    }
  }
}

// k_conv_reduce: comb = sum of 8 k-partials
__global__ __launch_bounds__(256) void k_conv_reduce(
    const float* __restrict__ part, float* __restrict__ comb)
{
  int i = blockIdx.x * 256 + threadIdx.x;
  if (i >= 100352) return;
  float a0 = 0.f, a1 = 0.f, a2 = 0.f, a3 = 0.f;
  #pragma unroll
  for (int p = 0; p < 8; p++){
    float4 v = ((const float4*)part)[(size_t)p * 100352 + i];
    a0 += v.x; a1 += v.y; a2 += v.z; a3 += v.w;
  }
  float4 o; o.x = a0; o.y = a1; o.z = a2; o.w = a3;
  ((float4*)comb)[i] = o;
}

// ---------------------------------------------------------------------------
// mfma_gemm_dev: per-wave 32m x 16p tile via mfma_f32_16x16x32_bf16.
// ---------------------------------------------------------------------------
__device__ __forceinline__ void mfma_gemm_dev(
    const float* __restrict__ W, const float* __restrict__ bias,
    const float* __restrict__ act, const float* __restrict__ res,
    float* __restrict__ out, int M, int K, int m0blk, int p0, int b,
    const float* __restrict__ lnm, const float* __restrict__ lnr,
    const float* __restrict__ lng, const float* __restrict__ lnb)
{
  int wv = threadIdx.x >> 6, lane = threadIdx.x & 63;
  int lo = lane & 15, hi = lane >> 4;
  int m0 = m0blk + wv * 32;
  int p = p0 + lo;
  bool pok = p < 49;
  const float* ab = act + (size_t)b * K * 49;
  float lm = 0.f, lr = 0.f;
  if (lng && pok){ lm = lnm[p]; lr = lnr[p]; }
  f32x4 acc0 = {0.f, 0.f, 0.f, 0.f};
  f32x4 acc1 = {0.f, 0.f, 0.f, 0.f};
  const float* wr0 = W + (size_t)(m0 + lo) * K + hi * 8;
  const float* wr1 = W + (size_t)(m0 + 16 + lo) * K + hi * 8;
  for (int k0 = 0; k0 < K; k0 += 32){
    int kb = k0 + hi * 8;
    float4 a0lo = *(const float4*)(wr0 + k0);
    float4 a0hi = *(const float4*)(wr0 + k0 + 4);
    float4 a1lo = *(const float4*)(wr1 + k0);
    float4 a1hi = *(const float4*)(wr1 + k0 + 4);
    float bv[8];
    if (pok){
      const float* ap = ab + (size_t)kb * 49 + p;
      #pragma unroll
      for (int i = 0; i < 8; i++) bv[i] = ap[i * 49];
      if (lng){
        #pragma unroll
        for (int i = 0; i < 8; i++) bv[i] = (bv[i] - lm) * lr * lng[kb + i] + lnb[kb + i];
      }
    } else {
      #pragma unroll
      for (int i = 0; i < 8; i++) bv[i] = 0.f;
    }
    BF8 A0, A1, B;
    A0.u[0] = pk2(a0lo.x, a0lo.y); A0.u[1] = pk2(a0lo.z, a0lo.w);
    A0.u[2] = pk2(a0hi.x, a0hi.y); A0.u[3] = pk2(a0hi.z, a0hi.w);
    A1.u[0] = pk2(a1lo.x, a1lo.y); A1.u[1] = pk2(a1lo.z, a1lo.w);
    A1.u[2] = pk2(a1hi.x, a1hi.y); A1.u[3] = pk2(a1hi.z, a1hi.w);
    B.u[0] = pk2(bv[0], bv[1]); B.u[1] = pk2(bv[2], bv[3]);
    B.u[2] = pk2(bv[4], bv[5]); B.u[3] = pk2(bv[6], bv[7]);
    acc0 = __builtin_amdgcn_mfma_f32_16x16x32_bf16(A0.v, B.v, acc0, 0, 0, 0);
    acc1 = __builtin_amdgcn_mfma_f32_16x16x32_bf16(A1.v, B.v, acc1, 0, 0, 0);
  }
  if (pok){
    #pragma unroll
    for (int r = 0; r < 4; r++){
      int m = m0 + hi * 4 + r;
      size_t idx = ((size_t)b * M + m) * 49 + p;
      float v = acc0[r] + (bias ? bias[m] : 0.f);
      if (res) v += res[idx];
      out[idx] = v;
      int m2 = m + 16;
      size_t idx2 = idx + 16 * 49;
      float v2 = acc1[r] + (bias ? bias[m2] : 0.f);
      if (res) v2 += res[idx2];
      out[idx2] = v2;
    }
  }
}

// merged qkv: bx<24 -> ra_qkv (act=xr); else aa_qkv (act=LN(normed) fused)
__global__ __launch_bounds__(256) void k_qkv(
    const float* __restrict__ ra_w, const float* __restrict__ aa_w,
    const float* __restrict__ xr, const float* __restrict__ normed,
    const float* __restrict__ lnm, const float* __restrict__ lnr,
    const float* __restrict__ ln_g, const float* __restrict__ ln_b,
    float* __restrict__ ra_qkv, float* __restrict__ aa_qkv)
{
  int bx = blockIdx.x, b = blockIdx.y;
  if (bx < 24){
    int m0 = (bx >> 2) * 128, p0 = (bx & 3) * 16;
    mfma_gemm_dev(ra_w, nullptr, xr, nullptr, ra_qkv, 768, 256, m0, p0, b,
                  nullptr, nullptr, nullptr, nullptr);
  } else {
    int bx2 = bx - 24;
    int m0 = (bx2 >> 2) * 128, p0 = (bx2 & 3) * 16;
    mfma_gemm_dev(aa_w, nullptr, normed, nullptr, aa_qkv, 1536, 256, m0, p0, b,
                  lnm + b * 49, lnr + b * 49, ln_g, ln_b);
  }
}

// merged projections: bx<8 ra_proj, <16 aa_out (K=512), else ad_proj
__global__ __launch_bounds__(256) void k_proj3(
    const float* __restrict__ ra_pw, const float* __restrict__ ra_pb, const float* __restrict__ r0,
    const float* __restrict__ aa_ow, const float* __restrict__ aa_ob, const float* __restrict__ aa_o,
    const float* __restrict__ ad_pw, const float* __restrict__ ad_pb, const float* __restrict__ comb,
    const float* __restrict__ normed,
    float* __restrict__ rotf, float* __restrict__ angf, float* __restrict__ adpf)
{
  int bx = blockIdx.x, b = blockIdx.y;
  if (bx < 8){
    int m0 = (bx >> 2) * 128, p0 = (bx & 3) * 16;
    mfma_gemm_dev(ra_pw, ra_pb, r0, normed, rotf, 256, 256, m0, p0, b,
                  nullptr, nullptr, nullptr, nullptr);
  } else if (bx < 16){
    int bx2 = bx - 8;
    int m0 = (bx2 >> 2) * 128, p0 = (bx2 & 3) * 16;
    mfma_gemm_dev(aa_ow, aa_ob, aa_o, normed, angf, 256, 512, m0, p0, b,
                  nullptr, nullptr, nullptr, nullptr);
  } else {
    int bx2 = bx - 16;
    int m0 = (bx2 >> 2) * 128, p0 = (bx2 & 3) * 16;
    mfma_gemm_dev(ad_pw, ad_pb, comb, normed, adpf, 256, 256, m0, p0, b,
                  nullptr, nullptr, nullptr, nullptr);
  }
}

// ---------------------------------------------------------------------------
// k_final: out = proj_w @ fused + proj_b + x, with fused = gated 4-branch sum
// computed on the fly in the B-staging (no materialized `fused` buffer).
// ---------------------------------------------------------------------------
__global__ __launch_bounds__(256) void k_final(
    const float* __restrict__ proj_w, const float* __restrict__ proj_b,
    const float* __restrict__ spat, const float* __restrict__ rotf,
    const float* __restrict__ angf, const float* __restrict__ adpf,
    const float* __restrict__ gates, const float* __restrict__ x,
    float* __restrict__ out)
{
  int bx = blockIdx.x, b = blockIdx.y;
  int wv = threadIdx.x >> 6, lane = threadIdx.x & 63;
  int lo = lane & 15, hi = lane >> 4;
  int m0 = (bx >> 2) * 128 + wv * 32;
  int p0 = (bx & 3) * 16;
  int p = p0 + lo;
  bool pok = p < 49;
  float g0 = 0.f, g1 = 0.f, g2 = 0.f, g3 = 0.f;
  if (pok){
    const float* g = gates + (size_t)b * 196 + p;
    g0 = g[0]; g1 = g[49]; g2 = g[98]; g3 = g[147];
  }
  size_t boff = (size_t)b * 12544;
  f32x4 acc0 = {0.f, 0.f, 0.f, 0.f};
  f32x4 acc1 = {0.f, 0.f, 0.f, 0.f};
  const float* wr0 = proj_w + (size_t)(m0 + lo) * 256 + hi * 8;
  const float* wr1 = wr0 + 16 * 256;
  for (int k0 = 0; k0 < 256; k0 += 32){
    int kb = k0 + hi * 8;
    float4 a0lo = *(const float4*)(wr0 + k0);
    float4 a0hi = *(const float4*)(wr0 + k0 + 4);
    float4 a1lo = *(const float4*)(wr1 + k0);
    float4 a1hi = *(const float4*)(wr1 + k0 + 4);
    float bv[8];
    if (pok){
      size_t base = boff + (size_t)kb * 49 + p;
      #pragma unroll
      for (int i = 0; i < 8; i++){
        size_t idx = base + (size_t)i * 49;
        bv[i] = spat[idx] * g0 + rotf[idx] * g1 + angf[idx] * g2 + adpf[idx] * g3;
      }
    } else {
      #pragma unroll
      for (int i = 0; i < 8; i++) bv[i] = 0.f;
    }
    BF8 A0, A1, B;
    A0.u[0] = pk2(a0lo.x, a0lo.y); A0.u[1] = pk2(a0lo.z, a0lo.w);
    A0.u[2] = pk2(a0hi.x, a0hi.y); A0.u[3] = pk2(a0hi.z, a0hi.w);
    A1.u[0] = pk2(a1lo.x, a1lo.y); A1.u[1] = pk2(a1lo.z, a1lo.w);
    A1.u[2] = pk2(a1hi.x, a1hi.y); A1.u[3] = pk2(a1hi.z, a1hi.w);
    B.u[0] = pk2(bv[0], bv[1]); B.u[1] = pk2(bv[2], bv[3]);
    B.u[2] = pk2(bv[4], bv[5]); B.u[3] = pk2(bv[6], bv[7]);
    acc0 = __builtin_amdgcn_mfma_f32_16x16x32_bf16(A0.v, B.v, acc0, 0, 0, 0);
    acc1 = __builtin_amdgcn_mfma_f32_16x16x32_bf16(A1.v, B.v, acc1, 0, 0, 0);
  }
  if (pok){
    #pragma unroll
    for (int r = 0; r < 4; r++){
      int m = m0 + hi * 4 + r;
      size_t idx = boff + (size_t)m * 49 + p;
      out[idx] = acc0[r] + proj_b[m] + x[idx];
      int m2 = m + 16;
      size_t idx2 = idx + 16 * 49;
      out[idx2] = acc1[r] + proj_b[m2] + x[idx2];
    }
  }
}

// ---------------------------------------------------------------------------
// k_attn: x<8 -> ra head (d=32, no bias); else aa head (d=64, rel-pos bias)
// softmax: 4 lanes per row + shfl_xor reduce (wave-parallel).
// ---------------------------------------------------------------------------
__device__ __forceinline__ void softmax_rows(float* sc, int tid)
{
  int r = tid >> 2, q = tid & 3;
  if (r < 49){
    float* row = sc + r * 52;
    float mx = -1e30f;
    for (int j = q; j < 49; j += 4) mx = fmaxf(mx, row[j]);
    mx = fmaxf(mx, __shfl_xor(mx, 1));
    mx = fmaxf(mx, __shfl_xor(mx, 2));
    float sm = 0.f;
    for (int j = q; j < 49; j += 4){ float e = __expf(row[j] - mx); row[j] = e; sm += e; }
    sm += __shfl_xor(sm, 1);
    sm += __shfl_xor(sm, 2);
    float inv = 1.f / sm;
    for (int j = q; j < 49; j += 4) row[j] *= inv;
  }
}

__global__ __launch_bounds__(256) void k_attn(
    const float* __restrict__ ra_qkv, const float* __restrict__ aa_qkv,
    const float* __restrict__ relpos,
    float* __restrict__ r0, float* __restrict__ ao)
{
  __shared__ float sm[3 * 49 * 65 + 49 * 52];
  int xb2 = blockIdx.x, b = blockIdx.y;
  if (xb2 < 8){
    int hd = xb2;
    float* qs = sm; float* ks = sm + 1617; float* vs = sm + 3234; float* sc = sm + 4851;
    const float* base = ra_qkv + (size_t)b * 768 * 49;
    for (int i = threadIdx.x; i < 1568; i += 256){
      int d = i / 49, tok = i - d * 49;
      qs[tok * 33 + d] = base[(hd * 32 + d) * 49 + tok];
      ks[tok * 33 + d] = base[(256 + hd * 32 + d) * 49 + tok];
      vs[tok * 33 + d] = base[(512 + hd * 32 + d) * 49 + tok];
    }
    __syncthreads();
    const float scale = 0.17677669529663687f;
    for (int it = threadIdx.x; it < 2401; it += 256){
      int i = it / 49, j = it - i * 49;
      float s = 0.f;
      #pragma unroll
      for (int d = 0; d < 32; d++) s += qs[i * 33 + d] * ks[j * 33 + d];
      sc[i * 52 + j] = s * scale;
    }
    __syncthreads();
    softmax_rows(sc, threadIdx.x);
    __syncthreads();
    for (int it = threadIdx.x; it < 1568; it += 256){
      int d = it / 49, i = it - d * 49;
      float o = 0.f;
      for (int j = 0; j < 49; j++) o += sc[i * 52 + j] * vs[j * 33 + d];
      r0[((size_t)b * 256 + hd * 32 + d) * 49 + i] = o;
    }
  } else {
    int hd = xb2 - 8;
    float* qs = sm; float* ks = sm + 3185; float* vs = sm + 6370; float* sc = sm + 9555;
    const float* base = aa_qkv + (size_t)b * 1536 * 49;
    for (int i = threadIdx.x; i < 3136; i += 256){
      int d = i / 49, tok = i - d * 49;
      qs[tok * 65 + d] = base[(hd * 64 + d) * 49 + tok];
      ks[tok * 65 + d] = base[(512 + hd * 64 + d) * 49 + tok];
      vs[tok * 65 + d] = base[(1024 + hd * 64 + d) * 49 + tok];
    }
    __syncthreads();
    for (int it = threadIdx.x; it < 2401; it += 256){
      int i = it / 49, j = it - i * 49;
      float s = 0.f;
      #pragma unroll
      for (int d = 0; d < 64; d++) s += qs[i * 65 + d] * ks[j * 65 + d];
      int dy = j / 7 - i / 7 + 6, dx = j % 7 - i % 7 + 6;
      sc[i * 52 + j] = s * 0.125f + relpos[(dy * 13 + dx) * 8 + hd];
    }
    __syncthreads();
    softmax_rows(sc, threadIdx.x);
    __syncthreads();
    for (int it = threadIdx.x; it < 3136; it += 256){
      int d = it / 49, i = it - d * 49;
      float o = 0.f;
      for (int j = 0; j < 49; j++) o += sc[i * 52 + j] * vs[j * 65 + d];
      ao[((size_t)b * 512 + hd * 64 + d) * 49 + i] = o;
    }
  }
}

// ---------------------------------------------------------------------------
extern "C" void kernel_launch(void* const* d_in, const int* in_sizes, int n_in,
                              void* d_out, int out_size, void* d_ws, size_t ws_size,
                              hipStream_t stream)
{
  const float* x        = (const float*)d_in[0];
  const float* gn_g     = (const float*)d_in[1];
  const float* gn_b     = (const float*)d_in[2];
  const float* sa_w1    = (const float*)d_in[3];
  const float* sa_b1    = (const float*)d_in[4];
  const float* sa_w2    = (const float*)d_in[5];
  const float* sa_b2    = (const float*)d_in[6];
  const float* sa_gn_g  = (const float*)d_in[7];
  const float* sa_gn_b  = (const float*)d_in[8];
  const float* ra_gn_g  = (const float*)d_in[9];
  const float* ra_gn_b  = (const float*)d_in[10];
  const float* ra_qkv_w = (const float*)d_in[11];
  const float* ra_proj_w= (const float*)d_in[12];
  const float* ra_proj_b= (const float*)d_in[13];
  const float* aa_ln_g  = (const float*)d_in[14];
  const float* aa_ln_b  = (const float*)d_in[15];
  const float* aa_qkv_w = (const float*)d_in[16];
  const float* aa_relpos= (const float*)d_in[17];
  const float* aa_out_w = (const float*)d_in[18];
  const float* aa_out_b = (const float*)d_in[19];
  const float* ad_dir_w = (const float*)d_in[20];
  const float* ad_ap_w1 = (const float*)d_in[21];
  const float* ad_ap_b1 = (const float*)d_in[22];
  const float* ad_ap_w2 = (const float*)d_in[23];
  const float* ad_ap_b2 = (const float*)d_in[24];
  const float* ad_proj_w= (const float*)d_in[25];
  const float* ad_proj_b= (const float*)d_in[26];
  const float* gate_w   = (const float*)d_in[27];
  const float* gate_b   = (const float*)d_in[28];
  const float* proj_w   = (const float*)d_in[29];
  const float* proj_b   = (const float*)d_in[30];

  char* ws = (char*)d_ws;
  float* normed    = (float*)(ws + 0);
  float* xr        = (float*)(ws + 1605632);
  float* h1_g      = (float*)(ws + 3211264);
  float* lnm       = (float*)(ws + 3420160);
  float* lnr       = (float*)(ws + 3426560);
  float* spatial   = (float*)(ws + 4816896);
  float* rotf      = (float*)(ws + 6422528);
  float* anglef    = (float*)(ws + 8028160);
  float* adaptf    = (float*)(ws + 9633792);
  float* r0        = (float*)(ws + 12845056);
  float* gap       = (float*)(ws + 14450688);
  float* aw        = (float*)(ws + 14483456);
  float* gates     = (float*)(ws + 14485504);
  float* ra_qkv    = (float*)(ws + 14510592);
  float* aa_qkv    = (float*)(ws + 19327488);
  float* aa_o      = (float*)(ws + 28961280);
  float* comb      = (float*)(ws + 32172544);
  float* partial   = (float*)(ws + 33778176);   // 12,845,056 B
  u16*   xim       = (u16*)  (ws + 46623232);   // 20,070,400 B
  u16*   weff      = (u16*)  (ws + 66693632);   // 104,857,600 B

  float* out = (float*)d_out;

  k_prep1<<<dim3(8, 32), 256, 0, stream>>>(x, gn_g, gn_b, ra_gn_g, ra_gn_b, normed, xr, gap);
  k_pos<<<dim3(7, 32), 256, 0, stream>>>(x, normed, gate_w, gate_b, gates, lnm, lnr);
  k_h1aw<<<dim3(8, 32), 256, 0, stream>>>(normed, sa_w1, sa_b1,
                                          ad_ap_w1, ad_ap_b1, ad_ap_w2, ad_ap_b2,
                                          gap, h1_g, aw);
  k_spatial<<<dim3(8, 32), 256, 0, stream>>>(normed, h1_g, sa_w2, sa_b2, sa_gn_g, sa_gn_b, spatial);
  k_weff<<<dim3(1600), 256, 0, stream>>>(ad_dir_w, aw, weff);
  k_im2col<<<dim3(49, 32), 256, 0, stream>>>(normed, xim);
  k_qkv<<<dim3(72, 32), 256, 0, stream>>>(ra_qkv_w, aa_qkv_w, xr, normed,
                                          lnm, lnr, aa_ln_g, aa_ln_b, ra_qkv, aa_qkv);
  k_attn<<<dim3(16, 32), 256, 0, stream>>>(ra_qkv, aa_qkv, aa_relpos, r0, aa_o);
  k_conv_mfma<<<dim3(16, 32), 256, 0, stream>>>(weff, xim, partial);
  k_conv_reduce<<<dim3(392), 256, 0, stream>>>(partial, comb);
  k_proj3<<<dim3(24, 32), 256, 0, stream>>>(ra_proj_w, ra_proj_b, r0,
                                            aa_out_w, aa_out_b, aa_o,
                                            ad_proj_w, ad_proj_b, comb,
                                            normed, rotf, anglef, adaptf);
  k_final<<<dim3(8, 32), 256, 0, stream>>>(proj_w, proj_b, spatial, rotf, anglef, adaptf,
                                           gates, x, out);
}

// Round 9
// 291.545 us; speedup vs baseline: 1.0316x; 1.0030x over previous
//
#include <hip/hip_runtime.h>

#define EPS 1e-5f
typedef unsigned short u16;
typedef unsigned int u32;
typedef float f32x4 __attribute__((ext_vector_type(4)));
typedef short bf16x8 __attribute__((ext_vector_type(8)));

__device__ __forceinline__ float bf2f(u16 h){
  return __uint_as_float(((u32)h) << 16);
}
__device__ __forceinline__ u16 f2bf(float f){
  u32 u = __float_as_uint(f);
  u += 0x7fffu + ((u >> 16) & 1u);
  return (u16)(u >> 16);
}
__device__ __forceinline__ u32 pk2(float lo, float hi){
  return ((u32)f2bf(hi) << 16) | (u32)f2bf(lo);
}
union BF8 { bf16x8 v; u32 u[4]; };

// ---------------------------------------------------------------------------
// k_prep1: GN(x)->normed, GN(normed)->xr, gap (per-channel mean of normed)
// ---------------------------------------------------------------------------
__global__ __launch_bounds__(256) void k_prep1(
    const float* __restrict__ x, const float* __restrict__ gn_g, const float* __restrict__ gn_b,
    const float* __restrict__ ra_g, const float* __restrict__ ra_b,
    float* __restrict__ normed, float* __restrict__ xr, float* __restrict__ gap)
{
  int ch = blockIdx.x, b = blockIdx.y;
  int c0 = ch * 32;
  __shared__ float xs[1568], ns[1568];
  const float* xb = x + ((size_t)b * 256 + c0) * 49;
  for (int i = threadIdx.x; i < 1568; i += 256) xs[i] = xb[i];
  __syncthreads();
  int wv = threadIdx.x >> 6, lane = threadIdx.x & 63;
  const float* gsrc = xs + wv * 392;
  float* ndst = ns + wv * 392;
  float s = 0.f, ss = 0.f;
  for (int i = lane; i < 392; i += 64){ float v = gsrc[i]; s += v; ss += v * v; }
  for (int off = 32; off; off >>= 1){ s += __shfl_down(s, off); ss += __shfl_down(ss, off); }
  s = __shfl(s, 0); ss = __shfl(ss, 0);
  float m = s / 392.f, rs = rsqrtf(ss / 392.f - m * m + EPS);
  for (int i = lane; i < 392; i += 64){
    int c = c0 + wv * 8 + i / 49;
    ndst[i] = (gsrc[i] - m) * rs * gn_g[c] + gn_b[c];
  }
  __syncthreads();
  float* nb = normed + ((size_t)b * 256 + c0) * 49;
  for (int i = threadIdx.x; i < 1568; i += 256) nb[i] = ns[i];
  if (threadIdx.x < 32){
    float g2 = 0.f; const float* rp = ns + threadIdx.x * 49;
    for (int p = 0; p < 49; p++) g2 += rp[p];
    gap[(size_t)b * 256 + c0 + threadIdx.x] = g2 * (1.f / 49.f);
  }
  s = 0.f; ss = 0.f;
  for (int i = lane; i < 392; i += 64){ float v = ndst[i]; s += v; ss += v * v; }
  for (int off = 32; off; off >>= 1){ s += __shfl_down(s, off); ss += __shfl_down(ss, off); }
  s = __shfl(s, 0); ss = __shfl(ss, 0);
  m = s / 392.f; rs = rsqrtf(ss / 392.f - m * m + EPS);
  float* xrb = xr + ((size_t)b * 256 + c0) * 49;
  for (int i = lane; i < 392; i += 64){
    int c = c0 + wv * 8 + i / 49;
    xrb[wv * 392 + i] = (ndst[i] - m) * rs * ra_g[c] + ra_b[c];
  }
}

// ---------------------------------------------------------------------------
// k_pos: per-(b,p) LN stats + gate softmax. grid(7,32), block 256.
// ---------------------------------------------------------------------------
__global__ __launch_bounds__(256) void k_pos(
    const float* __restrict__ x, const float* __restrict__ normed,
    const float* __restrict__ gate_w, const float* __restrict__ gate_b,
    float* __restrict__ gates_g, float* __restrict__ lnm_g, float* __restrict__ lnr_g)
{
  int pc = blockIdx.x, b = blockIdx.y;
  __shared__ float gw[1024];
  for (int i = threadIdx.x; i < 1024; i += 256) gw[i] = gate_w[i];
  __syncthreads();
  int wv = threadIdx.x >> 6, lane = threadIdx.x & 63;
  for (int pi = wv; pi < 7; pi += 4){
    int p = pc * 7 + pi;
    const float* nb = normed + (size_t)b * 12544 + p;
    const float* xb = x + (size_t)b * 12544 + p;
    float s = 0.f, ss = 0.f, g0 = 0.f, g1 = 0.f, g2 = 0.f, g3 = 0.f;
    for (int c = lane; c < 256; c += 64){
      float nv = nb[c * 49];
      float xv = xb[c * 49];
      s += nv; ss += nv * nv;
      g0 += xv * gw[c]; g1 += xv * gw[256 + c];
      g2 += xv * gw[512 + c]; g3 += xv * gw[768 + c];
    }
    for (int off = 32; off; off >>= 1){
      s += __shfl_down(s, off); ss += __shfl_down(ss, off);
      g0 += __shfl_down(g0, off); g1 += __shfl_down(g1, off);
      g2 += __shfl_down(g2, off); g3 += __shfl_down(g3, off);
    }
    if (lane == 0){
      float mu = s / 256.f;
      lnm_g[b * 49 + p] = mu;
      lnr_g[b * 49 + p] = rsqrtf(ss / 256.f - mu * mu + EPS);
      g0 += gate_b[0]; g1 += gate_b[1]; g2 += gate_b[2]; g3 += gate_b[3];
      float mx = fmaxf(fmaxf(g0, g1), fmaxf(g2, g3));
      float e0 = __expf(g0 - mx), e1 = __expf(g1 - mx), e2 = __expf(g2 - mx), e3 = __expf(g3 - mx);
      float inv = 1.f / (e0 + e1 + e2 + e3);
      float* gg = gates_g + (size_t)b * 196 + p;
      gg[0] = e0 * inv; gg[49] = e1 * inv; gg[98] = e2 * inv; gg[147] = e3 * inv;
    }
  }
}

// ---------------------------------------------------------------------------
// k_h1aw: x<7 -> h1 (LDS GEMM); x==7 -> aw MLP. grid(8,32).
// ---------------------------------------------------------------------------
__global__ __launch_bounds__(256) void k_h1aw(
    const float* __restrict__ normed, const float* __restrict__ sa_w1, const float* __restrict__ sa_b1,
    const float* __restrict__ ap_w1, const float* __restrict__ ap_b1,
    const float* __restrict__ ap_w2, const float* __restrict__ ap_b2,
    const float* __restrict__ gap_g,
    float* __restrict__ h1_g, float* __restrict__ aw_g)
{
  int xb2 = blockIdx.x, b = blockIdx.y;
  int t = threadIdx.x;
  if (xb2 == 7){
    __shared__ float gaps[256], h[128], lg[16];
    gaps[t] = gap_g[b * 256 + t];
    __syncthreads();
    if (t < 128){
      float s = ap_b1[t];
      const float* wr = ap_w1 + t * 256;
      #pragma unroll 4
      for (int c = 0; c < 256; c++) s += gaps[c] * wr[c];
      h[t] = fmaxf(s, 0.f);
    }
    __syncthreads();
    if (t < 16){
      float s = ap_b2[t];
      const float* wr = ap_w2 + t * 128;
      #pragma unroll 4
      for (int o = 0; o < 128; o++) s += h[o] * wr[o];
      lg[t] = s;
    }
    __syncthreads();
    if (t == 0){
      float mx = -1e30f;
      for (int k = 0; k < 16; k++) mx = fmaxf(mx, lg[k]);
      float e[16], sm = 0.f;
      for (int k = 0; k < 16; k++){ e[k] = __expf(lg[k] - mx); sm += e[k]; }
      float inv = 1.f / sm;
      for (int k = 0; k < 16; k++) aw_g[b * 16 + k] = e[k] * inv;
    }
    return;
  }
  __shared__ float w1t[256 * 33];
  __shared__ float ns2[256 * 7];
  int p0 = xb2 * 7;
  for (int i = t; i < 8192; i += 256){
    int o = i >> 8, c = i & 255;
    w1t[c * 33 + o] = sa_w1[i];
  }
  for (int i = t; i < 1792; i += 256){
    int c = i / 7, pl = i - c * 7;
    ns2[i] = normed[(size_t)b * 12544 + c * 49 + p0 + pl];
  }
  __syncthreads();
  if (t < 224){
    int pl = t >> 5, o = t & 31;
    float s = sa_b1[o];
    #pragma unroll 8
    for (int c = 0; c < 256; c++) s += ns2[c * 7 + pl] * w1t[c * 33 + o];
    h1_g[(size_t)b * 1568 + (p0 + pl) * 32 + o] = fmaxf(s, 0.f);
  }
}

// ---------------------------------------------------------------------------
// k_spatial: tmp = normed*(1+sigmoid(w2@h1+b2)); GN(tmp) -> spatial. grid(8,32)
// ---------------------------------------------------------------------------
__global__ __launch_bounds__(256) void k_spatial(
    const float* __restrict__ normed, const float* __restrict__ h1_g,
    const float* __restrict__ sa_w2, const float* __restrict__ sa_b2,
    const float* __restrict__ sa_g, const float* __restrict__ sa_bb,
    float* __restrict__ spat_g)
{
  int gc = blockIdx.x, b = blockIdx.y;
  __shared__ float h1s[49 * 33];
  __shared__ float w2s[1024];
  int t = threadIdx.x;
  for (int i = t; i < 1568; i += 256){
    int p = i >> 5, o = i & 31;
    h1s[p * 33 + o] = h1_g[(size_t)b * 1568 + i];
  }
  for (int i = t; i < 1024; i += 256) w2s[i] = sa_w2[gc * 1024 + i];
  __syncthreads();
  int wv = t >> 6, lane = t & 63;
  int cg0 = wv * 8;
  const float* nb = normed + (size_t)b * 12544 + (gc * 32 + cg0) * 49;
  float tmp[7];
  float s = 0.f, ss = 0.f;
  #pragma unroll
  for (int j = 0; j < 7; j++){
    int i = lane + 64 * j;
    float v = 0.f;
    if (i < 392){
      int c = i / 49;
      const float* wr = w2s + (cg0 + c) * 32;
      const float* hp = h1s + (i - c * 49) * 33;
      float d = sa_b2[gc * 32 + cg0 + c];
      #pragma unroll
      for (int o = 0; o < 32; o++) d += hp[o] * wr[o];
      v = nb[i] * (1.f + 1.f / (1.f + __expf(-d)));
      s += v; ss += v * v;
    }
    tmp[j] = v;
  }
  for (int off = 32; off; off >>= 1){ s += __shfl_down(s, off); ss += __shfl_down(ss, off); }
  s = __shfl(s, 0); ss = __shfl(ss, 0);
  float m = s / 392.f, rs = rsqrtf(ss / 392.f - m * m + EPS);
  float* sb = spat_g + (size_t)b * 12544 + (gc * 32 + cg0) * 49;
  #pragma unroll
  for (int j = 0; j < 7; j++){
    int i = lane + 64 * j;
    if (i < 392){
      int c = gc * 32 + cg0 + i / 49;
      sb[i] = (tmp[j] - m) * rs * sa_g[c] + sa_bb[c];
    }
  }
}

// ---------------------------------------------------------------------------
// k_weff: Weff[b, j] = sum_k aw[b,k] * W[k, j]  (bf16 out).
// aw read via grid-uniform global loads -> SGPRs (s_load, K$-cached), so the
// FMA loop has ZERO LDS traffic. 4-chunk register pipeline: loads of chunk
// c+1 overlap compute+store of chunk c. grid 1600.
// ---------------------------------------------------------------------------
__global__ __launch_bounds__(256) void k_weff(
    const float* __restrict__ W, const float* __restrict__ aw, u16* __restrict__ weff)
{
  const size_t t = (size_t)blockIdx.x * 256 + threadIdx.x;  // 0..409599
  const size_t CS = 409600;
  float A[16], B[16];
  #pragma unroll
  for (int k = 0; k < 16; k++) A[k] = W[(size_t)k * 1638400 + t];
  #pragma unroll
  for (int k = 0; k < 16; k++) B[k] = W[(size_t)k * 1638400 + t + CS];

  #pragma unroll 1
  for (int b = 0; b < 32; b++){
    float s = 0.f;
    #pragma unroll
    for (int k = 0; k < 16; k++) s += aw[b * 16 + k] * A[k];
    weff[(size_t)b * 1638400 + t] = f2bf(s);
  }
  #pragma unroll
  for (int k = 0; k < 16; k++) A[k] = W[(size_t)k * 1638400 + t + 2 * CS];

  #pragma unroll 1
  for (int b = 0; b < 32; b++){
    float s = 0.f;
    #pragma unroll
    for (int k = 0; k < 16; k++) s += aw[b * 16 + k] * B[k];
    weff[(size_t)b * 1638400 + t + CS] = f2bf(s);
  }
  #pragma unroll
  for (int k = 0; k < 16; k++) B[k] = W[(size_t)k * 1638400 + t + 3 * CS];

  #pragma unroll 1
  for (int b = 0; b < 32; b++){
    float s = 0.f;
    #pragma unroll
    for (int k = 0; k < 16; k++) s += aw[b * 16 + k] * A[k];
    weff[(size_t)b * 1638400 + t + 2 * CS] = f2bf(s);
  }
  #pragma unroll 1
  for (int b = 0; b < 32; b++){
    float s = 0.f;
    #pragma unroll
    for (int k = 0; k < 16; k++) s += aw[b * 16 + k] * B[k];
    weff[(size_t)b * 1638400 + t + 3 * CS] = f2bf(s);
  }
}

// ---------------------------------------------------------------------------
// k_im2col: X'[b][p][k'] bf16, k' = ci*25 + sy*5+sx; zero outside image.
// ---------------------------------------------------------------------------
__global__ __launch_bounds__(256) void k_im2col(
    const float* __restrict__ normed, u16* __restrict__ xim)
{
  int p = blockIdx.x, b = blockIdx.y;
  __shared__ u16 row[6400];
  int ci = threadIdx.x;
  int py = p / 7, px = p - py * 7;
  const float* nb = normed + (size_t)b * 12544 + ci * 49;
  u16* rp = row + ci * 25;
  #pragma unroll
  for (int sy = 0; sy < 5; sy++){
    int iy = py + sy - 2;
    #pragma unroll
    for (int sx = 0; sx < 5; sx++){
      int ix = px + sx - 2;
      float v = (iy >= 0 && iy < 7 && ix >= 0 && ix < 7) ? nb[iy * 7 + ix] : 0.f;
      rp[sy * 5 + sx] = f2bf(v);
    }
  }
  __syncthreads();
  const u32* rs = (const u32*)row;
  u32* od = (u32*)(xim + (size_t)(b * 49 + p) * 6400);
  for (int i = threadIdx.x; i < 3200; i += 256) od[i] = rs[i];
}

// ---------------------------------------------------------------------------
// k_conv_mfma: comb_part[kp][b][co][p] = Weff[b] @ X'[b] over k'-slice.
// ---------------------------------------------------------------------------
__global__ __launch_bounds__(256) void k_conv_mfma(
    const u16* __restrict__ weff, const u16* __restrict__ xim, float* __restrict__ partial)
{
  int bx = blockIdx.x, b = blockIdx.y;
  int mblk = bx >> 3, kp = bx & 7;
  int wv = threadIdx.x >> 6, lane = threadIdx.x & 63;
  int lo = lane & 15, hi = lane >> 4;
  int co0 = mblk * 128 + wv * 32;
  const u16* wr0 = weff + (size_t)b * 1638400 + (size_t)(co0 + lo) * 6400 + kp * 800 + hi * 8;
  const u16* wr1 = wr0 + 16 * 6400;
  const u16* xb = xim + (size_t)b * 313600 + (size_t)lo * 6400 + kp * 800 + hi * 8;
  f32x4 acc[2][4];
  #pragma unroll
  for (int mi = 0; mi < 2; mi++)
    #pragma unroll
    for (int pi = 0; pi < 4; pi++) acc[mi][pi] = (f32x4){0.f, 0.f, 0.f, 0.f};
  #pragma unroll 1
  for (int ks = 0; ks < 25; ks++){
    int k0 = ks * 32;
    bf16x8 A0 = *(const bf16x8*)(wr0 + k0);
    bf16x8 A1 = *(const bf16x8*)(wr1 + k0);
    bf16x8 B0 = *(const bf16x8*)(xb + k0);
    bf16x8 B1 = *(const bf16x8*)(xb + 16 * 6400 + k0);
    bf16x8 B2 = *(const bf16x8*)(xb + 32 * 6400 + k0);
    bf16x8 B3 = *(const bf16x8*)(xb + 48 * 6400 + k0);
    acc[0][0] = __builtin_amdgcn_mfma_f32_16x16x32_bf16(A0, B0, acc[0][0], 0, 0, 0);
    acc[0][1] = __builtin_amdgcn_mfma_f32_16x16x32_bf16(A0, B1, acc[0][1], 0, 0, 0);
    acc[0][2] = __builtin_amdgcn_mfma_f32_16x16x32_bf16(A0, B2, acc[0][2], 0, 0, 0);
    acc[0][3] = __builtin_amdgcn_mfma_f32_16x16x32_bf16(A0, B3, acc[0][3], 0, 0, 0);
    acc[1][0] = __builtin_amdgcn_mfma_f32_16x16x32_bf16(A1, B0, acc[1][0], 0, 0, 0);
    acc[1][1] = __builtin_amdgcn_mfma_f32_16x16x32_bf16(A1, B1, acc[1][1], 0, 0, 0);
    acc[1][2] = __builtin_amdgcn_mfma_f32_16x16x32_bf16(A1, B2, acc[1][2], 0, 0, 0);
    acc[1][3] = __builtin_amdgcn_mfma_f32_16x16x32_bf16(A1, B3, acc[1][3], 0, 0, 0);
  }
  float* pb = partial + ((size_t)kp * 32 + b) * 12544;
  #pragma unroll
  for (int mi = 0; mi < 2; mi++){
    #pragma unroll
    for (int pi = 0; pi < 4; pi++){
      int p = pi * 16 + lo;
      if (p < 49){
        #pragma unroll
        for (int r = 0; r < 4; r++){
          int co = co0 + mi * 16 + hi * 4 + r;
          pb[co * 49 + p] = acc[mi][pi][r];
        }
      }
    }
  }
}

// k_conv_reduce: comb = sum of 8 k-partials
__global__ __launch_bounds__(256) void k_conv_reduce(
    const float* __restrict__ part, float* __restrict__ comb)
{
  int i = blockIdx.x * 256 + threadIdx.x;
  if (i >= 100352) return;
  float a0 = 0.f, a1 = 0.f, a2 = 0.f, a3 = 0.f;
  #pragma unroll
  for (int p = 0; p < 8; p++){
    float4 v = ((const float4*)part)[(size_t)p * 100352 + i];
    a0 += v.x; a1 += v.y; a2 += v.z; a3 += v.w;
  }
  float4 o; o.x = a0; o.y = a1; o.z = a2; o.w = a3;
  ((float4*)comb)[i] = o;
}

// ---------------------------------------------------------------------------
// mfma_gemm_dev: per-wave 32m x 16p tile via mfma_f32_16x16x32_bf16.
// ---------------------------------------------------------------------------
__device__ __forceinline__ void mfma_gemm_dev(
    const float* __restrict__ W, const float* __restrict__ bias,
    const float* __restrict__ act, const float* __restrict__ res,
    float* __restrict__ out, int M, int K, int m0blk, int p0, int b,
    const float* __restrict__ lnm, const float* __restrict__ lnr,
    const float* __restrict__ lng, const float* __restrict__ lnb)
{
  int wv = threadIdx.x >> 6, lane = threadIdx.x & 63;
  int lo = lane & 15, hi = lane >> 4;
  int m0 = m0blk + wv * 32;
  int p = p0 + lo;
  bool pok = p < 49;
  const float* ab = act + (size_t)b * K * 49;
  float lm = 0.f, lr = 0.f;
  if (lng && pok){ lm = lnm[p]; lr = lnr[p]; }
  f32x4 acc0 = {0.f, 0.f, 0.f, 0.f};
  f32x4 acc1 = {0.f, 0.f, 0.f, 0.f};
  const float* wr0 = W + (size_t)(m0 + lo) * K + hi * 8;
  const float* wr1 = W + (size_t)(m0 + 16 + lo) * K + hi * 8;
  for (int k0 = 0; k0 < K; k0 += 32){
    int kb = k0 + hi * 8;
    float4 a0lo = *(const float4*)(wr0 + k0);
    float4 a0hi = *(const float4*)(wr0 + k0 + 4);
    float4 a1lo = *(const float4*)(wr1 + k0);
    float4 a1hi = *(const float4*)(wr1 + k0 + 4);
    float bv[8];
    if (pok){
      const float* ap = ab + (size_t)kb * 49 + p;
      #pragma unroll
      for (int i = 0; i < 8; i++) bv[i] = ap[i * 49];
      if (lng){
        #pragma unroll
        for (int i = 0; i < 8; i++) bv[i] = (bv[i] - lm) * lr * lng[kb + i] + lnb[kb + i];
      }
    } else {
      #pragma unroll
      for (int i = 0; i < 8; i++) bv[i] = 0.f;
    }
    BF8 A0, A1, B;
    A0.u[0] = pk2(a0lo.x, a0lo.y); A0.u[1] = pk2(a0lo.z, a0lo.w);
    A0.u[2] = pk2(a0hi.x, a0hi.y); A0.u[3] = pk2(a0hi.z, a0hi.w);
    A1.u[0] = pk2(a1lo.x, a1lo.y); A1.u[1] = pk2(a1lo.z, a1lo.w);
    A1.u[2] = pk2(a1hi.x, a1hi.y); A1.u[3] = pk2(a1hi.z, a1hi.w);
    B.u[0] = pk2(bv[0], bv[1]); B.u[1] = pk2(bv[2], bv[3]);
    B.u[2] = pk2(bv[4], bv[5]); B.u[3] = pk2(bv[6], bv[7]);
    acc0 = __builtin_amdgcn_mfma_f32_16x16x32_bf16(A0.v, B.v, acc0, 0, 0, 0);
    acc1 = __builtin_amdgcn_mfma_f32_16x16x32_bf16(A1.v, B.v, acc1, 0, 0, 0);
  }
  if (pok){
    #pragma unroll
    for (int r = 0; r < 4; r++){
      int m = m0 + hi * 4 + r;
      size_t idx = ((size_t)b * M + m) * 49 + p;
      float v = acc0[r] + (bias ? bias[m] : 0.f);
      if (res) v += res[idx];
      out[idx] = v;
      int m2 = m + 16;
      size_t idx2 = idx + 16 * 49;
      float v2 = acc1[r] + (bias ? bias[m2] : 0.f);
      if (res) v2 += res[idx2];
      out[idx2] = v2;
    }
  }
}

// merged qkv: bx<24 -> ra_qkv (act=xr); else aa_qkv (act=LN(normed) fused)
__global__ __launch_bounds__(256) void k_qkv(
    const float* __restrict__ ra_w, const float* __restrict__ aa_w,
    const float* __restrict__ xr, const float* __restrict__ normed,
    const float* __restrict__ lnm, const float* __restrict__ lnr,
    const float* __restrict__ ln_g, const float* __restrict__ ln_b,
    float* __restrict__ ra_qkv, float* __restrict__ aa_qkv)
{
  int bx = blockIdx.x, b = blockIdx.y;
  if (bx < 24){
    int m0 = (bx >> 2) * 128, p0 = (bx & 3) * 16;
    mfma_gemm_dev(ra_w, nullptr, xr, nullptr, ra_qkv, 768, 256, m0, p0, b,
                  nullptr, nullptr, nullptr, nullptr);
  } else {
    int bx2 = bx - 24;
    int m0 = (bx2 >> 2) * 128, p0 = (bx2 & 3) * 16;
    mfma_gemm_dev(aa_w, nullptr, normed, nullptr, aa_qkv, 1536, 256, m0, p0, b,
                  lnm + b * 49, lnr + b * 49, ln_g, ln_b);
  }
}

// merged projections: bx<8 ra_proj, <16 aa_out (K=512), else ad_proj
__global__ __launch_bounds__(256) void k_proj3(
    const float* __restrict__ ra_pw, const float* __restrict__ ra_pb, const float* __restrict__ r0,
    const float* __restrict__ aa_ow, const float* __restrict__ aa_ob, const float* __restrict__ aa_o,
    const float* __restrict__ ad_pw, const float* __restrict__ ad_pb, const float* __restrict__ comb,
    const float* __restrict__ normed,
    float* __restrict__ rotf, float* __restrict__ angf, float* __restrict__ adpf)
{
  int bx = blockIdx.x, b = blockIdx.y;
  if (bx < 8){
    int m0 = (bx >> 2) * 128, p0 = (bx & 3) * 16;
    mfma_gemm_dev(ra_pw, ra_pb, r0, normed, rotf, 256, 256, m0, p0, b,
                  nullptr, nullptr, nullptr, nullptr);
  } else if (bx < 16){
    int bx2 = bx - 8;
    int m0 = (bx2 >> 2) * 128, p0 = (bx2 & 3) * 16;
    mfma_gemm_dev(aa_ow, aa_ob, aa_o, normed, angf, 256, 512, m0, p0, b,
                  nullptr, nullptr, nullptr, nullptr);
  } else {
    int bx2 = bx - 16;
    int m0 = (bx2 >> 2) * 128, p0 = (bx2 & 3) * 16;
    mfma_gemm_dev(ad_pw, ad_pb, comb, normed, adpf, 256, 256, m0, p0, b,
                  nullptr, nullptr, nullptr, nullptr);
  }
}

// ---------------------------------------------------------------------------
// k_final: out = proj_w @ fused + proj_b + x, with fused = gated 4-branch sum
// computed on the fly in the B-staging (no materialized `fused` buffer).
// ---------------------------------------------------------------------------
__global__ __launch_bounds__(256) void k_final(
    const float* __restrict__ proj_w, const float* __restrict__ proj_b,
    const float* __restrict__ spat, const float* __restrict__ rotf,
    const float* __restrict__ angf, const float* __restrict__ adpf,
    const float* __restrict__ gates, const float* __restrict__ x,
    float* __restrict__ out)
{
  int bx = blockIdx.x, b = blockIdx.y;
  int wv = threadIdx.x >> 6, lane = threadIdx.x & 63;
  int lo = lane & 15, hi = lane >> 4;
  int m0 = (bx >> 2) * 128 + wv * 32;
  int p0 = (bx & 3) * 16;
  int p = p0 + lo;
  bool pok = p < 49;
  float g0 = 0.f, g1 = 0.f, g2 = 0.f, g3 = 0.f;
  if (pok){
    const float* g = gates + (size_t)b * 196 + p;
    g0 = g[0]; g1 = g[49]; g2 = g[98]; g3 = g[147];
  }
  size_t boff = (size_t)b * 12544;
  f32x4 acc0 = {0.f, 0.f, 0.f, 0.f};
  f32x4 acc1 = {0.f, 0.f, 0.f, 0.f};
  const float* wr0 = proj_w + (size_t)(m0 + lo) * 256 + hi * 8;
  const float* wr1 = wr0 + 16 * 256;
  for (int k0 = 0; k0 < 256; k0 += 32){
    int kb = k0 + hi * 8;
    float4 a0lo = *(const float4*)(wr0 + k0);
    float4 a0hi = *(const float4*)(wr0 + k0 + 4);
    float4 a1lo = *(const float4*)(wr1 + k0);
    float4 a1hi = *(const float4*)(wr1 + k0 + 4);
    float bv[8];
    if (pok){
      size_t base = boff + (size_t)kb * 49 + p;
      #pragma unroll
      for (int i = 0; i < 8; i++){
        size_t idx = base + (size_t)i * 49;
        bv[i] = spat[idx] * g0 + rotf[idx] * g1 + angf[idx] * g2 + adpf[idx] * g3;
      }
    } else {
      #pragma unroll
      for (int i = 0; i < 8; i++) bv[i] = 0.f;
    }
    BF8 A0, A1, B;
    A0.u[0] = pk2(a0lo.x, a0lo.y); A0.u[1] = pk2(a0lo.z, a0lo.w);
    A0.u[2] = pk2(a0hi.x, a0hi.y); A0.u[3] = pk2(a0hi.z, a0hi.w);
    A1.u[0] = pk2(a1lo.x, a1lo.y); A1.u[1] = pk2(a1lo.z, a1lo.w);
    A1.u[2] = pk2(a1hi.x, a1hi.y); A1.u[3] = pk2(a1hi.z, a1hi.w);
    B.u[0] = pk2(bv[0], bv[1]); B.u[1] = pk2(bv[2], bv[3]);
    B.u[2] = pk2(bv[4], bv[5]); B.u[3] = pk2(bv[6], bv[7]);
    acc0 = __builtin_amdgcn_mfma_f32_16x16x32_bf16(A0.v, B.v, acc0, 0, 0, 0);
    acc1 = __builtin_amdgcn_mfma_f32_16x16x32_bf16(A1.v, B.v, acc1, 0, 0, 0);
  }
  if (pok){
    #pragma unroll
    for (int r = 0; r < 4; r++){
      int m = m0 + hi * 4 + r;
      size_t idx = boff + (size_t)m * 49 + p;
      out[idx] = acc0[r] + proj_b[m] + x[idx];
      int m2 = m + 16;
      size_t idx2 = idx + 16 * 49;
      out[idx2] = acc1[r] + proj_b[m2] + x[idx2];
    }
  }
}

// ---------------------------------------------------------------------------
// k_attn: x<8 -> ra head (d=32, no bias); else aa head (d=64, rel-pos bias)
// softmax: 4 lanes per row + shfl_xor reduce (wave-parallel).
// ---------------------------------------------------------------------------
__device__ __forceinline__ void softmax_rows(float* sc, int tid)
{
  int r = tid >> 2, q = tid & 3;
  if (r < 49){
    float* row = sc + r * 52;
    float mx = -1e30f;
    for (int j = q; j < 49; j += 4) mx = fmaxf(mx, row[j]);
    mx = fmaxf(mx, __shfl_xor(mx, 1));
    mx = fmaxf(mx, __shfl_xor(mx, 2));
    float sm = 0.f;
    for (int j = q; j < 49; j += 4){ float e = __expf(row[j] - mx); row[j] = e; sm += e; }
    sm += __shfl_xor(sm, 1);
    sm += __shfl_xor(sm, 2);
    float inv = 1.f / sm;
    for (int j = q; j < 49; j += 4) row[j] *= inv;
  }
}

__global__ __launch_bounds__(256) void k_attn(
    const float* __restrict__ ra_qkv, const float* __restrict__ aa_qkv,
    const float* __restrict__ relpos,
    float* __restrict__ r0, float* __restrict__ ao)
{
  __shared__ float sm[3 * 49 * 65 + 49 * 52];
  int xb2 = blockIdx.x, b = blockIdx.y;
  if (xb2 < 8){
    int hd = xb2;
    float* qs = sm; float* ks = sm + 1617; float* vs = sm + 3234; float* sc = sm + 4851;
    const float* base = ra_qkv + (size_t)b * 768 * 49;
    for (int i = threadIdx.x; i < 1568; i += 256){
      int d = i / 49, tok = i - d * 49;
      qs[tok * 33 + d] = base[(hd * 32 + d) * 49 + tok];
      ks[tok * 33 + d] = base[(256 + hd * 32 + d) * 49 + tok];
      vs[tok * 33 + d] = base[(512 + hd * 32 + d) * 49 + tok];
    }
    __syncthreads();
    const float scale = 0.17677669529663687f;
    for (int it = threadIdx.x; it < 2401; it += 256){
      int i = it / 49, j = it - i * 49;
      float s = 0.f;
      #pragma unroll
      for (int d = 0; d < 32; d++) s += qs[i * 33 + d] * ks[j * 33 + d];
      sc[i * 52 + j] = s * scale;
    }
    __syncthreads();
    softmax_rows(sc, threadIdx.x);
    __syncthreads();
    for (int it = threadIdx.x; it < 1568; it += 256){
      int d = it / 49, i = it - d * 49;
      float o = 0.f;
      for (int j = 0; j < 49; j++) o += sc[i * 52 + j] * vs[j * 33 + d];
      r0[((size_t)b * 256 + hd * 32 + d) * 49 + i] = o;
    }
  } else {
    int hd = xb2 - 8;
    float* qs = sm; float* ks = sm + 3185; float* vs = sm + 6370; float* sc = sm + 9555;
    const float* base = aa_qkv + (size_t)b * 1536 * 49;
    for (int i = threadIdx.x; i < 3136; i += 256){
      int d = i / 49, tok = i - d * 49;
      qs[tok * 65 + d] = base[(hd * 64 + d) * 49 + tok];
      ks[tok * 65 + d] = base[(512 + hd * 64 + d) * 49 + tok];
      vs[tok * 65 + d] = base[(1024 + hd * 64 + d) * 49 + tok];
    }
    __syncthreads();
    for (int it = threadIdx.x; it < 2401; it += 256){
      int i = it / 49, j = it - i * 49;
      float s = 0.f;
      #pragma unroll
      for (int d = 0; d < 64; d++) s += qs[i * 65 + d] * ks[j * 65 + d];
      int dy = j / 7 - i / 7 + 6, dx = j % 7 - i % 7 + 6;
      sc[i * 52 + j] = s * 0.125f + relpos[(dy * 13 + dx) * 8 + hd];
    }
    __syncthreads();
    softmax_rows(sc, threadIdx.x);
    __syncthreads();
    for (int it = threadIdx.x; it < 3136; it += 256){
      int d = it / 49, i = it - d * 49;
      float o = 0.f;
      for (int j = 0; j < 49; j++) o += sc[i * 52 + j] * vs[j * 65 + d];
      ao[((size_t)b * 512 + hd * 64 + d) * 49 + i] = o;
    }
  }
}

// ---------------------------------------------------------------------------
extern "C" void kernel_launch(void* const* d_in, const int* in_sizes, int n_in,
                              void* d_out, int out_size, void* d_ws, size_t ws_size,
                              hipStream_t stream)
{
  const float* x        = (const float*)d_in[0];
  const float* gn_g     = (const float*)d_in[1];
  const float* gn_b     = (const float*)d_in[2];
  const float* sa_w1    = (const float*)d_in[3];
  const float* sa_b1    = (const float*)d_in[4];
  const float* sa_w2    = (const float*)d_in[5];
  const float* sa_b2    = (const float*)d_in[6];
  const float* sa_gn_g  = (const float*)d_in[7];
  const float* sa_gn_b  = (const float*)d_in[8];
  const float* ra_gn_g  = (const float*)d_in[9];
  const float* ra_gn_b  = (const float*)d_in[10];
  const float* ra_qkv_w = (const float*)d_in[11];
  const float* ra_proj_w= (const float*)d_in[12];
  const float* ra_proj_b= (const float*)d_in[13];
  const float* aa_ln_g  = (const float*)d_in[14];
  const float* aa_ln_b  = (const float*)d_in[15];
  const float* aa_qkv_w = (const float*)d_in[16];
  const float* aa_relpos= (const float*)d_in[17];
  const float* aa_out_w = (const float*)d_in[18];
  const float* aa_out_b = (const float*)d_in[19];
  const float* ad_dir_w = (const float*)d_in[20];
  const float* ad_ap_w1 = (const float*)d_in[21];
  const float* ad_ap_b1 = (const float*)d_in[22];
  const float* ad_ap_w2 = (const float*)d_in[23];
  const float* ad_ap_b2 = (const float*)d_in[24];
  const float* ad_proj_w= (const float*)d_in[25];
  const float* ad_proj_b= (const float*)d_in[26];
  const float* gate_w   = (const float*)d_in[27];
  const float* gate_b   = (const float*)d_in[28];
  const float* proj_w   = (const float*)d_in[29];
  const float* proj_b   = (const float*)d_in[30];

  char* ws = (char*)d_ws;
  float* normed    = (float*)(ws + 0);
  float* xr        = (float*)(ws + 1605632);
  float* h1_g      = (float*)(ws + 3211264);
  float* lnm       = (float*)(ws + 3420160);
  float* lnr       = (float*)(ws + 3426560);
  float* spatial   = (float*)(ws + 4816896);
  float* rotf      = (float*)(ws + 6422528);
  float* anglef    = (float*)(ws + 8028160);
  float* adaptf    = (float*)(ws + 9633792);
  float* r0        = (float*)(ws + 12845056);
  float* gap       = (float*)(ws + 14450688);
  float* aw        = (float*)(ws + 14483456);
  float* gates     = (float*)(ws + 14485504);
  float* ra_qkv    = (float*)(ws + 14510592);
  float* aa_qkv    = (float*)(ws + 19327488);
  float* aa_o      = (float*)(ws + 28961280);
  float* comb      = (float*)(ws + 32172544);
  float* partial   = (float*)(ws + 33778176);   // 12,845,056 B
  u16*   xim       = (u16*)  (ws + 46623232);   // 20,070,400 B
  u16*   weff      = (u16*)  (ws + 66693632);   // 104,857,600 B

  float* out = (float*)d_out;

  k_prep1<<<dim3(8, 32), 256, 0, stream>>>(x, gn_g, gn_b, ra_gn_g, ra_gn_b, normed, xr, gap);
  k_pos<<<dim3(7, 32), 256, 0, stream>>>(x, normed, gate_w, gate_b, gates, lnm, lnr);
  k_h1aw<<<dim3(8, 32), 256, 0, stream>>>(normed, sa_w1, sa_b1,
                                          ad_ap_w1, ad_ap_b1, ad_ap_w2, ad_ap_b2,
                                          gap, h1_g, aw);
  k_spatial<<<dim3(8, 32), 256, 0, stream>>>(normed, h1_g, sa_w2, sa_b2, sa_gn_g, sa_gn_b, spatial);
  k_weff<<<dim3(1600), 256, 0, stream>>>(ad_dir_w, aw, weff);
  k_im2col<<<dim3(49, 32), 256, 0, stream>>>(normed, xim);
  k_qkv<<<dim3(72, 32), 256, 0, stream>>>(ra_qkv_w, aa_qkv_w, xr, normed,
                                          lnm, lnr, aa_ln_g, aa_ln_b, ra_qkv, aa_qkv);
  k_attn<<<dim3(16, 32), 256, 0, stream>>>(ra_qkv, aa_qkv, aa_relpos, r0, aa_o);
  k_conv_mfma<<<dim3(16, 32), 256, 0, stream>>>(weff, xim, partial);
  k_conv_reduce<<<dim3(392), 256, 0, stream>>>(partial, comb);
  k_proj3<<<dim3(24, 32), 256, 0, stream>>>(ra_proj_w, ra_proj_b, r0,
                                            aa_out_w, aa_out_b, aa_o,
                                            ad_proj_w, ad_proj_b, comb,
                                            normed, rotf, anglef, adaptf);
  k_final<<<dim3(8, 32), 256, 0, stream>>>(proj_w, proj_b, spatial, rotf, anglef, adaptf,
                                           gates, x, out);
}

// Round 10
// 291.142 us; speedup vs baseline: 1.0330x; 1.0014x over previous
//
#include <hip/hip_runtime.h>

#define EPS 1e-5f
typedef unsigned short u16;
typedef unsigned int u32;
typedef float f32x4 __attribute__((ext_vector_type(4)));
typedef short bf16x8 __attribute__((ext_vector_type(8)));

__device__ __forceinline__ float bf2f(u16 h){
  return __uint_as_float(((u32)h) << 16);
}
__device__ __forceinline__ u16 f2bf(float f){
  u32 u = __float_as_uint(f);
  u += 0x7fffu + ((u >> 16) & 1u);
  return (u16)(u >> 16);
}
__device__ __forceinline__ u32 pk2(float lo, float hi){
  return ((u32)f2bf(hi) << 16) | (u32)f2bf(lo);
}
union BF8 { bf16x8 v; u32 u[4]; };

// ---------------------------------------------------------------------------
// k_prep1: GN(x)->normed, GN(normed)->xr, gap (per-channel mean of normed)
// ---------------------------------------------------------------------------
__global__ __launch_bounds__(256) void k_prep1(
    const float* __restrict__ x, const float* __restrict__ gn_g, const float* __restrict__ gn_b,
    const float* __restrict__ ra_g, const float* __restrict__ ra_b,
    float* __restrict__ normed, float* __restrict__ xr, float* __restrict__ gap)
{
  int ch = blockIdx.x, b = blockIdx.y;
  int c0 = ch * 32;
  __shared__ float xs[1568], ns[1568];
  const float* xb = x + ((size_t)b * 256 + c0) * 49;
  for (int i = threadIdx.x; i < 1568; i += 256) xs[i] = xb[i];
  __syncthreads();
  int wv = threadIdx.x >> 6, lane = threadIdx.x & 63;
  const float* gsrc = xs + wv * 392;
  float* ndst = ns + wv * 392;
  float s = 0.f, ss = 0.f;
  for (int i = lane; i < 392; i += 64){ float v = gsrc[i]; s += v; ss += v * v; }
  for (int off = 32; off; off >>= 1){ s += __shfl_down(s, off); ss += __shfl_down(ss, off); }
  s = __shfl(s, 0); ss = __shfl(ss, 0);
  float m = s / 392.f, rs = rsqrtf(ss / 392.f - m * m + EPS);
  for (int i = lane; i < 392; i += 64){
    int c = c0 + wv * 8 + i / 49;
    ndst[i] = (gsrc[i] - m) * rs * gn_g[c] + gn_b[c];
  }
  __syncthreads();
  float* nb = normed + ((size_t)b * 256 + c0) * 49;
  for (int i = threadIdx.x; i < 1568; i += 256) nb[i] = ns[i];
  if (threadIdx.x < 32){
    float g2 = 0.f; const float* rp = ns + threadIdx.x * 49;
    for (int p = 0; p < 49; p++) g2 += rp[p];
    gap[(size_t)b * 256 + c0 + threadIdx.x] = g2 * (1.f / 49.f);
  }
  s = 0.f; ss = 0.f;
  for (int i = lane; i < 392; i += 64){ float v = ndst[i]; s += v; ss += v * v; }
  for (int off = 32; off; off >>= 1){ s += __shfl_down(s, off); ss += __shfl_down(ss, off); }
  s = __shfl(s, 0); ss = __shfl(ss, 0);
  m = s / 392.f; rs = rsqrtf(ss / 392.f - m * m + EPS);
  float* xrb = xr + ((size_t)b * 256 + c0) * 49;
  for (int i = lane; i < 392; i += 64){
    int c = c0 + wv * 8 + i / 49;
    xrb[wv * 392 + i] = (ndst[i] - m) * rs * ra_g[c] + ra_b[c];
  }
}

// ---------------------------------------------------------------------------
// k_pos: per-(b,p) LN stats + gate softmax. grid(7,32), block 256.
// ---------------------------------------------------------------------------
__global__ __launch_bounds__(256) void k_pos(
    const float* __restrict__ x, const float* __restrict__ normed,
    const float* __restrict__ gate_w, const float* __restrict__ gate_b,
    float* __restrict__ gates_g, float* __restrict__ lnm_g, float* __restrict__ lnr_g)
{
  int pc = blockIdx.x, b = blockIdx.y;
  __shared__ float gw[1024];
  for (int i = threadIdx.x; i < 1024; i += 256) gw[i] = gate_w[i];
  __syncthreads();
  int wv = threadIdx.x >> 6, lane = threadIdx.x & 63;
  for (int pi = wv; pi < 7; pi += 4){
    int p = pc * 7 + pi;
    const float* nb = normed + (size_t)b * 12544 + p;
    const float* xb = x + (size_t)b * 12544 + p;
    float s = 0.f, ss = 0.f, g0 = 0.f, g1 = 0.f, g2 = 0.f, g3 = 0.f;
    for (int c = lane; c < 256; c += 64){
      float nv = nb[c * 49];
      float xv = xb[c * 49];
      s += nv; ss += nv * nv;
      g0 += xv * gw[c]; g1 += xv * gw[256 + c];
      g2 += xv * gw[512 + c]; g3 += xv * gw[768 + c];
    }
    for (int off = 32; off; off >>= 1){
      s += __shfl_down(s, off); ss += __shfl_down(ss, off);
      g0 += __shfl_down(g0, off); g1 += __shfl_down(g1, off);
      g2 += __shfl_down(g2, off); g3 += __shfl_down(g3, off);
    }
    if (lane == 0){
      float mu = s / 256.f;
      lnm_g[b * 49 + p] = mu;
      lnr_g[b * 49 + p] = rsqrtf(ss / 256.f - mu * mu + EPS);
      g0 += gate_b[0]; g1 += gate_b[1]; g2 += gate_b[2]; g3 += gate_b[3];
      float mx = fmaxf(fmaxf(g0, g1), fmaxf(g2, g3));
      float e0 = __expf(g0 - mx), e1 = __expf(g1 - mx), e2 = __expf(g2 - mx), e3 = __expf(g3 - mx);
      float inv = 1.f / (e0 + e1 + e2 + e3);
      float* gg = gates_g + (size_t)b * 196 + p;
      gg[0] = e0 * inv; gg[49] = e1 * inv; gg[98] = e2 * inv; gg[147] = e3 * inv;
    }
  }
}

// ---------------------------------------------------------------------------
// k_h1aw: x<7 -> h1 (LDS GEMM); x==7 -> aw MLP. grid(8,32).
// ---------------------------------------------------------------------------
__global__ __launch_bounds__(256) void k_h1aw(
    const float* __restrict__ normed, const float* __restrict__ sa_w1, const float* __restrict__ sa_b1,
    const float* __restrict__ ap_w1, const float* __restrict__ ap_b1,
    const float* __restrict__ ap_w2, const float* __restrict__ ap_b2,
    const float* __restrict__ gap_g,
    float* __restrict__ h1_g, float* __restrict__ aw_g)
{
  int xb2 = blockIdx.x, b = blockIdx.y;
  int t = threadIdx.x;
  if (xb2 == 7){
    __shared__ float gaps[256], h[128], lg[16];
    gaps[t] = gap_g[b * 256 + t];
    __syncthreads();
    if (t < 128){
      float s = ap_b1[t];
      const float* wr = ap_w1 + t * 256;
      #pragma unroll 4
      for (int c = 0; c < 256; c++) s += gaps[c] * wr[c];
      h[t] = fmaxf(s, 0.f);
    }
    __syncthreads();
    if (t < 16){
      float s = ap_b2[t];
      const float* wr = ap_w2 + t * 128;
      #pragma unroll 4
      for (int o = 0; o < 128; o++) s += h[o] * wr[o];
      lg[t] = s;
    }
    __syncthreads();
    if (t == 0){
      float mx = -1e30f;
      for (int k = 0; k < 16; k++) mx = fmaxf(mx, lg[k]);
      float e[16], sm = 0.f;
      for (int k = 0; k < 16; k++){ e[k] = __expf(lg[k] - mx); sm += e[k]; }
      float inv = 1.f / sm;
      for (int k = 0; k < 16; k++) aw_g[b * 16 + k] = e[k] * inv;
    }
    return;
  }
  __shared__ float w1t[256 * 33];
  __shared__ float ns2[256 * 7];
  int p0 = xb2 * 7;
  for (int i = t; i < 8192; i += 256){
    int o = i >> 8, c = i & 255;
    w1t[c * 33 + o] = sa_w1[i];
  }
  for (int i = t; i < 1792; i += 256){
    int c = i / 7, pl = i - c * 7;
    ns2[i] = normed[(size_t)b * 12544 + c * 49 + p0 + pl];
  }
  __syncthreads();
  if (t < 224){
    int pl = t >> 5, o = t & 31;
    float s = sa_b1[o];
    #pragma unroll 8
    for (int c = 0; c < 256; c++) s += ns2[c * 7 + pl] * w1t[c * 33 + o];
    h1_g[(size_t)b * 1568 + (p0 + pl) * 32 + o] = fmaxf(s, 0.f);
  }
}

// ---------------------------------------------------------------------------
// k_spatial: tmp = normed*(1+sigmoid(w2@h1+b2)); GN(tmp) -> spatial. grid(8,32)
// ---------------------------------------------------------------------------
__global__ __launch_bounds__(256) void k_spatial(
    const float* __restrict__ normed, const float* __restrict__ h1_g,
    const float* __restrict__ sa_w2, const float* __restrict__ sa_b2,
    const float* __restrict__ sa_g, const float* __restrict__ sa_bb,
    float* __restrict__ spat_g)
{
  int gc = blockIdx.x, b = blockIdx.y;
  __shared__ float h1s[49 * 33];
  __shared__ float w2s[1024];
  int t = threadIdx.x;
  for (int i = t; i < 1568; i += 256){
    int p = i >> 5, o = i & 31;
    h1s[p * 33 + o] = h1_g[(size_t)b * 1568 + i];
  }
  for (int i = t; i < 1024; i += 256) w2s[i] = sa_w2[gc * 1024 + i];
  __syncthreads();
  int wv = t >> 6, lane = t & 63;
  int cg0 = wv * 8;
  const float* nb = normed + (size_t)b * 12544 + (gc * 32 + cg0) * 49;
  float tmp[7];
  float s = 0.f, ss = 0.f;
  #pragma unroll
  for (int j = 0; j < 7; j++){
    int i = lane + 64 * j;
    float v = 0.f;
    if (i < 392){
      int c = i / 49;
      const float* wr = w2s + (cg0 + c) * 32;
      const float* hp = h1s + (i - c * 49) * 33;
      float d = sa_b2[gc * 32 + cg0 + c];
      #pragma unroll
      for (int o = 0; o < 32; o++) d += hp[o] * wr[o];
      v = nb[i] * (1.f + 1.f / (1.f + __expf(-d)));
      s += v; ss += v * v;
    }
    tmp[j] = v;
  }
  for (int off = 32; off; off >>= 1){ s += __shfl_down(s, off); ss += __shfl_down(ss, off); }
  s = __shfl(s, 0); ss = __shfl(ss, 0);
  float m = s / 392.f, rs = rsqrtf(ss / 392.f - m * m + EPS);
  float* sb = spat_g + (size_t)b * 12544 + (gc * 32 + cg0) * 49;
  #pragma unroll
  for (int j = 0; j < 7; j++){
    int i = lane + 64 * j;
    if (i < 392){
      int c = gc * 32 + cg0 + i / 49;
      sb[i] = (tmp[j] - m) * rs * sa_g[c] + sa_bb[c];
    }
  }
}

// ---------------------------------------------------------------------------
// k_weff: Weff[b, j] = sum_k aw[b,k] * W[k, j]  (bf16 out).
// aw via grid-uniform s_loads (SGPR). Thread owns 2 chunks x 2 consecutive j
// (float2 regs); chunk-B loads in flight during chunk-A compute. Stores are
// NON-TEMPORAL packed u32 (2xbf16, 256B/wave-inst): streams 102MB out without
// evicting W from L3. grid 1600.
// ---------------------------------------------------------------------------
__global__ __launch_bounds__(256) void k_weff(
    const float* __restrict__ W, const float* __restrict__ aw, u16* __restrict__ weff)
{
  const size_t t = ((size_t)blockIdx.x * 256 + threadIdx.x) * 2;  // even j
  const size_t CS = 819200;  // second half offset (elements)
  float2 A[16], B[16];
  #pragma unroll
  for (int k = 0; k < 16; k++) A[k] = *(const float2*)(W + (size_t)k * 1638400 + t);
  #pragma unroll
  for (int k = 0; k < 16; k++) B[k] = *(const float2*)(W + (size_t)k * 1638400 + t + CS);

  #pragma unroll 1
  for (int b = 0; b < 32; b++){
    float s0 = 0.f, s1 = 0.f;
    #pragma unroll
    for (int k = 0; k < 16; k++){
      float a = aw[b * 16 + k];
      s0 += a * A[k].x; s1 += a * A[k].y;
    }
    __builtin_nontemporal_store(pk2(s0, s1), (u32*)(weff + (size_t)b * 1638400 + t));
  }
  #pragma unroll 1
  for (int b = 0; b < 32; b++){
    float s0 = 0.f, s1 = 0.f;
    #pragma unroll
    for (int k = 0; k < 16; k++){
      float a = aw[b * 16 + k];
      s0 += a * B[k].x; s1 += a * B[k].y;
    }
    __builtin_nontemporal_store(pk2(s0, s1), (u32*)(weff + (size_t)b * 1638400 + t + CS));
  }
}

// ---------------------------------------------------------------------------
// k_im2col: X'[b][p][k'] bf16, k' = ci*25 + sy*5+sx; zero outside image.
// ---------------------------------------------------------------------------
__global__ __launch_bounds__(256) void k_im2col(
    const float* __restrict__ normed, u16* __restrict__ xim)
{
  int p = blockIdx.x, b = blockIdx.y;
  __shared__ u16 row[6400];
  int ci = threadIdx.x;
  int py = p / 7, px = p - py * 7;
  const float* nb = normed + (size_t)b * 12544 + ci * 49;
  u16* rp = row + ci * 25;
  #pragma unroll
  for (int sy = 0; sy < 5; sy++){
    int iy = py + sy - 2;
    #pragma unroll
    for (int sx = 0; sx < 5; sx++){
      int ix = px + sx - 2;
      float v = (iy >= 0 && iy < 7 && ix >= 0 && ix < 7) ? nb[iy * 7 + ix] : 0.f;
      rp[sy * 5 + sx] = f2bf(v);
    }
  }
  __syncthreads();
  const u32* rs = (const u32*)row;
  u32* od = (u32*)(xim + (size_t)(b * 49 + p) * 6400);
  for (int i = threadIdx.x; i < 3200; i += 256) od[i] = rs[i];
}

// ---------------------------------------------------------------------------
// k_conv_mfma: comb_part[kp][b][co][p] = Weff[b] @ X'[b] over k'-slice.
// ---------------------------------------------------------------------------
__global__ __launch_bounds__(256) void k_conv_mfma(
    const u16* __restrict__ weff, const u16* __restrict__ xim, float* __restrict__ partial)
{
  int bx = blockIdx.x, b = blockIdx.y;
  int mblk = bx >> 3, kp = bx & 7;
  int wv = threadIdx.x >> 6, lane = threadIdx.x & 63;
  int lo = lane & 15, hi = lane >> 4;
  int co0 = mblk * 128 + wv * 32;
  const u16* wr0 = weff + (size_t)b * 1638400 + (size_t)(co0 + lo) * 6400 + kp * 800 + hi * 8;
  const u16* wr1 = wr0 + 16 * 6400;
  const u16* xb = xim + (size_t)b * 313600 + (size_t)lo * 6400 + kp * 800 + hi * 8;
  f32x4 acc[2][4];
  #pragma unroll
  for (int mi = 0; mi < 2; mi++)
    #pragma unroll
    for (int pi = 0; pi < 4; pi++) acc[mi][pi] = (f32x4){0.f, 0.f, 0.f, 0.f};
  #pragma unroll 1
  for (int ks = 0; ks < 25; ks++){
    int k0 = ks * 32;
    bf16x8 A0 = *(const bf16x8*)(wr0 + k0);
    bf16x8 A1 = *(const bf16x8*)(wr1 + k0);
    bf16x8 B0 = *(const bf16x8*)(xb + k0);
    bf16x8 B1 = *(const bf16x8*)(xb + 16 * 6400 + k0);
    bf16x8 B2 = *(const bf16x8*)(xb + 32 * 6400 + k0);
    bf16x8 B3 = *(const bf16x8*)(xb + 48 * 6400 + k0);
    acc[0][0] = __builtin_amdgcn_mfma_f32_16x16x32_bf16(A0, B0, acc[0][0], 0, 0, 0);
    acc[0][1] = __builtin_amdgcn_mfma_f32_16x16x32_bf16(A0, B1, acc[0][1], 0, 0, 0);
    acc[0][2] = __builtin_amdgcn_mfma_f32_16x16x32_bf16(A0, B2, acc[0][2], 0, 0, 0);
    acc[0][3] = __builtin_amdgcn_mfma_f32_16x16x32_bf16(A0, B3, acc[0][3], 0, 0, 0);
    acc[1][0] = __builtin_amdgcn_mfma_f32_16x16x32_bf16(A1, B0, acc[1][0], 0, 0, 0);
    acc[1][1] = __builtin_amdgcn_mfma_f32_16x16x32_bf16(A1, B1, acc[1][1], 0, 0, 0);
    acc[1][2] = __builtin_amdgcn_mfma_f32_16x16x32_bf16(A1, B2, acc[1][2], 0, 0, 0);
    acc[1][3] = __builtin_amdgcn_mfma_f32_16x16x32_bf16(A1, B3, acc[1][3], 0, 0, 0);
  }
  float* pb = partial + ((size_t)kp * 32 + b) * 12544;
  #pragma unroll
  for (int mi = 0; mi < 2; mi++){
    #pragma unroll
    for (int pi = 0; pi < 4; pi++){
      int p = pi * 16 + lo;
      if (p < 49){
        #pragma unroll
        for (int r = 0; r < 4; r++){
          int co = co0 + mi * 16 + hi * 4 + r;
          pb[co * 49 + p] = acc[mi][pi][r];
        }
      }
    }
  }
}

// k_conv_reduce: comb = sum of 8 k-partials
__global__ __launch_bounds__(256) void k_conv_reduce(
    const float* __restrict__ part, float* __restrict__ comb)
{
  int i = blockIdx.x * 256 + threadIdx.x;
  if (i >= 100352) return;
  float a0 = 0.f, a1 = 0.f, a2 = 0.f, a3 = 0.f;
  #pragma unroll
  for (int p = 0; p < 8; p++){
    float4 v = ((const float4*)part)[(size_t)p * 100352 + i];
    a0 += v.x; a1 += v.y; a2 += v.z; a3 += v.w;
  }
  float4 o; o.x = a0; o.y = a1; o.z = a2; o.w = a3;
  ((float4*)comb)[i] = o;
}

// ---------------------------------------------------------------------------
// mfma_gemm_dev: per-wave 32m x 16p tile via mfma_f32_16x16x32_bf16.
// ---------------------------------------------------------------------------
__device__ __forceinline__ void mfma_gemm_dev(
    const float* __restrict__ W, const float* __restrict__ bias,
    const float* __restrict__ act, const float* __restrict__ res,
    float* __restrict__ out, int M, int K, int m0blk, int p0, int b,
    const float* __restrict__ lnm, const float* __restrict__ lnr,
    const float* __restrict__ lng, const float* __restrict__ lnb)
{
  int wv = threadIdx.x >> 6, lane = threadIdx.x & 63;
  int lo = lane & 15, hi = lane >> 4;
  int m0 = m0blk + wv * 32;
  int p = p0 + lo;
  bool pok = p < 49;
  const float* ab = act + (size_t)b * K * 49;
  float lm = 0.f, lr = 0.f;
  if (lng && pok){ lm = lnm[p]; lr = lnr[p]; }
  f32x4 acc0 = {0.f, 0.f, 0.f, 0.f};
  f32x4 acc1 = {0.f, 0.f, 0.f, 0.f};
  const float* wr0 = W + (size_t)(m0 + lo) * K + hi * 8;
  const float* wr1 = W + (size_t)(m0 + 16 + lo) * K + hi * 8;
  for (int k0 = 0; k0 < K; k0 += 32){
    int kb = k0 + hi * 8;
    float4 a0lo = *(const float4*)(wr0 + k0);
    float4 a0hi = *(const float4*)(wr0 + k0 + 4);
    float4 a1lo = *(const float4*)(wr1 + k0);
    float4 a1hi = *(const float4*)(wr1 + k0 + 4);
    float bv[8];
    if (pok){
      const float* ap = ab + (size_t)kb * 49 + p;
      #pragma unroll
      for (int i = 0; i < 8; i++) bv[i] = ap[i * 49];
      if (lng){
        #pragma unroll
        for (int i = 0; i < 8; i++) bv[i] = (bv[i] - lm) * lr * lng[kb + i] + lnb[kb + i];
      }
    } else {
      #pragma unroll
      for (int i = 0; i < 8; i++) bv[i] = 0.f;
    }
    BF8 A0, A1, B;
    A0.u[0] = pk2(a0lo.x, a0lo.y); A0.u[1] = pk2(a0lo.z, a0lo.w);
    A0.u[2] = pk2(a0hi.x, a0hi.y); A0.u[3] = pk2(a0hi.z, a0hi.w);
    A1.u[0] = pk2(a1lo.x, a1lo.y); A1.u[1] = pk2(a1lo.z, a1lo.w);
    A1.u[2] = pk2(a1hi.x, a1hi.y); A1.u[3] = pk2(a1hi.z, a1hi.w);
    B.u[0] = pk2(bv[0], bv[1]); B.u[1] = pk2(bv[2], bv[3]);
    B.u[2] = pk2(bv[4], bv[5]); B.u[3] = pk2(bv[6], bv[7]);
    acc0 = __builtin_amdgcn_mfma_f32_16x16x32_bf16(A0.v, B.v, acc0, 0, 0, 0);
    acc1 = __builtin_amdgcn_mfma_f32_16x16x32_bf16(A1.v, B.v, acc1, 0, 0, 0);
  }
  if (pok){
    #pragma unroll
    for (int r = 0; r < 4; r++){
      int m = m0 + hi * 4 + r;
      size_t idx = ((size_t)b * M + m) * 49 + p;
      float v = acc0[r] + (bias ? bias[m] : 0.f);
      if (res) v += res[idx];
      out[idx] = v;
      int m2 = m + 16;
      size_t idx2 = idx + 16 * 49;
      float v2 = acc1[r] + (bias ? bias[m2] : 0.f);
      if (res) v2 += res[idx2];
      out[idx2] = v2;
    }
  }
}

// merged qkv: bx<24 -> ra_qkv (act=xr); else aa_qkv (act=LN(normed) fused)
__global__ __launch_bounds__(256) void k_qkv(
    const float* __restrict__ ra_w, const float* __restrict__ aa_w,
    const float* __restrict__ xr, const float* __restrict__ normed,
    const float* __restrict__ lnm, const float* __restrict__ lnr,
    const float* __restrict__ ln_g, const float* __restrict__ ln_b,
    float* __restrict__ ra_qkv, float* __restrict__ aa_qkv)
{
  int bx = blockIdx.x, b = blockIdx.y;
  if (bx < 24){
    int m0 = (bx >> 2) * 128, p0 = (bx & 3) * 16;
    mfma_gemm_dev(ra_w, nullptr, xr, nullptr, ra_qkv, 768, 256, m0, p0, b,
                  nullptr, nullptr, nullptr, nullptr);
  } else {
    int bx2 = bx - 24;
    int m0 = (bx2 >> 2) * 128, p0 = (bx2 & 3) * 16;
    mfma_gemm_dev(aa_w, nullptr, normed, nullptr, aa_qkv, 1536, 256, m0, p0, b,
                  lnm + b * 49, lnr + b * 49, ln_g, ln_b);
  }
}

// merged projections: bx<8 ra_proj, <16 aa_out (K=512), else ad_proj
__global__ __launch_bounds__(256) void k_proj3(
    const float* __restrict__ ra_pw, const float* __restrict__ ra_pb, const float* __restrict__ r0,
    const float* __restrict__ aa_ow, const float* __restrict__ aa_ob, const float* __restrict__ aa_o,
    const float* __restrict__ ad_pw, const float* __restrict__ ad_pb, const float* __restrict__ comb,
    const float* __restrict__ normed,
    float* __restrict__ rotf, float* __restrict__ angf, float* __restrict__ adpf)
{
  int bx = blockIdx.x, b = blockIdx.y;
  if (bx < 8){
    int m0 = (bx >> 2) * 128, p0 = (bx & 3) * 16;
    mfma_gemm_dev(ra_pw, ra_pb, r0, normed, rotf, 256, 256, m0, p0, b,
                  nullptr, nullptr, nullptr, nullptr);
  } else if (bx < 16){
    int bx2 = bx - 8;
    int m0 = (bx2 >> 2) * 128, p0 = (bx2 & 3) * 16;
    mfma_gemm_dev(aa_ow, aa_ob, aa_o, normed, angf, 256, 512, m0, p0, b,
                  nullptr, nullptr, nullptr, nullptr);
  } else {
    int bx2 = bx - 16;
    int m0 = (bx2 >> 2) * 128, p0 = (bx2 & 3) * 16;
    mfma_gemm_dev(ad_pw, ad_pb, comb, normed, adpf, 256, 256, m0, p0, b,
                  nullptr, nullptr, nullptr, nullptr);
  }
}

// ---------------------------------------------------------------------------
// k_final: out = proj_w @ fused + proj_b + x, with fused = gated 4-branch sum
// computed on the fly in the B-staging (no materialized `fused` buffer).
// ---------------------------------------------------------------------------
__global__ __launch_bounds__(256) void k_final(
    const float* __restrict__ proj_w, const float* __restrict__ proj_b,
    const float* __restrict__ spat, const float* __restrict__ rotf,
    const float* __restrict__ angf, const float* __restrict__ adpf,
    const float* __restrict__ gates, const float* __restrict__ x,
    float* __restrict__ out)
{
  int bx = blockIdx.x, b = blockIdx.y;
  int wv = threadIdx.x >> 6, lane = threadIdx.x & 63;
  int lo = lane & 15, hi = lane >> 4;
  int m0 = (bx >> 2) * 128 + wv * 32;
  int p0 = (bx & 3) * 16;
  int p = p0 + lo;
  bool pok = p < 49;
  float g0 = 0.f, g1 = 0.f, g2 = 0.f, g3 = 0.f;
  if (pok){
    const float* g = gates + (size_t)b * 196 + p;
    g0 = g[0]; g1 = g[49]; g2 = g[98]; g3 = g[147];
  }
  size_t boff = (size_t)b * 12544;
  f32x4 acc0 = {0.f, 0.f, 0.f, 0.f};
  f32x4 acc1 = {0.f, 0.f, 0.f, 0.f};
  const float* wr0 = proj_w + (size_t)(m0 + lo) * 256 + hi * 8;
  const float* wr1 = wr0 + 16 * 256;
  for (int k0 = 0; k0 < 256; k0 += 32){
    int kb = k0 + hi * 8;
    float4 a0lo = *(const float4*)(wr0 + k0);
    float4 a0hi = *(const float4*)(wr0 + k0 + 4);
    float4 a1lo = *(const float4*)(wr1 + k0);
    float4 a1hi = *(const float4*)(wr1 + k0 + 4);
    float bv[8];
    if (pok){
      size_t base = boff + (size_t)kb * 49 + p;
      #pragma unroll
      for (int i = 0; i < 8; i++){
        size_t idx = base + (size_t)i * 49;
        bv[i] = spat[idx] * g0 + rotf[idx] * g1 + angf[idx] * g2 + adpf[idx] * g3;
      }
    } else {
      #pragma unroll
      for (int i = 0; i < 8; i++) bv[i] = 0.f;
    }
    BF8 A0, A1, B;
    A0.u[0] = pk2(a0lo.x, a0lo.y); A0.u[1] = pk2(a0lo.z, a0lo.w);
    A0.u[2] = pk2(a0hi.x, a0hi.y); A0.u[3] = pk2(a0hi.z, a0hi.w);
    A1.u[0] = pk2(a1lo.x, a1lo.y); A1.u[1] = pk2(a1lo.z, a1lo.w);
    A1.u[2] = pk2(a1hi.x, a1hi.y); A1.u[3] = pk2(a1hi.z, a1hi.w);
    B.u[0] = pk2(bv[0], bv[1]); B.u[1] = pk2(bv[2], bv[3]);
    B.u[2] = pk2(bv[4], bv[5]); B.u[3] = pk2(bv[6], bv[7]);
    acc0 = __builtin_amdgcn_mfma_f32_16x16x32_bf16(A0.v, B.v, acc0, 0, 0, 0);
    acc1 = __builtin_amdgcn_mfma_f32_16x16x32_bf16(A1.v, B.v, acc1, 0, 0, 0);
  }
  if (pok){
    #pragma unroll
    for (int r = 0; r < 4; r++){
      int m = m0 + hi * 4 + r;
      size_t idx = boff + (size_t)m * 49 + p;
      out[idx] = acc0[r] + proj_b[m] + x[idx];
      int m2 = m + 16;
      size_t idx2 = idx + 16 * 49;
      out[idx2] = acc1[r] + proj_b[m2] + x[idx2];
    }
  }
}

// ---------------------------------------------------------------------------
// k_attn: x<8 -> ra head (d=32, no bias); else aa head (d=64, rel-pos bias)
// softmax: 4 lanes per row + shfl_xor reduce (wave-parallel).
// ---------------------------------------------------------------------------
__device__ __forceinline__ void softmax_rows(float* sc, int tid)
{
  int r = tid >> 2, q = tid & 3;
  if (r < 49){
    float* row = sc + r * 52;
    float mx = -1e30f;
    for (int j = q; j < 49; j += 4) mx = fmaxf(mx, row[j]);
    mx = fmaxf(mx, __shfl_xor(mx, 1));
    mx = fmaxf(mx, __shfl_xor(mx, 2));
    float sm = 0.f;
    for (int j = q; j < 49; j += 4){ float e = __expf(row[j] - mx); row[j] = e; sm += e; }
    sm += __shfl_xor(sm, 1);
    sm += __shfl_xor(sm, 2);
    float inv = 1.f / sm;
    for (int j = q; j < 49; j += 4) row[j] *= inv;
  }
}

__global__ __launch_bounds__(256) void k_attn(
    const float* __restrict__ ra_qkv, const float* __restrict__ aa_qkv,
    const float* __restrict__ relpos,
    float* __restrict__ r0, float* __restrict__ ao)
{
  __shared__ float sm[3 * 49 * 65 + 49 * 52];
  int xb2 = blockIdx.x, b = blockIdx.y;
  if (xb2 < 8){
    int hd = xb2;
    float* qs = sm; float* ks = sm + 1617; float* vs = sm + 3234; float* sc = sm + 4851;
    const float* base = ra_qkv + (size_t)b * 768 * 49;
    for (int i = threadIdx.x; i < 1568; i += 256){
      int d = i / 49, tok = i - d * 49;
      qs[tok * 33 + d] = base[(hd * 32 + d) * 49 + tok];
      ks[tok * 33 + d] = base[(256 + hd * 32 + d) * 49 + tok];
      vs[tok * 33 + d] = base[(512 + hd * 32 + d) * 49 + tok];
    }
    __syncthreads();
    const float scale = 0.17677669529663687f;
    for (int it = threadIdx.x; it < 2401; it += 256){
      int i = it / 49, j = it - i * 49;
      float s = 0.f;
      #pragma unroll
      for (int d = 0; d < 32; d++) s += qs[i * 33 + d] * ks[j * 33 + d];
      sc[i * 52 + j] = s * scale;
    }
    __syncthreads();
    softmax_rows(sc, threadIdx.x);
    __syncthreads();
    for (int it = threadIdx.x; it < 1568; it += 256){
      int d = it / 49, i = it - d * 49;
      float o = 0.f;
      for (int j = 0; j < 49; j++) o += sc[i * 52 + j] * vs[j * 33 + d];
      r0[((size_t)b * 256 + hd * 32 + d) * 49 + i] = o;
    }
  } else {
    int hd = xb2 - 8;
    float* qs = sm; float* ks = sm + 3185; float* vs = sm + 6370; float* sc = sm + 9555;
    const float* base = aa_qkv + (size_t)b * 1536 * 49;
    for (int i = threadIdx.x; i < 3136; i += 256){
      int d = i / 49, tok = i - d * 49;
      qs[tok * 65 + d] = base[(hd * 64 + d) * 49 + tok];
      ks[tok * 65 + d] = base[(512 + hd * 64 + d) * 49 + tok];
      vs[tok * 65 + d] = base[(1024 + hd * 64 + d) * 49 + tok];
    }
    __syncthreads();
    for (int it = threadIdx.x; it < 2401; it += 256){
      int i = it / 49, j = it - i * 49;
      float s = 0.f;
      #pragma unroll
      for (int d = 0; d < 64; d++) s += qs[i * 65 + d] * ks[j * 65 + d];
      int dy = j / 7 - i / 7 + 6, dx = j % 7 - i % 7 + 6;
      sc[i * 52 + j] = s * 0.125f + relpos[(dy * 13 + dx) * 8 + hd];
    }
    __syncthreads();
    softmax_rows(sc, threadIdx.x);
    __syncthreads();
    for (int it = threadIdx.x; it < 3136; it += 256){
      int d = it / 49, i = it - d * 49;
      float o = 0.f;
      for (int j = 0; j < 49; j++) o += sc[i * 52 + j] * vs[j * 65 + d];
      ao[((size_t)b * 512 + hd * 64 + d) * 49 + i] = o;
    }
  }
}

// ---------------------------------------------------------------------------
extern "C" void kernel_launch(void* const* d_in, const int* in_sizes, int n_in,
                              void* d_out, int out_size, void* d_ws, size_t ws_size,
                              hipStream_t stream)
{
  const float* x        = (const float*)d_in[0];
  const float* gn_g     = (const float*)d_in[1];
  const float* gn_b     = (const float*)d_in[2];
  const float* sa_w1    = (const float*)d_in[3];
  const float* sa_b1    = (const float*)d_in[4];
  const float* sa_w2    = (const float*)d_in[5];
  const float* sa_b2    = (const float*)d_in[6];
  const float* sa_gn_g  = (const float*)d_in[7];
  const float* sa_gn_b  = (const float*)d_in[8];
  const float* ra_gn_g  = (const float*)d_in[9];
  const float* ra_gn_b  = (const float*)d_in[10];
  const float* ra_qkv_w = (const float*)d_in[11];
  const float* ra_proj_w= (const float*)d_in[12];
  const float* ra_proj_b= (const float*)d_in[13];
  const float* aa_ln_g  = (const float*)d_in[14];
  const float* aa_ln_b  = (const float*)d_in[15];
  const float* aa_qkv_w = (const float*)d_in[16];
  const float* aa_relpos= (const float*)d_in[17];
  const float* aa_out_w = (const float*)d_in[18];
  const float* aa_out_b = (const float*)d_in[19];
  const float* ad_dir_w = (const float*)d_in[20];
  const float* ad_ap_w1 = (const float*)d_in[21];
  const float* ad_ap_b1 = (const float*)d_in[22];
  const float* ad_ap_w2 = (const float*)d_in[23];
  const float* ad_ap_b2 = (const float*)d_in[24];
  const float* ad_proj_w= (const float*)d_in[25];
  const float* ad_proj_b= (const float*)d_in[26];
  const float* gate_w   = (const float*)d_in[27];
  const float* gate_b   = (const float*)d_in[28];
  const float* proj_w   = (const float*)d_in[29];
  const float* proj_b   = (const float*)d_in[30];

  char* ws = (char*)d_ws;
  float* normed    = (float*)(ws + 0);
  float* xr        = (float*)(ws + 1605632);
  float* h1_g      = (float*)(ws + 3211264);
  float* lnm       = (float*)(ws + 3420160);
  float* lnr       = (float*)(ws + 3426560);
  float* spatial   = (float*)(ws + 4816896);
  float* rotf      = (float*)(ws + 6422528);
  float* anglef    = (float*)(ws + 8028160);
  float* adaptf    = (float*)(ws + 9633792);
  float* r0        = (float*)(ws + 12845056);
  float* gap       = (float*)(ws + 14450688);
  float* aw        = (float*)(ws + 14483456);
  float* gates     = (float*)(ws + 14485504);
  float* ra_qkv    = (float*)(ws + 14510592);
  float* aa_qkv    = (float*)(ws + 19327488);
  float* aa_o      = (float*)(ws + 28961280);
  float* comb      = (float*)(ws + 32172544);
  float* partial   = (float*)(ws + 33778176);   // 12,845,056 B
  u16*   xim       = (u16*)  (ws + 46623232);   // 20,070,400 B
  u16*   weff      = (u16*)  (ws + 66693632);   // 104,857,600 B

  float* out = (float*)d_out;

  k_prep1<<<dim3(8, 32), 256, 0, stream>>>(x, gn_g, gn_b, ra_gn_g, ra_gn_b, normed, xr, gap);
  k_pos<<<dim3(7, 32), 256, 0, stream>>>(x, normed, gate_w, gate_b, gates, lnm, lnr);
  k_h1aw<<<dim3(8, 32), 256, 0, stream>>>(normed, sa_w1, sa_b1,
                                          ad_ap_w1, ad_ap_b1, ad_ap_w2, ad_ap_b2,
                                          gap, h1_g, aw);
  k_spatial<<<dim3(8, 32), 256, 0, stream>>>(normed, h1_g, sa_w2, sa_b2, sa_gn_g, sa_gn_b, spatial);
  k_weff<<<dim3(1600), 256, 0, stream>>>(ad_dir_w, aw, weff);
  k_im2col<<<dim3(49, 32), 256, 0, stream>>>(normed, xim);
  k_qkv<<<dim3(72, 32), 256, 0, stream>>>(ra_qkv_w, aa_qkv_w, xr, normed,
                                          lnm, lnr, aa_ln_g, aa_ln_b, ra_qkv, aa_qkv);
  k_attn<<<dim3(16, 32), 256, 0, stream>>>(ra_qkv, aa_qkv, aa_relpos, r0, aa_o);
  k_conv_mfma<<<dim3(16, 32), 256, 0, stream>>>(weff, xim, partial);
  k_conv_reduce<<<dim3(392), 256, 0, stream>>>(partial, comb);
  k_proj3<<<dim3(24, 32), 256, 0, stream>>>(ra_proj_w, ra_proj_b, r0,
                                            aa_out_w, aa_out_b, aa_o,
                                            ad_proj_w, ad_proj_b, comb,
                                            normed, rotf, anglef, adaptf);
  k_final<<<dim3(8, 32), 256, 0, stream>>>(proj_w, proj_b, spatial, rotf, anglef, adaptf,
                                           gates, x, out);
}

// Round 12
// 265.707 us; speedup vs baseline: 1.1319x; 1.0957x over previous
//
#include <hip/hip_runtime.h>

#define EPS 1e-5f
typedef unsigned short u16;
typedef unsigned int u32;
typedef float f32x4 __attribute__((ext_vector_type(4)));
typedef short bf16x8 __attribute__((ext_vector_type(8)));
typedef unsigned int u32x2 __attribute__((ext_vector_type(2)));

__device__ __forceinline__ float bf2f(u16 h){
  return __uint_as_float(((u32)h) << 16);
}
__device__ __forceinline__ u16 f2bf(float f){
  u32 u = __float_as_uint(f);
  u += 0x7fffu + ((u >> 16) & 1u);
  return (u16)(u >> 16);
}
__device__ __forceinline__ u32 pk2(float lo, float hi){
  return ((u32)f2bf(hi) << 16) | (u32)f2bf(lo);
}
union BF8 { bf16x8 v; u32 u[4]; };

// ---------------------------------------------------------------------------
// k_prep1: GN(x)->normed, GN(normed)->xr, gap. grid(8,32).
// ---------------------------------------------------------------------------
__global__ __launch_bounds__(256) void k_prep1(
    const float* __restrict__ x, const float* __restrict__ gn_g, const float* __restrict__ gn_b,
    const float* __restrict__ ra_g, const float* __restrict__ ra_b,
    float* __restrict__ normed, float* __restrict__ xr, float* __restrict__ gap)
{
  int ch = blockIdx.x, b = blockIdx.y;
  int c0 = ch * 32;
  __shared__ float xs[1568], ns[1568];
  const float* xb = x + ((size_t)b * 256 + c0) * 49;
  for (int i = threadIdx.x; i < 1568; i += 256) xs[i] = xb[i];
  __syncthreads();
  int wv = threadIdx.x >> 6, lane = threadIdx.x & 63;
  const float* gsrc = xs + wv * 392;
  float* ndst = ns + wv * 392;
  float s = 0.f, ss = 0.f;
  for (int i = lane; i < 392; i += 64){ float v = gsrc[i]; s += v; ss += v * v; }
  for (int off = 32; off; off >>= 1){ s += __shfl_down(s, off); ss += __shfl_down(ss, off); }
  s = __shfl(s, 0); ss = __shfl(ss, 0);
  float m = s / 392.f, rs = rsqrtf(ss / 392.f - m * m + EPS);
  for (int i = lane; i < 392; i += 64){
    int c = c0 + wv * 8 + i / 49;
    ndst[i] = (gsrc[i] - m) * rs * gn_g[c] + gn_b[c];
  }
  __syncthreads();
  float* nb = normed + ((size_t)b * 256 + c0) * 49;
  for (int i = threadIdx.x; i < 1568; i += 256) nb[i] = ns[i];
  if (threadIdx.x < 32){
    float g2 = 0.f; const float* rp = ns + threadIdx.x * 49;
    for (int p = 0; p < 49; p++) g2 += rp[p];
    gap[(size_t)b * 256 + c0 + threadIdx.x] = g2 * (1.f / 49.f);
  }
  s = 0.f; ss = 0.f;
  for (int i = lane; i < 392; i += 64){ float v = ndst[i]; s += v; ss += v * v; }
  for (int off = 32; off; off >>= 1){ s += __shfl_down(s, off); ss += __shfl_down(ss, off); }
  s = __shfl(s, 0); ss = __shfl(ss, 0);
  m = s / 392.f; rs = rsqrtf(ss / 392.f - m * m + EPS);
  float* xrb = xr + ((size_t)b * 256 + c0) * 49;
  for (int i = lane; i < 392; i += 64){
    int c = c0 + wv * 8 + i / 49;
    xrb[wv * 392 + i] = (ndst[i] - m) * rs * ra_g[c] + ra_b[c];
  }
}

// ---------------------------------------------------------------------------
// dev_pos / dev_h1aw  (merged into k_pre2)
// ---------------------------------------------------------------------------
__device__ void dev_pos(
    const float* __restrict__ x, const float* __restrict__ normed,
    const float* __restrict__ gate_w, const float* __restrict__ gate_b,
    float* __restrict__ gates_g, float* __restrict__ lnm_g, float* __restrict__ lnr_g,
    int pc, int b, float* sm)
{
  float* gw = sm;  // 1024
  for (int i = threadIdx.x; i < 1024; i += 256) gw[i] = gate_w[i];
  __syncthreads();
  int wv = threadIdx.x >> 6, lane = threadIdx.x & 63;
  for (int pi = wv; pi < 7; pi += 4){
    int p = pc * 7 + pi;
    const float* nb = normed + (size_t)b * 12544 + p;
    const float* xb = x + (size_t)b * 12544 + p;
    float s = 0.f, ss = 0.f, g0 = 0.f, g1 = 0.f, g2 = 0.f, g3 = 0.f;
    for (int c = lane; c < 256; c += 64){
      float nv = nb[c * 49];
      float xv = xb[c * 49];
      s += nv; ss += nv * nv;
      g0 += xv * gw[c]; g1 += xv * gw[256 + c];
      g2 += xv * gw[512 + c]; g3 += xv * gw[768 + c];
    }
    for (int off = 32; off; off >>= 1){
      s += __shfl_down(s, off); ss += __shfl_down(ss, off);
      g0 += __shfl_down(g0, off); g1 += __shfl_down(g1, off);
      g2 += __shfl_down(g2, off); g3 += __shfl_down(g3, off);
    }
    if (lane == 0){
      float mu = s / 256.f;
      lnm_g[b * 49 + p] = mu;
      lnr_g[b * 49 + p] = rsqrtf(ss / 256.f - mu * mu + EPS);
      g0 += gate_b[0]; g1 += gate_b[1]; g2 += gate_b[2]; g3 += gate_b[3];
      float mx = fmaxf(fmaxf(g0, g1), fmaxf(g2, g3));
      float e0 = __expf(g0 - mx), e1 = __expf(g1 - mx), e2 = __expf(g2 - mx), e3 = __expf(g3 - mx);
      float inv = 1.f / (e0 + e1 + e2 + e3);
      float* gg = gates_g + (size_t)b * 196 + p;
      gg[0] = e0 * inv; gg[49] = e1 * inv; gg[98] = e2 * inv; gg[147] = e3 * inv;
    }
  }
}

__device__ void dev_h1aw(
    const float* __restrict__ normed, const float* __restrict__ sa_w1, const float* __restrict__ sa_b1,
    const float* __restrict__ ap_w1, const float* __restrict__ ap_b1,
    const float* __restrict__ ap_w2, const float* __restrict__ ap_b2,
    const float* __restrict__ gap_g,
    float* __restrict__ h1_g, float* __restrict__ aw_g,
    int xb2, int b, float* sm)
{
  int t = threadIdx.x;
  if (xb2 == 7){
    float* gaps = sm; float* h = sm + 256; float* lg = sm + 384;
    gaps[t] = gap_g[b * 256 + t];
    __syncthreads();
    if (t < 128){
      float s = ap_b1[t];
      const float* wr = ap_w1 + t * 256;
      #pragma unroll 4
      for (int c = 0; c < 256; c++) s += gaps[c] * wr[c];
      h[t] = fmaxf(s, 0.f);
    }
    __syncthreads();
    if (t < 16){
      float s = ap_b2[t];
      const float* wr = ap_w2 + t * 128;
      #pragma unroll 4
      for (int o = 0; o < 128; o++) s += h[o] * wr[o];
      lg[t] = s;
    }
    __syncthreads();
    if (t == 0){
      float mx = -1e30f;
      for (int k = 0; k < 16; k++) mx = fmaxf(mx, lg[k]);
      float e[16], smm = 0.f;
      for (int k = 0; k < 16; k++){ e[k] = __expf(lg[k] - mx); smm += e[k]; }
      float inv = 1.f / smm;
      for (int k = 0; k < 16; k++) aw_g[b * 16 + k] = e[k] * inv;
    }
    return;
  }
  float* w1t = sm;            // 256*33 = 8448
  float* ns2 = sm + 8448;     // 1792
  int p0 = xb2 * 7;
  for (int i = t; i < 8192; i += 256){
    int o = i >> 8, c = i & 255;
    w1t[c * 33 + o] = sa_w1[i];
  }
  for (int i = t; i < 1792; i += 256){
    int c = i / 7, pl = i - c * 7;
    ns2[i] = normed[(size_t)b * 12544 + c * 49 + p0 + pl];
  }
  __syncthreads();
  if (t < 224){
    int pl = t >> 5, o = t & 31;
    float s = sa_b1[o];
    #pragma unroll 8
    for (int c = 0; c < 256; c++) s += ns2[c * 7 + pl] * w1t[c * 33 + o];
    h1_g[(size_t)b * 1568 + (p0 + pl) * 32 + o] = fmaxf(s, 0.f);
  }
}

__global__ __launch_bounds__(256) void k_pre2(
    const float* __restrict__ x, const float* __restrict__ normed,
    const float* __restrict__ gate_w, const float* __restrict__ gate_b,
    const float* __restrict__ sa_w1, const float* __restrict__ sa_b1,
    const float* __restrict__ ap_w1, const float* __restrict__ ap_b1,
    const float* __restrict__ ap_w2, const float* __restrict__ ap_b2,
    const float* __restrict__ gap_g,
    float* __restrict__ gates_g, float* __restrict__ lnm_g, float* __restrict__ lnr_g,
    float* __restrict__ h1_g, float* __restrict__ aw_g)
{
  __shared__ float sm[10240];
  int bx = blockIdx.x, b = blockIdx.y;
  if (bx < 7)
    dev_pos(x, normed, gate_w, gate_b, gates_g, lnm_g, lnr_g, bx, b, sm);
  else
    dev_h1aw(normed, sa_w1, sa_b1, ap_w1, ap_b1, ap_w2, ap_b2, gap_g, h1_g, aw_g, bx - 7, b, sm);
}

// ---------------------------------------------------------------------------
// dev_spatial / dev_weff / dev_im2col / mfma_gemm_dev  (merged into k_mega1)
// ---------------------------------------------------------------------------
__device__ void dev_spatial(
    const float* __restrict__ normed, const float* __restrict__ h1_g,
    const float* __restrict__ sa_w2, const float* __restrict__ sa_b2,
    const float* __restrict__ sa_g, const float* __restrict__ sa_bb,
    float* __restrict__ spat_g, int gc, int b, float* sm)
{
  float* h1s = sm;           // 49*33 = 1617
  float* w2s = sm + 1617;    // 1024
  int t = threadIdx.x;
  for (int i = t; i < 1568; i += 256){
    int p = i >> 5, o = i & 31;
    h1s[p * 33 + o] = h1_g[(size_t)b * 1568 + i];
  }
  for (int i = t; i < 1024; i += 256) w2s[i] = sa_w2[gc * 1024 + i];
  __syncthreads();
  int wv = t >> 6, lane = t & 63;
  int cg0 = wv * 8;
  const float* nb = normed + (size_t)b * 12544 + (gc * 32 + cg0) * 49;
  float tmp[7];
  float s = 0.f, ss = 0.f;
  #pragma unroll
  for (int j = 0; j < 7; j++){
    int i = lane + 64 * j;
    float v = 0.f;
    if (i < 392){
      int c = i / 49;
      const float* wr = w2s + (cg0 + c) * 32;
      const float* hp = h1s + (i - c * 49) * 33;
      float d = sa_b2[gc * 32 + cg0 + c];
      #pragma unroll
      for (int o = 0; o < 32; o++) d += hp[o] * wr[o];
      v = nb[i] * (1.f + 1.f / (1.f + __expf(-d)));
      s += v; ss += v * v;
    }
    tmp[j] = v;
  }
  for (int off = 32; off; off >>= 1){ s += __shfl_down(s, off); ss += __shfl_down(ss, off); }
  s = __shfl(s, 0); ss = __shfl(ss, 0);
  float m = s / 392.f, rs = rsqrtf(ss / 392.f - m * m + EPS);
  float* sb = spat_g + (size_t)b * 12544 + (gc * 32 + cg0) * 49;
  #pragma unroll
  for (int j = 0; j < 7; j++){
    int i = lane + 64 * j;
    if (i < 392){
      int c = gc * 32 + cg0 + i / 49;
      sb[i] = (tmp[j] - m) * rs * sa_g[c] + sa_bb[c];
    }
  }
}

// weff: thread owns 4 consecutive j; float4 W loads, u32x2 NT stores.
__device__ void dev_weff(
    const float* __restrict__ W, const float* __restrict__ aw, u16* __restrict__ weff, int bx)
{
  const size_t t = ((size_t)bx * 256 + threadIdx.x) * 4;
  float4 A[16];
  #pragma unroll
  for (int k = 0; k < 16; k++) A[k] = *(const float4*)(W + (size_t)k * 1638400 + t);
  #pragma unroll 1
  for (int b = 0; b < 32; b++){
    float s0 = 0.f, s1 = 0.f, s2 = 0.f, s3 = 0.f;
    #pragma unroll
    for (int k = 0; k < 16; k++){
      float a = aw[b * 16 + k];
      s0 += a * A[k].x; s1 += a * A[k].y; s2 += a * A[k].z; s3 += a * A[k].w;
    }
    u32x2 o; o.x = pk2(s0, s1); o.y = pk2(s2, s3);
    __builtin_nontemporal_store(o, (u32x2*)(weff + (size_t)b * 1638400 + t));
  }
}

__device__ void dev_im2col(
    const float* __restrict__ normed, u16* __restrict__ xim, int p, int b, float* sm)
{
  u16* row = (u16*)sm;  // 6400 u16
  int ci = threadIdx.x;
  int py = p / 7, px = p - py * 7;
  const float* nb = normed + (size_t)b * 12544 + ci * 49;
  u16* rp = row + ci * 25;
  #pragma unroll
  for (int sy = 0; sy < 5; sy++){
    int iy = py + sy - 2;
    #pragma unroll
    for (int sx = 0; sx < 5; sx++){
      int ix = px + sx - 2;
      float v = (iy >= 0 && iy < 7 && ix >= 0 && ix < 7) ? nb[iy * 7 + ix] : 0.f;
      rp[sy * 5 + sx] = f2bf(v);
    }
  }
  __syncthreads();
  const u32* rs = (const u32*)row;
  u32* od = (u32*)(xim + (size_t)(b * 49 + p) * 6400);
  for (int i = threadIdx.x; i < 3200; i += 256) od[i] = rs[i];
}

__device__ __forceinline__ void mfma_gemm_dev(
    const float* __restrict__ W, const float* __restrict__ bias,
    const float* __restrict__ act, const float* __restrict__ res,
    float* __restrict__ out, int M, int K, int m0blk, int p0, int b,
    const float* __restrict__ lnm, const float* __restrict__ lnr,
    const float* __restrict__ lng, const float* __restrict__ lnb)
{
  int wv = threadIdx.x >> 6, lane = threadIdx.x & 63;
  int lo = lane & 15, hi = lane >> 4;
  int m0 = m0blk + wv * 32;
  int p = p0 + lo;
  bool pok = p < 49;
  const float* ab = act + (size_t)b * K * 49;
  float lm = 0.f, lr = 0.f;
  if (lng && pok){ lm = lnm[p]; lr = lnr[p]; }
  f32x4 acc0 = {0.f, 0.f, 0.f, 0.f};
  f32x4 acc1 = {0.f, 0.f, 0.f, 0.f};
  const float* wr0 = W + (size_t)(m0 + lo) * K + hi * 8;
  const float* wr1 = W + (size_t)(m0 + 16 + lo) * K + hi * 8;
  for (int k0 = 0; k0 < K; k0 += 32){
    int kb = k0 + hi * 8;
    float4 a0lo = *(const float4*)(wr0 + k0);
    float4 a0hi = *(const float4*)(wr0 + k0 + 4);
    float4 a1lo = *(const float4*)(wr1 + k0);
    float4 a1hi = *(const float4*)(wr1 + k0 + 4);
    float bv[8];
    if (pok){
      const float* ap = ab + (size_t)kb * 49 + p;
      #pragma unroll
      for (int i = 0; i < 8; i++) bv[i] = ap[i * 49];
      if (lng){
        #pragma unroll
        for (int i = 0; i < 8; i++) bv[i] = (bv[i] - lm) * lr * lng[kb + i] + lnb[kb + i];
      }
    } else {
      #pragma unroll
      for (int i = 0; i < 8; i++) bv[i] = 0.f;
    }
    BF8 A0, A1, B;
    A0.u[0] = pk2(a0lo.x, a0lo.y); A0.u[1] = pk2(a0lo.z, a0lo.w);
    A0.u[2] = pk2(a0hi.x, a0hi.y); A0.u[3] = pk2(a0hi.z, a0hi.w);
    A1.u[0] = pk2(a1lo.x, a1lo.y); A1.u[1] = pk2(a1lo.z, a1lo.w);
    A1.u[2] = pk2(a1hi.x, a1hi.y); A1.u[3] = pk2(a1hi.z, a1hi.w);
    B.u[0] = pk2(bv[0], bv[1]); B.u[1] = pk2(bv[2], bv[3]);
    B.u[2] = pk2(bv[4], bv[5]); B.u[3] = pk2(bv[6], bv[7]);
    acc0 = __builtin_amdgcn_mfma_f32_16x16x32_bf16(A0.v, B.v, acc0, 0, 0, 0);
    acc1 = __builtin_amdgcn_mfma_f32_16x16x32_bf16(A1.v, B.v, acc1, 0, 0, 0);
  }
  if (pok){
    #pragma unroll
    for (int r = 0; r < 4; r++){
      int m = m0 + hi * 4 + r;
      size_t idx = ((size_t)b * M + m) * 49 + p;
      float v = acc0[r] + (bias ? bias[m] : 0.f);
      if (res) v += res[idx];
      out[idx] = v;
      int m2 = m + 16;
      size_t idx2 = idx + 16 * 49;
      float v2 = acc1[r] + (bias ? bias[m2] : 0.f);
      if (res) v2 += res[idx2];
      out[idx2] = v2;
    }
  }
}

// k_mega1: [0,1600) weff | [1600,3904) qkv | [3904,5472) im2col | [5472,5728) spatial
__global__ __launch_bounds__(256) void k_mega1(
    const float* __restrict__ ad_dir_w, const float* __restrict__ aw, u16* __restrict__ weff,
    const float* __restrict__ ra_w, const float* __restrict__ aa_w,
    const float* __restrict__ xr, const float* __restrict__ normed,
    const float* __restrict__ lnm, const float* __restrict__ lnr,
    const float* __restrict__ ln_g, const float* __restrict__ ln_b,
    float* __restrict__ ra_qkv, float* __restrict__ aa_qkv,
    u16* __restrict__ xim,
    const float* __restrict__ h1_g, const float* __restrict__ sa_w2, const float* __restrict__ sa_b2,
    const float* __restrict__ sa_g, const float* __restrict__ sa_bb, float* __restrict__ spat_g)
{
  __shared__ float sm[3300];
  int id = blockIdx.x;
  if (id < 1600){
    dev_weff(ad_dir_w, aw, weff, id);
  } else if (id < 3904){
    int q = id - 1600;
    int bx = q % 72, b = q / 72;
    if (bx < 24){
      int m0 = (bx >> 2) * 128, p0 = (bx & 3) * 16;
      mfma_gemm_dev(ra_w, nullptr, xr, nullptr, ra_qkv, 768, 256, m0, p0, b,
                    nullptr, nullptr, nullptr, nullptr);
    } else {
      int bx2 = bx - 24;
      int m0 = (bx2 >> 2) * 128, p0 = (bx2 & 3) * 16;
      mfma_gemm_dev(aa_w, nullptr, normed, nullptr, aa_qkv, 1536, 256, m0, p0, b,
                    lnm + b * 49, lnr + b * 49, ln_g, ln_b);
    }
  } else if (id < 5472){
    int q = id - 3904;
    dev_im2col(normed, xim, q % 49, q / 49, sm);
  } else {
    int q = id - 5472;
    dev_spatial(normed, h1_g, sa_w2, sa_b2, sa_g, sa_bb, spat_g, q % 8, q / 8, sm);
  }
}

// ---------------------------------------------------------------------------
// dev_conv / dev_attn  (merged into k_mega2)
// ---------------------------------------------------------------------------
__device__ void dev_conv(
    const u16* __restrict__ weff, const u16* __restrict__ xim, float* __restrict__ partial,
    int bx, int b)
{
  int mblk = bx >> 3, kp = bx & 7;
  int wv = threadIdx.x >> 6, lane = threadIdx.x & 63;
  int lo = lane & 15, hi = lane >> 4;
  int co0 = mblk * 128 + wv * 32;
  const u16* wr0 = weff + (size_t)b * 1638400 + (size_t)(co0 + lo) * 6400 + kp * 800 + hi * 8;
  const u16* wr1 = wr0 + 16 * 6400;
  const u16* xb = xim + (size_t)b * 313600 + (size_t)lo * 6400 + kp * 800 + hi * 8;
  f32x4 acc[2][4];
  #pragma unroll
  for (int mi = 0; mi < 2; mi++)
    #pragma unroll
    for (int pi = 0; pi < 4; pi++) acc[mi][pi] = (f32x4){0.f, 0.f, 0.f, 0.f};
  #pragma unroll 1
  for (int ks = 0; ks < 25; ks++){
    int k0 = ks * 32;
    bf16x8 A0 = __builtin_nontemporal_load((const bf16x8*)(wr0 + k0));
    bf16x8 A1 = __builtin_nontemporal_load((const bf16x8*)(wr1 + k0));
    bf16x8 B0 = *(const bf16x8*)(xb + k0);
    bf16x8 B1 = *(const bf16x8*)(xb + 16 * 6400 + k0);
    bf16x8 B2 = *(const bf16x8*)(xb + 32 * 6400 + k0);
    bf16x8 B3 = *(const bf16x8*)(xb + 48 * 6400 + k0);
    acc[0][0] = __builtin_amdgcn_mfma_f32_16x16x32_bf16(A0, B0, acc[0][0], 0, 0, 0);
    acc[0][1] = __builtin_amdgcn_mfma_f32_16x16x32_bf16(A0, B1, acc[0][1], 0, 0, 0);
    acc[0][2] = __builtin_amdgcn_mfma_f32_16x16x32_bf16(A0, B2, acc[0][2], 0, 0, 0);
    acc[0][3] = __builtin_amdgcn_mfma_f32_16x16x32_bf16(A0, B3, acc[0][3], 0, 0, 0);
    acc[1][0] = __builtin_amdgcn_mfma_f32_16x16x32_bf16(A1, B0, acc[1][0], 0, 0, 0);
    acc[1][1] = __builtin_amdgcn_mfma_f32_16x16x32_bf16(A1, B1, acc[1][1], 0, 0, 0);
    acc[1][2] = __builtin_amdgcn_mfma_f32_16x16x32_bf16(A1, B2, acc[1][2], 0, 0, 0);
    acc[1][3] = __builtin_amdgcn_mfma_f32_16x16x32_bf16(A1, B3, acc[1][3], 0, 0, 0);
  }
  float* pb = partial + ((size_t)kp * 32 + b) * 12544;
  #pragma unroll
  for (int mi = 0; mi < 2; mi++){
    #pragma unroll
    for (int pi = 0; pi < 4; pi++){
      int p = pi * 16 + lo;
      if (p < 49){
        #pragma unroll
        for (int r = 0; r < 4; r++){
          int co = co0 + mi * 16 + hi * 4 + r;
          pb[co * 49 + p] = acc[mi][pi][r];
        }
      }
    }
  }
}

__device__ __forceinline__ void softmax_rows(float* sc, int tid)
{
  int r = tid >> 2, q = tid & 3;
  if (r < 49){
    float* row = sc + r * 52;
    float mx = -1e30f;
    for (int j = q; j < 49; j += 4) mx = fmaxf(mx, row[j]);
    mx = fmaxf(mx, __shfl_xor(mx, 1));
    mx = fmaxf(mx, __shfl_xor(mx, 2));
    float sm = 0.f;
    for (int j = q; j < 49; j += 4){ float e = __expf(row[j] - mx); row[j] = e; sm += e; }
    sm += __shfl_xor(sm, 1);
    sm += __shfl_xor(sm, 2);
    float inv = 1.f / sm;
    for (int j = q; j < 49; j += 4) row[j] *= inv;
  }
}

__device__ void dev_attn(
    const float* __restrict__ ra_qkv, const float* __restrict__ aa_qkv,
    const float* __restrict__ relpos,
    float* __restrict__ r0, float* __restrict__ ao,
    int xb2, int b, float* sm)
{
  if (xb2 < 8){
    int hd = xb2;
    float* qs = sm; float* ks = sm + 1617; float* vs = sm + 3234; float* sc = sm + 4851;
    const float* base = ra_qkv + (size_t)b * 768 * 49;
    for (int i = threadIdx.x; i < 1568; i += 256){
      int d = i / 49, tok = i - d * 49;
      qs[tok * 33 + d] = base[(hd * 32 + d) * 49 + tok];
      ks[tok * 33 + d] = base[(256 + hd * 32 + d) * 49 + tok];
      vs[tok * 33 + d] = base[(512 + hd * 32 + d) * 49 + tok];
    }
    __syncthreads();
    const float scale = 0.17677669529663687f;
    for (int it = threadIdx.x; it < 2401; it += 256){
      int i = it / 49, j = it - i * 49;
      float s = 0.f;
      #pragma unroll
      for (int d = 0; d < 32; d++) s += qs[i * 33 + d] * ks[j * 33 + d];
      sc[i * 52 + j] = s * scale;
    }
    __syncthreads();
    softmax_rows(sc, threadIdx.x);
    __syncthreads();
    for (int it = threadIdx.x; it < 1568; it += 256){
      int d = it / 49, i = it - d * 49;
      float o = 0.f;
      for (int j = 0; j < 49; j++) o += sc[i * 52 + j] * vs[j * 33 + d];
      r0[((size_t)b * 256 + hd * 32 + d) * 49 + i] = o;
    }
  } else {
    int hd = xb2 - 8;
    float* qs = sm; float* ks = sm + 3185; float* vs = sm + 6370; float* sc = sm + 9555;
    const float* base = aa_qkv + (size_t)b * 1536 * 49;
    for (int i = threadIdx.x; i < 3136; i += 256){
      int d = i / 49, tok = i - d * 49;
      qs[tok * 65 + d] = base[(hd * 64 + d) * 49 + tok];
      ks[tok * 65 + d] = base[(512 + hd * 64 + d) * 49 + tok];
      vs[tok * 65 + d] = base[(1024 + hd * 64 + d) * 49 + tok];
    }
    __syncthreads();
    for (int it = threadIdx.x; it < 2401; it += 256){
      int i = it / 49, j = it - i * 49;
      float s = 0.f;
      #pragma unroll
      for (int d = 0; d < 64; d++) s += qs[i * 65 + d] * ks[j * 65 + d];
      int dy = j / 7 - i / 7 + 6, dx = j % 7 - i % 7 + 6;
      sc[i * 52 + j] = s * 0.125f + relpos[(dy * 13 + dx) * 8 + hd];
    }
    __syncthreads();
    softmax_rows(sc, threadIdx.x);
    __syncthreads();
    for (int it = threadIdx.x; it < 3136; it += 256){
      int d = it / 49, i = it - d * 49;
      float o = 0.f;
      for (int j = 0; j < 49; j++) o += sc[i * 52 + j] * vs[j * 65 + d];
      ao[((size_t)b * 512 + hd * 64 + d) * 49 + i] = o;
    }
  }
}

// k_mega2: [0,512) conv | [512,1024) attn
__global__ __launch_bounds__(256) void k_mega2(
    const u16* __restrict__ weff, const u16* __restrict__ xim, float* __restrict__ partial,
    const float* __restrict__ ra_qkv, const float* __restrict__ aa_qkv,
    const float* __restrict__ relpos, float* __restrict__ r0, float* __restrict__ ao)
{
  __shared__ float sm[12103];
  int id = blockIdx.x;
  if (id < 512){
    dev_conv(weff, xim, partial, id % 16, id / 16);
  } else {
    int q = id - 512;
    dev_attn(ra_qkv, aa_qkv, relpos, r0, ao, q % 16, q / 16, sm);
  }
}

// k_conv_reduce: comb = sum of 8 k-partials
__global__ __launch_bounds__(256) void k_conv_reduce(
    const float* __restrict__ part, float* __restrict__ comb)
{
  int i = blockIdx.x * 256 + threadIdx.x;
  if (i >= 100352) return;
  float a0 = 0.f, a1 = 0.f, a2 = 0.f, a3 = 0.f;
  #pragma unroll
  for (int p = 0; p < 8; p++){
    float4 v = ((const float4*)part)[(size_t)p * 100352 + i];
    a0 += v.x; a1 += v.y; a2 += v.z; a3 += v.w;
  }
  float4 o; o.x = a0; o.y = a1; o.z = a2; o.w = a3;
  ((float4*)comb)[i] = o;
}

// merged projections: bx<8 ra_proj, <16 aa_out (K=512), else ad_proj
__global__ __launch_bounds__(256) void k_proj3(
    const float* __restrict__ ra_pw, const float* __restrict__ ra_pb, const float* __restrict__ r0,
    const float* __restrict__ aa_ow, const float* __restrict__ aa_ob, const float* __restrict__ aa_o,
    const float* __restrict__ ad_pw, const float* __restrict__ ad_pb, const float* __restrict__ comb,
    const float* __restrict__ normed,
    float* __restrict__ rotf, float* __restrict__ angf, float* __restrict__ adpf)
{
  int bx = blockIdx.x, b = blockIdx.y;
  if (bx < 8){
    int m0 = (bx >> 2) * 128, p0 = (bx & 3) * 16;
    mfma_gemm_dev(ra_pw, ra_pb, r0, normed, rotf, 256, 256, m0, p0, b,
                  nullptr, nullptr, nullptr, nullptr);
  } else if (bx < 16){
    int bx2 = bx - 8;
    int m0 = (bx2 >> 2) * 128, p0 = (bx2 & 3) * 16;
    mfma_gemm_dev(aa_ow, aa_ob, aa_o, normed, angf, 256, 512, m0, p0, b,
                  nullptr, nullptr, nullptr, nullptr);
  } else {
    int bx2 = bx - 16;
    int m0 = (bx2 >> 2) * 128, p0 = (bx2 & 3) * 16;
    mfma_gemm_dev(ad_pw, ad_pb, comb, normed, adpf, 256, 256, m0, p0, b,
                  nullptr, nullptr, nullptr, nullptr);
  }
}

// k_final: out = proj_w @ fused + proj_b + x, fused computed on the fly
__global__ __launch_bounds__(256) void k_final(
    const float* __restrict__ proj_w, const float* __restrict__ proj_b,
    const float* __restrict__ spat, const float* __restrict__ rotf,
    const float* __restrict__ angf, const float* __restrict__ adpf,
    const float* __restrict__ gates, const float* __restrict__ x,
    float* __restrict__ out)
{
  int bx = blockIdx.x, b = blockIdx.y;
  int wv = threadIdx.x >> 6, lane = threadIdx.x & 63;
  int lo = lane & 15, hi = lane >> 4;
  int m0 = (bx >> 2) * 128 + wv * 32;
  int p0 = (bx & 3) * 16;
  int p = p0 + lo;
  bool pok = p < 49;
  float g0 = 0.f, g1 = 0.f, g2 = 0.f, g3 = 0.f;
  if (pok){
    const float* g = gates + (size_t)b * 196 + p;
    g0 = g[0]; g1 = g[49]; g2 = g[98]; g3 = g[147];
  }
  size_t boff = (size_t)b * 12544;
  f32x4 acc0 = {0.f, 0.f, 0.f, 0.f};
  f32x4 acc1 = {0.f, 0.f, 0.f, 0.f};
  const float* wr0 = proj_w + (size_t)(m0 + lo) * 256 + hi * 8;
  const float* wr1 = wr0 + 16 * 256;
  for (int k0 = 0; k0 < 256; k0 += 32){
    int kb = k0 + hi * 8;
    float4 a0lo = *(const float4*)(wr0 + k0);
    float4 a0hi = *(const float4*)(wr0 + k0 + 4);
    float4 a1lo = *(const float4*)(wr1 + k0);
    float4 a1hi = *(const float4*)(wr1 + k0 + 4);
    float bv[8];
    if (pok){
      size_t base = boff + (size_t)kb * 49 + p;
      #pragma unroll
      for (int i = 0; i < 8; i++){
        size_t idx = base + (size_t)i * 49;
        bv[i] = spat[idx] * g0 + rotf[idx] * g1 + angf[idx] * g2 + adpf[idx] * g3;
      }
    } else {
      #pragma unroll
      for (int i = 0; i < 8; i++) bv[i] = 0.f;
    }
    BF8 A0, A1, B;
    A0.u[0] = pk2(a0lo.x, a0lo.y); A0.u[1] = pk2(a0lo.z, a0lo.w);
    A0.u[2] = pk2(a0hi.x, a0hi.y); A0.u[3] = pk2(a0hi.z, a0hi.w);
    A1.u[0] = pk2(a1lo.x, a1lo.y); A1.u[1] = pk2(a1lo.z, a1lo.w);
    A1.u[2] = pk2(a1hi.x, a1hi.y); A1.u[3] = pk2(a1hi.z, a1hi.w);
    B.u[0] = pk2(bv[0], bv[1]); B.u[1] = pk2(bv[2], bv[3]);
    B.u[2] = pk2(bv[4], bv[5]); B.u[3] = pk2(bv[6], bv[7]);
    acc0 = __builtin_amdgcn_mfma_f32_16x16x32_bf16(A0.v, B.v, acc0, 0, 0, 0);
    acc1 = __builtin_amdgcn_mfma_f32_16x16x32_bf16(A1.v, B.v, acc1, 0, 0, 0);
  }
  if (pok){
    #pragma unroll
    for (int r = 0; r < 4; r++){
      int m = m0 + hi * 4 + r;
      size_t idx = boff + (size_t)m * 49 + p;
      out[idx] = acc0[r] + proj_b[m] + x[idx];
      int m2 = m + 16;
      size_t idx2 = idx + 16 * 49;
      out[idx2] = acc1[r] + proj_b[m2] + x[idx2];
    }
  }
}

// ---------------------------------------------------------------------------
extern "C" void kernel_launch(void* const* d_in, const int* in_sizes, int n_in,
                              void* d_out, int out_size, void* d_ws, size_t ws_size,
                              hipStream_t stream)
{
  const float* x        = (const float*)d_in[0];
  const float* gn_g     = (const float*)d_in[1];
  const float* gn_b     = (const float*)d_in[2];
  const float* sa_w1    = (const float*)d_in[3];
  const float* sa_b1    = (const float*)d_in[4];
  const float* sa_w2    = (const float*)d_in[5];
  const float* sa_b2    = (const float*)d_in[6];
  const float* sa_gn_g  = (const float*)d_in[7];
  const float* sa_gn_b  = (const float*)d_in[8];
  const float* ra_gn_g  = (const float*)d_in[9];
  const float* ra_gn_b  = (const float*)d_in[10];
  const float* ra_qkv_w = (const float*)d_in[11];
  const float* ra_proj_w= (const float*)d_in[12];
  const float* ra_proj_b= (const float*)d_in[13];
  const float* aa_ln_g  = (const float*)d_in[14];
  const float* aa_ln_b  = (const float*)d_in[15];
  const float* aa_qkv_w = (const float*)d_in[16];
  const float* aa_relpos= (const float*)d_in[17];
  const float* aa_out_w = (const float*)d_in[18];
  const float* aa_out_b = (const float*)d_in[19];
  const float* ad_dir_w = (const float*)d_in[20];
  const float* ad_ap_w1 = (const float*)d_in[21];
  const float* ad_ap_b1 = (const float*)d_in[22];
  const float* ad_ap_w2 = (const float*)d_in[23];
  const float* ad_ap_b2 = (const float*)d_in[24];
  const float* ad_proj_w= (const float*)d_in[25];
  const float* ad_proj_b= (const float*)d_in[26];
  const float* gate_w   = (const float*)d_in[27];
  const float* gate_b   = (const float*)d_in[28];
  const float* proj_w   = (const float*)d_in[29];
  const float* proj_b   = (const float*)d_in[30];

  char* ws = (char*)d_ws;
  float* normed    = (float*)(ws + 0);
  float* xr        = (float*)(ws + 1605632);
  float* h1_g      = (float*)(ws + 3211264);
  float* lnm       = (float*)(ws + 3420160);
  float* lnr       = (float*)(ws + 3426560);
  float* spatial   = (float*)(ws + 4816896);
  float* rotf      = (float*)(ws + 6422528);
  float* anglef    = (float*)(ws + 8028160);
  float* adaptf    = (float*)(ws + 9633792);
  float* r0        = (float*)(ws + 12845056);
  float* gap       = (float*)(ws + 14450688);
  float* aw        = (float*)(ws + 14483456);
  float* gates     = (float*)(ws + 14485504);
  float* ra_qkv    = (float*)(ws + 14510592);
  float* aa_qkv    = (float*)(ws + 19327488);
  float* aa_o      = (float*)(ws + 28961280);
  float* comb      = (float*)(ws + 32172544);
  float* partial   = (float*)(ws + 33778176);   // 12,845,056 B
  u16*   xim       = (u16*)  (ws + 46623232);   // 20,070,400 B
  u16*   weff      = (u16*)  (ws + 66693632);   // 104,857,600 B

  float* out = (float*)d_out;

  k_prep1<<<dim3(8, 32), 256, 0, stream>>>(x, gn_g, gn_b, ra_gn_g, ra_gn_b, normed, xr, gap);
  k_pre2<<<dim3(15, 32), 256, 0, stream>>>(x, normed, gate_w, gate_b,
                                           sa_w1, sa_b1, ad_ap_w1, ad_ap_b1, ad_ap_w2, ad_ap_b2,
                                           gap, gates, lnm, lnr, h1_g, aw);
  k_mega1<<<dim3(5728), 256, 0, stream>>>(ad_dir_w, aw, weff,
                                          ra_qkv_w, aa_qkv_w, xr, normed,
                                          lnm, lnr, aa_ln_g, aa_ln_b, ra_qkv, aa_qkv,
                                          xim,
                                          h1_g, sa_w2, sa_b2, sa_gn_g, sa_gn_b, spatial);
  k_mega2<<<dim3(1024), 256, 0, stream>>>(weff, xim, partial,
                                          ra_qkv, aa_qkv, aa_relpos, r0, aa_o);
  k_conv_reduce<<<dim3(392), 256, 0, stream>>>(partial, comb);
  k_proj3<<<dim3(24, 32), 256, 0, stream>>>(ra_proj_w, ra_proj_b, r0,
                                            aa_out_w, aa_out_b, aa_o,
                                            ad_proj_w, ad_proj_b, comb,
                                            normed, rotf, anglef, adaptf);
  k_final<<<dim3(8, 32), 256, 0, stream>>>(proj_w, proj_b, spatial, rotf, anglef, adaptf,
                                           gates, x, out);
}

// Round 13
// 250.232 us; speedup vs baseline: 1.2019x; 1.0618x over previous
//
#include <hip/hip_runtime.h>

#define EPS 1e-5f
typedef unsigned short u16;
typedef unsigned int u32;
typedef float f32x4 __attribute__((ext_vector_type(4)));
typedef short bf16x8 __attribute__((ext_vector_type(8)));
typedef unsigned int u32x2 __attribute__((ext_vector_type(2)));

__device__ __forceinline__ float bf2f(u16 h){
  return __uint_as_float(((u32)h) << 16);
}
__device__ __forceinline__ u16 f2bf(float f){
  u32 u = __float_as_uint(f);
  u += 0x7fffu + ((u >> 16) & 1u);
  return (u16)(u >> 16);
}
__device__ __forceinline__ u32 pk2(float lo, float hi){
  return ((u32)f2bf(hi) << 16) | (u32)f2bf(lo);
}
union BF8 { bf16x8 v; u32 u[4]; };

// ---------------------------------------------------------------------------
// k_prep1: GN(x)->normed, GN(normed)->xr, gap. grid(8,32).
// ---------------------------------------------------------------------------
__global__ __launch_bounds__(256) void k_prep1(
    const float* __restrict__ x, const float* __restrict__ gn_g, const float* __restrict__ gn_b,
    const float* __restrict__ ra_g, const float* __restrict__ ra_b,
    float* __restrict__ normed, float* __restrict__ xr, float* __restrict__ gap)
{
  int ch = blockIdx.x, b = blockIdx.y;
  int c0 = ch * 32;
  __shared__ float xs[1568], ns[1568];
  const float* xb = x + ((size_t)b * 256 + c0) * 49;
  for (int i = threadIdx.x; i < 1568; i += 256) xs[i] = xb[i];
  __syncthreads();
  int wv = threadIdx.x >> 6, lane = threadIdx.x & 63;
  const float* gsrc = xs + wv * 392;
  float* ndst = ns + wv * 392;
  float s = 0.f, ss = 0.f;
  for (int i = lane; i < 392; i += 64){ float v = gsrc[i]; s += v; ss += v * v; }
  for (int off = 32; off; off >>= 1){ s += __shfl_down(s, off); ss += __shfl_down(ss, off); }
  s = __shfl(s, 0); ss = __shfl(ss, 0);
  float m = s / 392.f, rs = rsqrtf(ss / 392.f - m * m + EPS);
  for (int i = lane; i < 392; i += 64){
    int c = c0 + wv * 8 + i / 49;
    ndst[i] = (gsrc[i] - m) * rs * gn_g[c] + gn_b[c];
  }
  __syncthreads();
  float* nb = normed + ((size_t)b * 256 + c0) * 49;
  for (int i = threadIdx.x; i < 1568; i += 256) nb[i] = ns[i];
  if (threadIdx.x < 32){
    float g2 = 0.f; const float* rp = ns + threadIdx.x * 49;
    for (int p = 0; p < 49; p++) g2 += rp[p];
    gap[(size_t)b * 256 + c0 + threadIdx.x] = g2 * (1.f / 49.f);
  }
  s = 0.f; ss = 0.f;
  for (int i = lane; i < 392; i += 64){ float v = ndst[i]; s += v; ss += v * v; }
  for (int off = 32; off; off >>= 1){ s += __shfl_down(s, off); ss += __shfl_down(ss, off); }
  s = __shfl(s, 0); ss = __shfl(ss, 0);
  m = s / 392.f; rs = rsqrtf(ss / 392.f - m * m + EPS);
  float* xrb = xr + ((size_t)b * 256 + c0) * 49;
  for (int i = lane; i < 392; i += 64){
    int c = c0 + wv * 8 + i / 49;
    xrb[wv * 392 + i] = (ndst[i] - m) * rs * ra_g[c] + ra_b[c];
  }
}

// ---------------------------------------------------------------------------
// dev_pos / dev_h1aw  (merged into k_pre2)
// ---------------------------------------------------------------------------
__device__ void dev_pos(
    const float* __restrict__ x, const float* __restrict__ normed,
    const float* __restrict__ gate_w, const float* __restrict__ gate_b,
    float* __restrict__ gates_g, float* __restrict__ lnm_g, float* __restrict__ lnr_g,
    int pc, int b, float* sm)
{
  float* gw = sm;  // 1024
  for (int i = threadIdx.x; i < 1024; i += 256) gw[i] = gate_w[i];
  __syncthreads();
  int wv = threadIdx.x >> 6, lane = threadIdx.x & 63;
  for (int pi = wv; pi < 7; pi += 4){
    int p = pc * 7 + pi;
    const float* nb = normed + (size_t)b * 12544 + p;
    const float* xb = x + (size_t)b * 12544 + p;
    float s = 0.f, ss = 0.f, g0 = 0.f, g1 = 0.f, g2 = 0.f, g3 = 0.f;
    for (int c = lane; c < 256; c += 64){
      float nv = nb[c * 49];
      float xv = xb[c * 49];
      s += nv; ss += nv * nv;
      g0 += xv * gw[c]; g1 += xv * gw[256 + c];
      g2 += xv * gw[512 + c]; g3 += xv * gw[768 + c];
    }
    for (int off = 32; off; off >>= 1){
      s += __shfl_down(s, off); ss += __shfl_down(ss, off);
      g0 += __shfl_down(g0, off); g1 += __shfl_down(g1, off);
      g2 += __shfl_down(g2, off); g3 += __shfl_down(g3, off);
    }
    if (lane == 0){
      float mu = s / 256.f;
      lnm_g[b * 49 + p] = mu;
      lnr_g[b * 49 + p] = rsqrtf(ss / 256.f - mu * mu + EPS);
      g0 += gate_b[0]; g1 += gate_b[1]; g2 += gate_b[2]; g3 += gate_b[3];
      float mx = fmaxf(fmaxf(g0, g1), fmaxf(g2, g3));
      float e0 = __expf(g0 - mx), e1 = __expf(g1 - mx), e2 = __expf(g2 - mx), e3 = __expf(g3 - mx);
      float inv = 1.f / (e0 + e1 + e2 + e3);
      float* gg = gates_g + (size_t)b * 196 + p;
      gg[0] = e0 * inv; gg[49] = e1 * inv; gg[98] = e2 * inv; gg[147] = e3 * inv;
    }
  }
}

__device__ void dev_h1aw(
    const float* __restrict__ normed, const float* __restrict__ sa_w1, const float* __restrict__ sa_b1,
    const float* __restrict__ ap_w1, const float* __restrict__ ap_b1,
    const float* __restrict__ ap_w2, const float* __restrict__ ap_b2,
    const float* __restrict__ gap_g,
    float* __restrict__ h1_g, float* __restrict__ aw_g,
    int xb2, int b, float* sm)
{
  int t = threadIdx.x;
  if (xb2 == 7){
    float* gaps = sm; float* h = sm + 256; float* lg = sm + 384;
    gaps[t] = gap_g[b * 256 + t];
    __syncthreads();
    if (t < 128){
      float s = ap_b1[t];
      const float* wr = ap_w1 + t * 256;
      #pragma unroll 4
      for (int c = 0; c < 256; c++) s += gaps[c] * wr[c];
      h[t] = fmaxf(s, 0.f);
    }
    __syncthreads();
    if (t < 16){
      float s = ap_b2[t];
      const float* wr = ap_w2 + t * 128;
      #pragma unroll 4
      for (int o = 0; o < 128; o++) s += h[o] * wr[o];
      lg[t] = s;
    }
    __syncthreads();
    if (t == 0){
      float mx = -1e30f;
      for (int k = 0; k < 16; k++) mx = fmaxf(mx, lg[k]);
      float e[16], smm = 0.f;
      for (int k = 0; k < 16; k++){ e[k] = __expf(lg[k] - mx); smm += e[k]; }
      float inv = 1.f / smm;
      for (int k = 0; k < 16; k++) aw_g[b * 16 + k] = e[k] * inv;
    }
    return;
  }
  float* w1t = sm;            // 256*33 = 8448
  float* ns2 = sm + 8448;     // 1792
  int p0 = xb2 * 7;
  for (int i = t; i < 8192; i += 256){
    int o = i >> 8, c = i & 255;
    w1t[c * 33 + o] = sa_w1[i];
  }
  for (int i = t; i < 1792; i += 256){
    int c = i / 7, pl = i - c * 7;
    ns2[i] = normed[(size_t)b * 12544 + c * 49 + p0 + pl];
  }
  __syncthreads();
  if (t < 224){
    int pl = t >> 5, o = t & 31;
    float s = sa_b1[o];
    #pragma unroll 8
    for (int c = 0; c < 256; c++) s += ns2[c * 7 + pl] * w1t[c * 33 + o];
    h1_g[(size_t)b * 1568 + (p0 + pl) * 32 + o] = fmaxf(s, 0.f);
  }
}

__global__ __launch_bounds__(256) void k_pre2(
    const float* __restrict__ x, const float* __restrict__ normed,
    const float* __restrict__ gate_w, const float* __restrict__ gate_b,
    const float* __restrict__ sa_w1, const float* __restrict__ sa_b1,
    const float* __restrict__ ap_w1, const float* __restrict__ ap_b1,
    const float* __restrict__ ap_w2, const float* __restrict__ ap_b2,
    const float* __restrict__ gap_g,
    float* __restrict__ gates_g, float* __restrict__ lnm_g, float* __restrict__ lnr_g,
    float* __restrict__ h1_g, float* __restrict__ aw_g)
{
  __shared__ float sm[10240];
  int bx = blockIdx.x, b = blockIdx.y;
  if (bx < 7)
    dev_pos(x, normed, gate_w, gate_b, gates_g, lnm_g, lnr_g, bx, b, sm);
  else
    dev_h1aw(normed, sa_w1, sa_b1, ap_w1, ap_b1, ap_w2, ap_b2, gap_g, h1_g, aw_g, bx - 7, b, sm);
}

// ---------------------------------------------------------------------------
// dev_spatial / dev_weff / dev_im2col / mfma_gemm_dev  (merged into k_mega1)
// ---------------------------------------------------------------------------
__device__ void dev_spatial(
    const float* __restrict__ normed, const float* __restrict__ h1_g,
    const float* __restrict__ sa_w2, const float* __restrict__ sa_b2,
    const float* __restrict__ sa_g, const float* __restrict__ sa_bb,
    float* __restrict__ spat_g, int gc, int b, float* sm)
{
  float* h1s = sm;           // 49*33 = 1617
  float* w2s = sm + 1617;    // 1024
  int t = threadIdx.x;
  for (int i = t; i < 1568; i += 256){
    int p = i >> 5, o = i & 31;
    h1s[p * 33 + o] = h1_g[(size_t)b * 1568 + i];
  }
  for (int i = t; i < 1024; i += 256) w2s[i] = sa_w2[gc * 1024 + i];
  __syncthreads();
  int wv = t >> 6, lane = t & 63;
  int cg0 = wv * 8;
  const float* nb = normed + (size_t)b * 12544 + (gc * 32 + cg0) * 49;
  float tmp[7];
  float s = 0.f, ss = 0.f;
  #pragma unroll
  for (int j = 0; j < 7; j++){
    int i = lane + 64 * j;
    float v = 0.f;
    if (i < 392){
      int c = i / 49;
      const float* wr = w2s + (cg0 + c) * 32;
      const float* hp = h1s + (i - c * 49) * 33;
      float d = sa_b2[gc * 32 + cg0 + c];
      #pragma unroll
      for (int o = 0; o < 32; o++) d += hp[o] * wr[o];
      v = nb[i] * (1.f + 1.f / (1.f + __expf(-d)));
      s += v; ss += v * v;
    }
    tmp[j] = v;
  }
  for (int off = 32; off; off >>= 1){ s += __shfl_down(s, off); ss += __shfl_down(ss, off); }
  s = __shfl(s, 0); ss = __shfl(ss, 0);
  float m = s / 392.f, rs = rsqrtf(ss / 392.f - m * m + EPS);
  float* sb = spat_g + (size_t)b * 12544 + (gc * 32 + cg0) * 49;
  #pragma unroll
  for (int j = 0; j < 7; j++){
    int i = lane + 64 * j;
    if (i < 392){
      int c = gc * 32 + cg0 + i / 49;
      sb[i] = (tmp[j] - m) * rs * sa_g[c] + sa_bb[c];
    }
  }
}

// weff: thread owns 4 consecutive j; float4 W loads, u32x2 NT stores.
__device__ void dev_weff(
    const float* __restrict__ W, const float* __restrict__ aw, u16* __restrict__ weff, int bx)
{
  const size_t t = ((size_t)bx * 256 + threadIdx.x) * 4;
  float4 A[16];
  #pragma unroll
  for (int k = 0; k < 16; k++) A[k] = *(const float4*)(W + (size_t)k * 1638400 + t);
  #pragma unroll 1
  for (int b = 0; b < 32; b++){
    float s0 = 0.f, s1 = 0.f, s2 = 0.f, s3 = 0.f;
    #pragma unroll
    for (int k = 0; k < 16; k++){
      float a = aw[b * 16 + k];
      s0 += a * A[k].x; s1 += a * A[k].y; s2 += a * A[k].z; s3 += a * A[k].w;
    }
    u32x2 o; o.x = pk2(s0, s1); o.y = pk2(s2, s3);
    __builtin_nontemporal_store(o, (u32x2*)(weff + (size_t)b * 1638400 + t));
  }
}

__device__ void dev_im2col(
    const float* __restrict__ normed, u16* __restrict__ xim, int p, int b, float* sm)
{
  u16* row = (u16*)sm;  // 6400 u16
  int ci = threadIdx.x;
  int py = p / 7, px = p - py * 7;
  const float* nb = normed + (size_t)b * 12544 + ci * 49;
  u16* rp = row + ci * 25;
  #pragma unroll
  for (int sy = 0; sy < 5; sy++){
    int iy = py + sy - 2;
    #pragma unroll
    for (int sx = 0; sx < 5; sx++){
      int ix = px + sx - 2;
      float v = (iy >= 0 && iy < 7 && ix >= 0 && ix < 7) ? nb[iy * 7 + ix] : 0.f;
      rp[sy * 5 + sx] = f2bf(v);
    }
  }
  __syncthreads();
  const u32* rs = (const u32*)row;
  u32* od = (u32*)(xim + (size_t)(b * 49 + p) * 6400);
  for (int i = threadIdx.x; i < 3200; i += 256) od[i] = rs[i];
}

__device__ __forceinline__ void mfma_gemm_dev(
    const float* __restrict__ W, const float* __restrict__ bias,
    const float* __restrict__ act, const float* __restrict__ res,
    float* __restrict__ out, int M, int K, int m0blk, int p0, int b,
    const float* __restrict__ lnm, const float* __restrict__ lnr,
    const float* __restrict__ lng, const float* __restrict__ lnb)
{
  int wv = threadIdx.x >> 6, lane = threadIdx.x & 63;
  int lo = lane & 15, hi = lane >> 4;
  int m0 = m0blk + wv * 32;
  int p = p0 + lo;
  bool pok = p < 49;
  const float* ab = act + (size_t)b * K * 49;
  float lm = 0.f, lr = 0.f;
  if (lng && pok){ lm = lnm[p]; lr = lnr[p]; }
  f32x4 acc0 = {0.f, 0.f, 0.f, 0.f};
  f32x4 acc1 = {0.f, 0.f, 0.f, 0.f};
  const float* wr0 = W + (size_t)(m0 + lo) * K + hi * 8;
  const float* wr1 = W + (size_t)(m0 + 16 + lo) * K + hi * 8;
  for (int k0 = 0; k0 < K; k0 += 32){
    int kb = k0 + hi * 8;
    float4 a0lo = *(const float4*)(wr0 + k0);
    float4 a0hi = *(const float4*)(wr0 + k0 + 4);
    float4 a1lo = *(const float4*)(wr1 + k0);
    float4 a1hi = *(const float4*)(wr1 + k0 + 4);
    float bv[8];
    if (pok){
      const float* ap = ab + (size_t)kb * 49 + p;
      #pragma unroll
      for (int i = 0; i < 8; i++) bv[i] = ap[i * 49];
      if (lng){
        #pragma unroll
        for (int i = 0; i < 8; i++) bv[i] = (bv[i] - lm) * lr * lng[kb + i] + lnb[kb + i];
      }
    } else {
      #pragma unroll
      for (int i = 0; i < 8; i++) bv[i] = 0.f;
    }
    BF8 A0, A1, B;
    A0.u[0] = pk2(a0lo.x, a0lo.y); A0.u[1] = pk2(a0lo.z, a0lo.w);
    A0.u[2] = pk2(a0hi.x, a0hi.y); A0.u[3] = pk2(a0hi.z, a0hi.w);
    A1.u[0] = pk2(a1lo.x, a1lo.y); A1.u[1] = pk2(a1lo.z, a1lo.w);
    A1.u[2] = pk2(a1hi.x, a1hi.y); A1.u[3] = pk2(a1hi.z, a1hi.w);
    B.u[0] = pk2(bv[0], bv[1]); B.u[1] = pk2(bv[2], bv[3]);
    B.u[2] = pk2(bv[4], bv[5]); B.u[3] = pk2(bv[6], bv[7]);
    acc0 = __builtin_amdgcn_mfma_f32_16x16x32_bf16(A0.v, B.v, acc0, 0, 0, 0);
    acc1 = __builtin_amdgcn_mfma_f32_16x16x32_bf16(A1.v, B.v, acc1, 0, 0, 0);
  }
  if (pok){
    #pragma unroll
    for (int r = 0; r < 4; r++){
      int m = m0 + hi * 4 + r;
      size_t idx = ((size_t)b * M + m) * 49 + p;
      float v = acc0[r] + (bias ? bias[m] : 0.f);
      if (res) v += res[idx];
      out[idx] = v;
      int m2 = m + 16;
      size_t idx2 = idx + 16 * 49;
      float v2 = acc1[r] + (bias ? bias[m2] : 0.f);
      if (res) v2 += res[idx2];
      out[idx2] = v2;
    }
  }
}

// k_mega1: 5728 blocks, type chosen after bijective scramble q=(id*2003)%5728
// so weff (memory-stream) / qkv (MFMA) / im2col / spatial co-schedule.
// q<1600 weff | <3904 qkv | <5472 im2col | else spatial
__global__ __launch_bounds__(256) void k_mega1(
    const float* __restrict__ ad_dir_w, const float* __restrict__ aw, u16* __restrict__ weff,
    const float* __restrict__ ra_w, const float* __restrict__ aa_w,
    const float* __restrict__ xr, const float* __restrict__ normed,
    const float* __restrict__ lnm, const float* __restrict__ lnr,
    const float* __restrict__ ln_g, const float* __restrict__ ln_b,
    float* __restrict__ ra_qkv, float* __restrict__ aa_qkv,
    u16* __restrict__ xim,
    const float* __restrict__ h1_g, const float* __restrict__ sa_w2, const float* __restrict__ sa_b2,
    const float* __restrict__ sa_g, const float* __restrict__ sa_bb, float* __restrict__ spat_g)
{
  __shared__ float sm[3300];
  int id = (blockIdx.x * 2003) % 5728;
  if (id < 1600){
    dev_weff(ad_dir_w, aw, weff, id);
  } else if (id < 3904){
    int q = id - 1600;
    int bx = q % 72, b = q / 72;
    if (bx < 24){
      int m0 = (bx >> 2) * 128, p0 = (bx & 3) * 16;
      mfma_gemm_dev(ra_w, nullptr, xr, nullptr, ra_qkv, 768, 256, m0, p0, b,
                    nullptr, nullptr, nullptr, nullptr);
    } else {
      int bx2 = bx - 24;
      int m0 = (bx2 >> 2) * 128, p0 = (bx2 & 3) * 16;
      mfma_gemm_dev(aa_w, nullptr, normed, nullptr, aa_qkv, 1536, 256, m0, p0, b,
                    lnm + b * 49, lnr + b * 49, ln_g, ln_b);
    }
  } else if (id < 5472){
    int q = id - 3904;
    dev_im2col(normed, xim, q % 49, q / 49, sm);
  } else {
    int q = id - 5472;
    dev_spatial(normed, h1_g, sa_w2, sa_b2, sa_g, sa_bb, spat_g, q % 8, q / 8, sm);
  }
}

// ---------------------------------------------------------------------------
// dev_conv / dev_attn  (merged into k_mega2)
// ---------------------------------------------------------------------------
__device__ void dev_conv(
    const u16* __restrict__ weff, const u16* __restrict__ xim, float* __restrict__ partial,
    int bx, int b)
{
  int mblk = bx >> 3, kp = bx & 7;
  int wv = threadIdx.x >> 6, lane = threadIdx.x & 63;
  int lo = lane & 15, hi = lane >> 4;
  int co0 = mblk * 128 + wv * 32;
  const u16* wr0 = weff + (size_t)b * 1638400 + (size_t)(co0 + lo) * 6400 + kp * 800 + hi * 8;
  const u16* wr1 = wr0 + 16 * 6400;
  const u16* xb = xim + (size_t)b * 313600 + (size_t)lo * 6400 + kp * 800 + hi * 8;
  f32x4 acc[2][4];
  #pragma unroll
  for (int mi = 0; mi < 2; mi++)
    #pragma unroll
    for (int pi = 0; pi < 4; pi++) acc[mi][pi] = (f32x4){0.f, 0.f, 0.f, 0.f};
  #pragma unroll 1
  for (int ks = 0; ks < 25; ks++){
    int k0 = ks * 32;
    bf16x8 A0 = __builtin_nontemporal_load((const bf16x8*)(wr0 + k0));
    bf16x8 A1 = __builtin_nontemporal_load((const bf16x8*)(wr1 + k0));
    bf16x8 B0 = *(const bf16x8*)(xb + k0);
    bf16x8 B1 = *(const bf16x8*)(xb + 16 * 6400 + k0);
    bf16x8 B2 = *(const bf16x8*)(xb + 32 * 6400 + k0);
    bf16x8 B3 = *(const bf16x8*)(xb + 48 * 6400 + k0);
    acc[0][0] = __builtin_amdgcn_mfma_f32_16x16x32_bf16(A0, B0, acc[0][0], 0, 0, 0);
    acc[0][1] = __builtin_amdgcn_mfma_f32_16x16x32_bf16(A0, B1, acc[0][1], 0, 0, 0);
    acc[0][2] = __builtin_amdgcn_mfma_f32_16x16x32_bf16(A0, B2, acc[0][2], 0, 0, 0);
    acc[0][3] = __builtin_amdgcn_mfma_f32_16x16x32_bf16(A0, B3, acc[0][3], 0, 0, 0);
    acc[1][0] = __builtin_amdgcn_mfma_f32_16x16x32_bf16(A1, B0, acc[1][0], 0, 0, 0);
    acc[1][1] = __builtin_amdgcn_mfma_f32_16x16x32_bf16(A1, B1, acc[1][1], 0, 0, 0);
    acc[1][2] = __builtin_amdgcn_mfma_f32_16x16x32_bf16(A1, B2, acc[1][2], 0, 0, 0);
    acc[1][3] = __builtin_amdgcn_mfma_f32_16x16x32_bf16(A1, B3, acc[1][3], 0, 0, 0);
  }
  float* pb = partial + ((size_t)kp * 32 + b) * 12544;
  #pragma unroll
  for (int mi = 0; mi < 2; mi++){
    #pragma unroll
    for (int pi = 0; pi < 4; pi++){
      int p = pi * 16 + lo;
      if (p < 49){
        #pragma unroll
        for (int r = 0; r < 4; r++){
          int co = co0 + mi * 16 + hi * 4 + r;
          pb[co * 49 + p] = acc[mi][pi][r];
        }
      }
    }
  }
}

__device__ __forceinline__ void softmax_rows(float* sc, int tid)
{
  int r = tid >> 2, q = tid & 3;
  if (r < 49){
    float* row = sc + r * 52;
    float mx = -1e30f;
    for (int j = q; j < 49; j += 4) mx = fmaxf(mx, row[j]);
    mx = fmaxf(mx, __shfl_xor(mx, 1));
    mx = fmaxf(mx, __shfl_xor(mx, 2));
    float sm = 0.f;
    for (int j = q; j < 49; j += 4){ float e = __expf(row[j] - mx); row[j] = e; sm += e; }
    sm += __shfl_xor(sm, 1);
    sm += __shfl_xor(sm, 2);
    float inv = 1.f / sm;
    for (int j = q; j < 49; j += 4) row[j] *= inv;
  }
}

__device__ void dev_attn(
    const float* __restrict__ ra_qkv, const float* __restrict__ aa_qkv,
    const float* __restrict__ relpos,
    float* __restrict__ r0, float* __restrict__ ao,
    int xb2, int b, float* sm)
{
  if (xb2 < 8){
    int hd = xb2;
    float* qs = sm; float* ks = sm + 1617; float* vs = sm + 3234; float* sc = sm + 4851;
    const float* base = ra_qkv + (size_t)b * 768 * 49;
    for (int i = threadIdx.x; i < 1568; i += 256){
      int d = i / 49, tok = i - d * 49;
      qs[tok * 33 + d] = base[(hd * 32 + d) * 49 + tok];
      ks[tok * 33 + d] = base[(256 + hd * 32 + d) * 49 + tok];
      vs[tok * 33 + d] = base[(512 + hd * 32 + d) * 49 + tok];
    }
    __syncthreads();
    const float scale = 0.17677669529663687f;
    for (int it = threadIdx.x; it < 2401; it += 256){
      int i = it / 49, j = it - i * 49;
      float s = 0.f;
      #pragma unroll
      for (int d = 0; d < 32; d++) s += qs[i * 33 + d] * ks[j * 33 + d];
      sc[i * 52 + j] = s * scale;
    }
    __syncthreads();
    softmax_rows(sc, threadIdx.x);
    __syncthreads();
    for (int it = threadIdx.x; it < 1568; it += 256){
      int d = it / 49, i = it - d * 49;
      float o = 0.f;
      for (int j = 0; j < 49; j++) o += sc[i * 52 + j] * vs[j * 33 + d];
      r0[((size_t)b * 256 + hd * 32 + d) * 49 + i] = o;
    }
  } else {
    int hd = xb2 - 8;
    float* qs = sm; float* ks = sm + 3185; float* vs = sm + 6370; float* sc = sm + 9555;
    const float* base = aa_qkv + (size_t)b * 1536 * 49;
    for (int i = threadIdx.x; i < 3136; i += 256){
      int d = i / 49, tok = i - d * 49;
      qs[tok * 65 + d] = base[(hd * 64 + d) * 49 + tok];
      ks[tok * 65 + d] = base[(512 + hd * 64 + d) * 49 + tok];
      vs[tok * 65 + d] = base[(1024 + hd * 64 + d) * 49 + tok];
    }
    __syncthreads();
    for (int it = threadIdx.x; it < 2401; it += 256){
      int i = it / 49, j = it - i * 49;
      float s = 0.f;
      #pragma unroll
      for (int d = 0; d < 64; d++) s += qs[i * 65 + d] * ks[j * 65 + d];
      int dy = j / 7 - i / 7 + 6, dx = j % 7 - i % 7 + 6;
      sc[i * 52 + j] = s * 0.125f + relpos[(dy * 13 + dx) * 8 + hd];
    }
    __syncthreads();
    softmax_rows(sc, threadIdx.x);
    __syncthreads();
    for (int it = threadIdx.x; it < 3136; it += 256){
      int d = it / 49, i = it - d * 49;
      float o = 0.f;
      for (int j = 0; j < 49; j++) o += sc[i * 52 + j] * vs[j * 65 + d];
      ao[((size_t)b * 512 + hd * 64 + d) * 49 + i] = o;
    }
  }
}

// k_mega2: 1024 blocks, parity interleave: even -> conv, odd -> attn
__global__ __launch_bounds__(256) void k_mega2(
    const u16* __restrict__ weff, const u16* __restrict__ xim, float* __restrict__ partial,
    const float* __restrict__ ra_qkv, const float* __restrict__ aa_qkv,
    const float* __restrict__ relpos, float* __restrict__ r0, float* __restrict__ ao)
{
  __shared__ float sm[12103];
  int id = blockIdx.x;
  int q = id >> 1;
  if ((id & 1) == 0){
    dev_conv(weff, xim, partial, q % 16, q / 16);
  } else {
    dev_attn(ra_qkv, aa_qkv, relpos, r0, ao, q % 16, q / 16, sm);
  }
}

// k_conv_reduce: comb = sum of 8 k-partials
__global__ __launch_bounds__(256) void k_conv_reduce(
    const float* __restrict__ part, float* __restrict__ comb)
{
  int i = blockIdx.x * 256 + threadIdx.x;
  if (i >= 100352) return;
  float a0 = 0.f, a1 = 0.f, a2 = 0.f, a3 = 0.f;
  #pragma unroll
  for (int p = 0; p < 8; p++){
    float4 v = ((const float4*)part)[(size_t)p * 100352 + i];
    a0 += v.x; a1 += v.y; a2 += v.z; a3 += v.w;
  }
  float4 o; o.x = a0; o.y = a1; o.z = a2; o.w = a3;
  ((float4*)comb)[i] = o;
}

// merged projections: bx<8 ra_proj, <16 aa_out (K=512), else ad_proj
__global__ __launch_bounds__(256) void k_proj3(
    const float* __restrict__ ra_pw, const float* __restrict__ ra_pb, const float* __restrict__ r0,
    const float* __restrict__ aa_ow, const float* __restrict__ aa_ob, const float* __restrict__ aa_o,
    const float* __restrict__ ad_pw, const float* __restrict__ ad_pb, const float* __restrict__ comb,
    const float* __restrict__ normed,
    float* __restrict__ rotf, float* __restrict__ angf, float* __restrict__ adpf)
{
  int bx = blockIdx.x, b = blockIdx.y;
  if (bx < 8){
    int m0 = (bx >> 2) * 128, p0 = (bx & 3) * 16;
    mfma_gemm_dev(ra_pw, ra_pb, r0, normed, rotf, 256, 256, m0, p0, b,
                  nullptr, nullptr, nullptr, nullptr);
  } else if (bx < 16){
    int bx2 = bx - 8;
    int m0 = (bx2 >> 2) * 128, p0 = (bx2 & 3) * 16;
    mfma_gemm_dev(aa_ow, aa_ob, aa_o, normed, angf, 256, 512, m0, p0, b,
                  nullptr, nullptr, nullptr, nullptr);
  } else {
    int bx2 = bx - 16;
    int m0 = (bx2 >> 2) * 128, p0 = (bx2 & 3) * 16;
    mfma_gemm_dev(ad_pw, ad_pb, comb, normed, adpf, 256, 256, m0, p0, b,
                  nullptr, nullptr, nullptr, nullptr);
  }
}

// k_final: out = proj_w @ fused + proj_b + x, fused computed on the fly
__global__ __launch_bounds__(256) void k_final(
    const float* __restrict__ proj_w, const float* __restrict__ proj_b,
    const float* __restrict__ spat, const float* __restrict__ rotf,
    const float* __restrict__ angf, const float* __restrict__ adpf,
    const float* __restrict__ gates, const float* __restrict__ x,
    float* __restrict__ out)
{
  int bx = blockIdx.x, b = blockIdx.y;
  int wv = threadIdx.x >> 6, lane = threadIdx.x & 63;
  int lo = lane & 15, hi = lane >> 4;
  int m0 = (bx >> 2) * 128 + wv * 32;
  int p0 = (bx & 3) * 16;
  int p = p0 + lo;
  bool pok = p < 49;
  float g0 = 0.f, g1 = 0.f, g2 = 0.f, g3 = 0.f;
  if (pok){
    const float* g = gates + (size_t)b * 196 + p;
    g0 = g[0]; g1 = g[49]; g2 = g[98]; g3 = g[147];
  }
  size_t boff = (size_t)b * 12544;
  f32x4 acc0 = {0.f, 0.f, 0.f, 0.f};
  f32x4 acc1 = {0.f, 0.f, 0.f, 0.f};
  const float* wr0 = proj_w + (size_t)(m0 + lo) * 256 + hi * 8;
  const float* wr1 = wr0 + 16 * 256;
  for (int k0 = 0; k0 < 256; k0 += 32){
    int kb = k0 + hi * 8;
    float4 a0lo = *(const float4*)(wr0 + k0);
    float4 a0hi = *(const float4*)(wr0 + k0 + 4);
    float4 a1lo = *(const float4*)(wr1 + k0);
    float4 a1hi = *(const float4*)(wr1 + k0 + 4);
    float bv[8];
    if (pok){
      size_t base = boff + (size_t)kb * 49 + p;
      #pragma unroll
      for (int i = 0; i < 8; i++){
        size_t idx = base + (size_t)i * 49;
        bv[i] = spat[idx] * g0 + rotf[idx] * g1 + angf[idx] * g2 + adpf[idx] * g3;
      }
    } else {
      #pragma unroll
      for (int i = 0; i < 8; i++) bv[i] = 0.f;
    }
    BF8 A0, A1, B;
    A0.u[0] = pk2(a0lo.x, a0lo.y); A0.u[1] = pk2(a0lo.z, a0lo.w);
    A0.u[2] = pk2(a0hi.x, a0hi.y); A0.u[3] = pk2(a0hi.z, a0hi.w);
    A1.u[0] = pk2(a1lo.x, a1lo.y); A1.u[1] = pk2(a1lo.z, a1lo.w);
    A1.u[2] = pk2(a1hi.x, a1hi.y); A1.u[3] = pk2(a1hi.z, a1hi.w);
    B.u[0] = pk2(bv[0], bv[1]); B.u[1] = pk2(bv[2], bv[3]);
    B.u[2] = pk2(bv[4], bv[5]); B.u[3] = pk2(bv[6], bv[7]);
    acc0 = __builtin_amdgcn_mfma_f32_16x16x32_bf16(A0.v, B.v, acc0, 0, 0, 0);
    acc1 = __builtin_amdgcn_mfma_f32_16x16x32_bf16(A1.v, B.v, acc1, 0, 0, 0);
  }
  if (pok){
    #pragma unroll
    for (int r = 0; r < 4; r++){
      int m = m0 + hi * 4 + r;
      size_t idx = boff + (size_t)m * 49 + p;
      out[idx] = acc0[r] + proj_b[m] + x[idx];
      int m2 = m + 16;
      size_t idx2 = idx + 16 * 49;
      out[idx2] = acc1[r] + proj_b[m2] + x[idx2];
    }
  }
}

// ---------------------------------------------------------------------------
extern "C" void kernel_launch(void* const* d_in, const int* in_sizes, int n_in,
                              void* d_out, int out_size, void* d_ws, size_t ws_size,
                              hipStream_t stream)
{
  const float* x        = (const float*)d_in[0];
  const float* gn_g     = (const float*)d_in[1];
  const float* gn_b     = (const float*)d_in[2];
  const float* sa_w1    = (const float*)d_in[3];
  const float* sa_b1    = (const float*)d_in[4];
  const float* sa_w2    = (const float*)d_in[5];
  const float* sa_b2    = (const float*)d_in[6];
  const float* sa_gn_g  = (const float*)d_in[7];
  const float* sa_gn_b  = (const float*)d_in[8];
  const float* ra_gn_g  = (const float*)d_in[9];
  const float* ra_gn_b  = (const float*)d_in[10];
  const float* ra_qkv_w = (const float*)d_in[11];
  const float* ra_proj_w= (const float*)d_in[12];
  const float* ra_proj_b= (const float*)d_in[13];
  const float* aa_ln_g  = (const float*)d_in[14];
  const float* aa_ln_b  = (const float*)d_in[15];
  const float* aa_qkv_w = (const float*)d_in[16];
  const float* aa_relpos= (const float*)d_in[17];
  const float* aa_out_w = (const float*)d_in[18];
  const float* aa_out_b = (const float*)d_in[19];
  const float* ad_dir_w = (const float*)d_in[20];
  const float* ad_ap_w1 = (const float*)d_in[21];
  const float* ad_ap_b1 = (const float*)d_in[22];
  const float* ad_ap_w2 = (const float*)d_in[23];
  const float* ad_ap_b2 = (const float*)d_in[24];
  const float* ad_proj_w= (const float*)d_in[25];
  const float* ad_proj_b= (const float*)d_in[26];
  const float* gate_w   = (const float*)d_in[27];
  const float* gate_b   = (const float*)d_in[28];
  const float* proj_w   = (const float*)d_in[29];
  const float* proj_b   = (const float*)d_in[30];

  char* ws = (char*)d_ws;
  float* normed    = (float*)(ws + 0);
  float* xr        = (float*)(ws + 1605632);
  float* h1_g      = (float*)(ws + 3211264);
  float* lnm       = (float*)(ws + 3420160);
  float* lnr       = (float*)(ws + 3426560);
  float* spatial   = (float*)(ws + 4816896);
  float* rotf      = (float*)(ws + 6422528);
  float* anglef    = (float*)(ws + 8028160);
  float* adaptf    = (float*)(ws + 9633792);
  float* r0        = (float*)(ws + 12845056);
  float* gap       = (float*)(ws + 14450688);
  float* aw        = (float*)(ws + 14483456);
  float* gates     = (float*)(ws + 14485504);
  float* ra_qkv    = (float*)(ws + 14510592);
  float* aa_qkv    = (float*)(ws + 19327488);
  float* aa_o      = (float*)(ws + 28961280);
  float* comb      = (float*)(ws + 32172544);
  float* partial   = (float*)(ws + 33778176);   // 12,845,056 B
  u16*   xim       = (u16*)  (ws + 46623232);   // 20,070,400 B
  u16*   weff      = (u16*)  (ws + 66693632);   // 104,857,600 B

  float* out = (float*)d_out;

  k_prep1<<<dim3(8, 32), 256, 0, stream>>>(x, gn_g, gn_b, ra_gn_g, ra_gn_b, normed, xr, gap);
  k_pre2<<<dim3(15, 32), 256, 0, stream>>>(x, normed, gate_w, gate_b,
                                           sa_w1, sa_b1, ad_ap_w1, ad_ap_b1, ad_ap_w2, ad_ap_b2,
                                           gap, gates, lnm, lnr, h1_g, aw);
  k_mega1<<<dim3(5728), 256, 0, stream>>>(ad_dir_w, aw, weff,
                                          ra_qkv_w, aa_qkv_w, xr, normed,
                                          lnm, lnr, aa_ln_g, aa_ln_b, ra_qkv, aa_qkv,
                                          xim,
                                          h1_g, sa_w2, sa_b2, sa_gn_g, sa_gn_b, spatial);
  k_mega2<<<dim3(1024), 256, 0, stream>>>(weff, xim, partial,
                                          ra_qkv, aa_qkv, aa_relpos, r0, aa_o);
  k_conv_reduce<<<dim3(392), 256, 0, stream>>>(partial, comb);
  k_proj3<<<dim3(24, 32), 256, 0, stream>>>(ra_proj_w, ra_proj_b, r0,
                                            aa_out_w, aa_out_b, aa_o,
                                            ad_proj_w, ad_proj_b, comb,
                                            normed, rotf, anglef, adaptf);
  k_final<<<dim3(8, 32), 256, 0, stream>>>(proj_w, proj_b, spatial, rotf, anglef, adaptf,
                                           gates, x, out);
}